// Round 3
// baseline (738.519 us; speedup 1.0000x reference)
//
#include <hip/hip_runtime.h>
#include <cstdint>
#include <cstddef>

typedef short  bf16x8 __attribute__((ext_vector_type(8)));
typedef float  f32x4  __attribute__((ext_vector_type(4)));

#define NEGV (-1e30f)
#define LDT 40   // padded LDS row pitch (shorts) = 80B, 16B-aligned, conflict-light

__device__ __forceinline__ short f2bf(float x){
    union { float f; unsigned u; } v; v.f = x;
    return (short)((v.u + 0x7fffu + ((v.u >> 16) & 1u)) >> 16);
}
__device__ __forceinline__ float bf2f(short h){
    union { float f; unsigned u; } v; v.u = ((unsigned)(unsigned short)h) << 16; return v.f;
}
__device__ __forceinline__ unsigned packbf(short a, short b){
    return (unsigned)(unsigned short)a | ((unsigned)(unsigned short)b << 16);
}

// ---------------- prep: W1,W2 -> transposed bf16 hi/lo ----------------
__global__ __launch_bounds__(256)
void k_prep_w(const float* __restrict__ W1, const float* __restrict__ W2,
              short* __restrict__ W1Th, short* __restrict__ W1Tl,
              short* __restrict__ W2Th, short* __restrict__ W2Tl)
{
    int idx = blockIdx.x * 256 + threadIdx.x;
    int w = idx >> 18;
    int e = idx & ((1 << 18) - 1);
    int n = e & 511, k = e >> 9;
    const float* W = w ? W2 : W1;
    float x = W[k * 512 + n];
    short hi = f2bf(x);
    short lo = f2bf(x - bf2f(hi));
    size_t o = (size_t)n * 512 + k;
    if (w) { W2Th[o] = hi; W2Tl[o] = lo; } else { W1Th[o] = hi; W1Tl[o] = lo; }
}

// ---------------- prep c: cqc = (c*cqw) bf16, c_hi/c_lo bf16, s0 = c@cw ----------------
__global__ __launch_bounds__(256)
void k_prep_c(const float* __restrict__ c, const float* __restrict__ cqw,
              const float* __restrict__ cwv, short* __restrict__ cqc,
              short* __restrict__ chi, short* __restrict__ clo,
              float* __restrict__ s0g)
{
    __shared__ float cqs[512], cws[512];
    const int t = threadIdx.x;
    cqs[t] = cqw[t]; cqs[t + 256] = cqw[t + 256];
    cws[t] = cwv[t]; cws[t + 256] = cwv[t + 256];
    __syncthreads();
    const int R = (int)blockIdx.x * 16 + (t >> 4);
    const int lane16 = t & 15;
    const size_t base = (size_t)R * 512;
    float s0acc = 0.f;
    #pragma unroll
    for (int i = 0; i < 8; i++) {
        int col = lane16 * 4 + i * 64;
        float4 v = *(const float4*)(c + base + col);
        short h0 = f2bf(v.x), h1 = f2bf(v.y), h2 = f2bf(v.z), h3 = f2bf(v.w);
        uint2 dh; dh.x = packbf(h0, h1); dh.y = packbf(h2, h3);
        *(uint2*)(chi + base + col) = dh;
        uint2 dl;
        dl.x = packbf(f2bf(v.x - bf2f(h0)), f2bf(v.y - bf2f(h1)));
        dl.y = packbf(f2bf(v.z - bf2f(h2)), f2bf(v.w - bf2f(h3)));
        *(uint2*)(clo + base + col) = dl;
        uint2 dq;
        dq.x = packbf(f2bf(v.x * cqs[col]),     f2bf(v.y * cqs[col + 1]));
        dq.y = packbf(f2bf(v.z * cqs[col + 2]), f2bf(v.w * cqs[col + 3]));
        *(uint2*)(cqc + base + col) = dq;
        s0acc += v.x * cws[col] + v.y * cws[col + 1] + v.z * cws[col + 2] + v.w * cws[col + 3];
    }
    #pragma unroll
    for (int off = 1; off < 16; off <<= 1) s0acc += __shfl_xor(s0acc, off);
    if (lane16 == 0) s0g[R] = s0acc;
}

// ---------------- prep q: q_bf, qT, s1 partials ----------------
__global__ __launch_bounds__(256)
void k_prep_q(const float* __restrict__ q, const float* __restrict__ qwv,
              short* __restrict__ q_bf, short* __restrict__ qT,
              float* __restrict__ s1p)
{
    __shared__ short TT[128 * 136];
    __shared__ float qws[128];
    const int t = threadIdx.x;
    const int b = (int)(blockIdx.x >> 2), hb = (int)(blockIdx.x & 3), h0 = hb * 128;
    if (t < 128) qws[t] = qwv[h0 + t];
    __syncthreads();
    #pragma unroll
    for (int it = 0; it < 16; it++) {
        int idx = it * 256 + t;
        int m = idx >> 5, c4 = (idx & 31) * 4;
        float4 v = *(const float4*)(q + ((size_t)b * 128 + m) * 512 + h0 + c4);
        short h0s = f2bf(v.x), h1s = f2bf(v.y), h2s = f2bf(v.z), h3s = f2bf(v.w);
        TT[(c4 + 0) * 136 + m] = h0s;
        TT[(c4 + 1) * 136 + m] = h1s;
        TT[(c4 + 2) * 136 + m] = h2s;
        TT[(c4 + 3) * 136 + m] = h3s;
        uint2 d; d.x = packbf(h0s, h1s); d.y = packbf(h2s, h3s);
        *(uint2*)(q_bf + ((size_t)b * 128 + m) * 512 + h0 + c4) = d;
        float dot = v.x * qws[c4] + v.y * qws[c4 + 1] + v.z * qws[c4 + 2] + v.w * qws[c4 + 3];
        #pragma unroll
        for (int off = 1; off < 32; off <<= 1) dot += __shfl_xor(dot, off);
        if ((t & 31) == 0) s1p[((size_t)b * 4 + hb) * 128 + m] = dot;
    }
    __syncthreads();
    const int h = t >> 1, half = t & 1;
    short* dst = qT + ((size_t)b * 512 + h0 + h) * 128 + half * 64;
    #pragma unroll
    for (int j = 0; j < 8; j++)
        *(bf16x8*)(dst + j * 8) = *(const bf16x8*)&TT[h * 136 + half * 64 + j * 8];
}

// ---------------- split-bf16 linear; WT variant writes hi/lo bf16 + transposed copy ----------------
template<bool WT>
__global__ __launch_bounds__(256)
void k_linear(const float* __restrict__ X, const short* __restrict__ WTh,
              const short* __restrict__ WTl, const float* __restrict__ bias,
              float* __restrict__ Y, short* __restrict__ Yh,
              short* __restrict__ Yl, short* __restrict__ YT)
{
    __shared__ short SMEM[4 * 128 * LDT];
    short* Ah = SMEM;
    short* Al = SMEM + 128 * LDT;
    short* Bh = SMEM + 2 * 128 * LDT;
    short* Bl = SMEM + 3 * 128 * LDT;
    const int t = threadIdx.x;
    const int m0 = (int)(blockIdx.x >> 2) * 128;
    const int n0 = (int)(blockIdx.x & 3) * 128;
    const int lane = t & 63;
    const int wr = (t >> 7) & 1, wc = (t >> 6) & 1;
    const int fr = lane & 15, fg = lane >> 4;
    const int srow = t >> 1, sk = (t & 1) * 16;

    f32x4 acc[4][4] = {};

    for (int k0 = 0; k0 < 512; k0 += 32) {
        __syncthreads();
        {
            const float* src = X + (size_t)(m0 + srow) * 512 + k0 + sk;
            float4 f[4];
            #pragma unroll
            for (int i = 0; i < 4; i++) f[i] = ((const float4*)src)[i];
            const float* fv = (const float*)f;
            short hi[16], lo[16];
            #pragma unroll
            for (int j = 0; j < 16; j++) {
                float x = fv[j];
                short h = f2bf(x);
                hi[j] = h; lo[j] = f2bf(x - bf2f(h));
            }
            #pragma unroll
            for (int j = 0; j < 2; j++) {
                *(bf16x8*)&Ah[srow * LDT + sk + j * 8] = *(bf16x8*)&hi[j * 8];
                *(bf16x8*)&Al[srow * LDT + sk + j * 8] = *(bf16x8*)&lo[j * 8];
            }
        }
        {
            const short* sh = WTh + (size_t)(n0 + srow) * 512 + k0 + sk;
            const short* sl = WTl + (size_t)(n0 + srow) * 512 + k0 + sk;
            #pragma unroll
            for (int j = 0; j < 2; j++) {
                *(bf16x8*)&Bh[srow * LDT + sk + j * 8] = ((const bf16x8*)sh)[j];
                *(bf16x8*)&Bl[srow * LDT + sk + j * 8] = ((const bf16x8*)sl)[j];
            }
        }
        __syncthreads();
        bf16x8 a_h[4], a_l[4], b_h[4], b_l[4];
        #pragma unroll
        for (int i = 0; i < 4; i++) {
            int ar = (wr * 64 + i * 16 + fr) * LDT + fg * 8;
            int br = (wc * 64 + i * 16 + fr) * LDT + fg * 8;
            a_h[i] = *(const bf16x8*)&Ah[ar];
            a_l[i] = *(const bf16x8*)&Al[ar];
            b_h[i] = *(const bf16x8*)&Bh[br];
            b_l[i] = *(const bf16x8*)&Bl[br];
        }
        #pragma unroll
        for (int mi = 0; mi < 4; mi++)
        #pragma unroll
        for (int ni = 0; ni < 4; ni++) {
            acc[mi][ni] = __builtin_amdgcn_mfma_f32_16x16x32_bf16(a_h[mi], b_h[ni], acc[mi][ni], 0, 0, 0);
            acc[mi][ni] = __builtin_amdgcn_mfma_f32_16x16x32_bf16(a_h[mi], b_l[ni], acc[mi][ni], 0, 0, 0);
            acc[mi][ni] = __builtin_amdgcn_mfma_f32_16x16x32_bf16(a_l[mi], b_h[ni], acc[mi][ni], 0, 0, 0);
        }
    }
    float bv[4];
    #pragma unroll
    for (int ni = 0; ni < 4; ni++) bv[ni] = bias[n0 + wc * 64 + ni * 16 + fr];

    if (!WT) {
        #pragma unroll
        for (int mi = 0; mi < 4; mi++)
        #pragma unroll
        for (int r = 0; r < 4; r++) {
            int row = m0 + wr * 64 + mi * 16 + fg * 4 + r;
            #pragma unroll
            for (int ni = 0; ni < 4; ni++)
                Y[(size_t)row * 512 + n0 + wc * 64 + ni * 16 + fr] =
                    fmaxf(acc[mi][ni][r] + bv[ni], 0.f);
        }
    } else {
        #pragma unroll
        for (int mi = 0; mi < 4; mi++)
        #pragma unroll
        for (int r = 0; r < 4; r++) {
            int row = m0 + wr * 64 + mi * 16 + fg * 4 + r;
            #pragma unroll
            for (int ni = 0; ni < 4; ni++) {
                float v = fmaxf(acc[mi][ni][r] + bv[ni], 0.f);
                short h = f2bf(v);
                size_t o = (size_t)row * 512 + n0 + wc * 64 + ni * 16 + fr;
                Yh[o] = h;
                Yl[o] = f2bf(v - bf2f(h));
            }
        }
        __syncthreads();
        short* TT = SMEM;
        #pragma unroll
        for (int mi = 0; mi < 4; mi++)
        #pragma unroll
        for (int r = 0; r < 4; r++) {
            int ml = wr * 64 + mi * 16 + fg * 4 + r;
            #pragma unroll
            for (int ni = 0; ni < 4; ni++)
                TT[(wc * 64 + ni * 16 + fr) * 136 + ml] =
                    f2bf(fmaxf(acc[mi][ni][r] + bv[ni], 0.f));
        }
        __syncthreads();
        const int n = t >> 1, half = t & 1;
        short* dst = YT + ((size_t)(m0 >> 7) * 512 + n0 + n) * 128 + half * 64;
        #pragma unroll
        for (int j = 0; j < 8; j++)
            *(bf16x8*)(dst + j * 8) = *(const bf16x8*)&TT[n * 136 + half * 64 + j * 8];
    }
}

// ---------------- logits GEMM (bf16 pre-staged operands) + fused row softmax + col partials ----------------
template<bool SPLIT, bool ADDS>
__global__ __launch_bounds__(256)
void k_att(const short* __restrict__ Ahg, const short* __restrict__ Alg,
           const short* __restrict__ Bhg, const short* __restrict__ Blg,
           const float* __restrict__ s0g, const float* __restrict__ s1pg,
           const float* __restrict__ biasp, const int* __restrict__ qmask,
           const int* __restrict__ cmask, float* __restrict__ simb,
           short* __restrict__ Pr, float2* __restrict__ colpart)
{
    __shared__ short Ah[128 * LDT], Bh[128 * LDT];
    __shared__ short Al[SPLIT ? 128 * LDT : 8], Bl[SPLIT ? 128 * LDT : 8];
    __shared__ float red[2][128];
    __shared__ float mrowL[128], rinvL[128], cmaxL[128];
    __shared__ float s0L[ADDS ? 128 : 1], s1L[ADDS ? 128 : 1];
    __shared__ int qmsL[128], cmsL[128];

    const int t = threadIdx.x;
    const int b  = (int)(blockIdx.x & 63);     // XCD-friendly: all chunks of b on one XCD
    const int ch = (int)(blockIdx.x >> 6);
    const int m0 = ch * 128;
    const int lane = t & 63;
    const int wr = (t >> 7) & 1, wc = (t >> 6) & 1;
    const int fr = lane & 15, fg = lane >> 4;
    const int srow = t >> 1, sk = (t & 1) * 16;

    if (t < 128) {
        qmsL[t] = qmask[b * 128 + t];
        cmsL[t] = cmask[b * 1024 + m0 + t];
        if (ADDS) {
            s0L[t] = s0g[b * 1024 + m0 + t];
            s1L[t] = s1pg[((size_t)b * 4 + 0) * 128 + t] + s1pg[((size_t)b * 4 + 1) * 128 + t]
                   + s1pg[((size_t)b * 4 + 2) * 128 + t] + s1pg[((size_t)b * 4 + 3) * 128 + t];
        }
    }

    const size_t aoff = ((size_t)b * 1024 + m0 + srow) * 512;
    const size_t boff = ((size_t)b * 128 + srow) * 512;
    f32x4 acc[4][4] = {};

    for (int k0 = 0; k0 < 512; k0 += 32) {
        __syncthreads();
        *(uint4*)&Ah[srow * LDT + sk]     = *(const uint4*)(Ahg + aoff + k0 + sk);
        *(uint4*)&Ah[srow * LDT + sk + 8] = *(const uint4*)(Ahg + aoff + k0 + sk + 8);
        *(uint4*)&Bh[srow * LDT + sk]     = *(const uint4*)(Bhg + boff + k0 + sk);
        *(uint4*)&Bh[srow * LDT + sk + 8] = *(const uint4*)(Bhg + boff + k0 + sk + 8);
        if (SPLIT) {
            *(uint4*)&Al[srow * LDT + sk]     = *(const uint4*)(Alg + aoff + k0 + sk);
            *(uint4*)&Al[srow * LDT + sk + 8] = *(const uint4*)(Alg + aoff + k0 + sk + 8);
            *(uint4*)&Bl[srow * LDT + sk]     = *(const uint4*)(Blg + boff + k0 + sk);
            *(uint4*)&Bl[srow * LDT + sk + 8] = *(const uint4*)(Blg + boff + k0 + sk + 8);
        }
        __syncthreads();
        bf16x8 a_h[4], b_h[4], a_l[4], b_l[4];
        #pragma unroll
        for (int i = 0; i < 4; i++) {
            int ar = (wr * 64 + i * 16 + fr) * LDT + fg * 8;
            int br = (wc * 64 + i * 16 + fr) * LDT + fg * 8;
            a_h[i] = *(const bf16x8*)&Ah[ar];
            b_h[i] = *(const bf16x8*)&Bh[br];
            if (SPLIT) { a_l[i] = *(const bf16x8*)&Al[ar]; b_l[i] = *(const bf16x8*)&Bl[br]; }
        }
        #pragma unroll
        for (int mi = 0; mi < 4; mi++)
        #pragma unroll
        for (int ni = 0; ni < 4; ni++) {
            acc[mi][ni] = __builtin_amdgcn_mfma_f32_16x16x32_bf16(a_h[mi], b_h[ni], acc[mi][ni], 0, 0, 0);
            if (SPLIT) {
                acc[mi][ni] = __builtin_amdgcn_mfma_f32_16x16x32_bf16(a_h[mi], b_l[ni], acc[mi][ni], 0, 0, 0);
                acc[mi][ni] = __builtin_amdgcn_mfma_f32_16x16x32_bf16(a_l[mi], b_h[ni], acc[mi][ni], 0, 0, 0);
            }
        }
    }

    // additive terms
    if (ADDS) {
        float b0 = biasp[0];
        #pragma unroll
        for (int mi = 0; mi < 4; mi++)
        #pragma unroll
        for (int r = 0; r < 4; r++) {
            float s0r = s0L[wr * 64 + mi * 16 + fg * 4 + r] + b0;
            #pragma unroll
            for (int ni = 0; ni < 4; ni++)
                acc[mi][ni][r] += s0r + s1L[wc * 64 + ni * 16 + fr];
        }
    }
    // raw logits (for the column pass)
    #pragma unroll
    for (int mi = 0; mi < 4; mi++)
    #pragma unroll
    for (int r = 0; r < 4; r++) {
        int row = m0 + wr * 64 + mi * 16 + fg * 4 + r;
        #pragma unroll
        for (int ni = 0; ni < 4; ni++)
            simb[((size_t)b * 1024 + row) * 128 + wc * 64 + ni * 16 + fr] = acc[mi][ni][r];
    }

    bool qmv[4];
    #pragma unroll
    for (int ni = 0; ni < 4; ni++) qmv[ni] = qmsL[wc * 64 + ni * 16 + fr] != 0;
    bool cmb[4][4];
    #pragma unroll
    for (int mi = 0; mi < 4; mi++)
    #pragma unroll
    for (int r = 0; r < 4; r++) cmb[mi][r] = cmsL[wr * 64 + mi * 16 + fg * 4 + r] != 0;

    // row max
    #pragma unroll
    for (int mi = 0; mi < 4; mi++)
    #pragma unroll
    for (int r = 0; r < 4; r++) {
        float m = NEGV;
        #pragma unroll
        for (int ni = 0; ni < 4; ni++) if (qmv[ni]) m = fmaxf(m, acc[mi][ni][r]);
        #pragma unroll
        for (int off = 1; off < 16; off <<= 1) m = fmaxf(m, __shfl_xor(m, off));
        if (fr == 0) red[wc][wr * 64 + mi * 16 + fg * 4 + r] = m;
    }
    __syncthreads();
    if (t < 128) mrowL[t] = fmaxf(red[0][t], red[1][t]);
    __syncthreads();
    // row exp-sum
    #pragma unroll
    for (int mi = 0; mi < 4; mi++)
    #pragma unroll
    for (int r = 0; r < 4; r++) {
        float mr = mrowL[wr * 64 + mi * 16 + fg * 4 + r];
        float s = 0.f;
        #pragma unroll
        for (int ni = 0; ni < 4; ni++) if (qmv[ni]) s += __expf(acc[mi][ni][r] - mr);
        #pragma unroll
        for (int off = 1; off < 16; off <<= 1) s += __shfl_xor(s, off);
        if (fr == 0) red[wc][wr * 64 + mi * 16 + fg * 4 + r] = s;
    }
    __syncthreads();
    if (t < 128) rinvL[t] = 1.f / (red[0][t] + red[1][t]);
    __syncthreads();
    // emit row-softmax bf16
    #pragma unroll
    for (int mi = 0; mi < 4; mi++)
    #pragma unroll
    for (int r = 0; r < 4; r++) {
        int rowl = wr * 64 + mi * 16 + fg * 4 + r;
        float mr = mrowL[rowl], iv = rinvL[rowl];
        size_t obase = ((size_t)b * 1024 + m0 + rowl) * 128;
        #pragma unroll
        for (int ni = 0; ni < 4; ni++) {
            float o = qmv[ni] ? __expf(acc[mi][ni][r] - mr) * iv : 0.f;
            Pr[obase + wc * 64 + ni * 16 + fr] = f2bf(o);
        }
    }
    // column partials over this 128-row chunk
    float cpart[4];
    #pragma unroll
    for (int ni = 0; ni < 4; ni++) {
        float m = NEGV;
        #pragma unroll
        for (int mi = 0; mi < 4; mi++)
        #pragma unroll
        for (int r = 0; r < 4; r++) if (cmb[mi][r]) m = fmaxf(m, acc[mi][ni][r]);
        m = fmaxf(m, __shfl_xor(m, 16));
        m = fmaxf(m, __shfl_xor(m, 32));
        cpart[ni] = m;
    }
    if (fg == 0) {
        #pragma unroll
        for (int ni = 0; ni < 4; ni++) red[wr][wc * 64 + ni * 16 + fr] = cpart[ni];
    }
    __syncthreads();
    if (t < 128) cmaxL[t] = fmaxf(red[0][t], red[1][t]);
    __syncthreads();
    #pragma unroll
    for (int ni = 0; ni < 4; ni++) {
        float cm = cmaxL[wc * 64 + ni * 16 + fr];
        float s = 0.f;
        #pragma unroll
        for (int mi = 0; mi < 4; mi++)
        #pragma unroll
        for (int r = 0; r < 4; r++) if (cmb[mi][r]) s += __expf(acc[mi][ni][r] - cm);
        s += __shfl_xor(s, 16);
        s += __shfl_xor(s, 32);
        cpart[ni] = s;
    }
    __syncthreads();
    if (fg == 0) {
        #pragma unroll
        for (int ni = 0; ni < 4; ni++) red[wr][wc * 64 + ni * 16 + fr] = cpart[ni];
    }
    __syncthreads();
    if (t < 128) colpart[((size_t)b * 8 + ch) * 128 + t] = make_float2(cmaxL[t], red[0][t] + red[1][t]);
}

// ---------------- column softmax emit (combine inlined), transposed bf16 output ----------------
__global__ __launch_bounds__(512)
void k_emit2(const float* __restrict__ S, const int* __restrict__ cmask,
             const float2* __restrict__ colpart, short* __restrict__ PcT)
{
    __shared__ float2 colfinL[128];
    const int t = threadIdx.x;
    const int b = (int)(blockIdx.x >> 3), ch = (int)(blockIdx.x & 7);
    const int r0 = ch * 128;
    if (t < 128) {
        float M = NEGV;
        #pragma unroll
        for (int c2 = 0; c2 < 8; c2++) M = fmaxf(M, colpart[((size_t)b * 8 + c2) * 128 + t].x);
        float Ss = 0.f;
        #pragma unroll
        for (int c2 = 0; c2 < 8; c2++) {
            float2 p = colpart[((size_t)b * 8 + c2) * 128 + t];
            Ss += p.y * __expf(p.x - M);
        }
        colfinL[t] = make_float2(M, Ss);
    }
    __syncthreads();
    const int q2 = t >> 2, ig = t & 3;
    float2 cs = colfinL[q2];
    float inv = 1.f / cs.y;
    short buf[32];
    #pragma unroll
    for (int i = 0; i < 32; i++) {
        int r = r0 + ig * 32 + i;
        bool cm = cmask[b * 1024 + r] != 0;
        float v = S[((size_t)b * 1024 + r) * 128 + q2];
        buf[i] = f2bf(cm ? __expf(v - cs.x) * inv : 0.f);
    }
    short* dst = PcT + ((size_t)b * 128 + q2) * 1024 + r0 + ig * 32;
    #pragma unroll
    for (int j = 0; j < 4; j++) *(bf16x8*)(dst + j * 8) = *(bf16x8*)&buf[j * 8];
}

// ---------------- fused dual K=1024 GEMM, bf16 B-source, reg-prefetch double buffer ----------------
__global__ __launch_bounds__(256)
void k_kgemm2(const short* __restrict__ A1, const short* __restrict__ A2,
              const short* __restrict__ Chi, short* __restrict__ Y1T,
              short* __restrict__ Y2T)
{
    __shared__ short Bs[2][128 * LDT];
    __shared__ short TT[128 * 136];
    const int t = threadIdx.x;
    const int b  = (int)(blockIdx.x & 63);
    const int n0 = (int)(blockIdx.x >> 6) * 128;
    const int lane = t & 63;
    const int wr = (t >> 7) & 1, wc = (t >> 6) & 1;
    const int fr = lane & 15, fg = lane >> 4;
    const int n4 = (t & 31) * 4, kp2 = (t >> 5) * 2;

    f32x4 acc1[4][4] = {}, acc2[4][4] = {};

    auto load_e = [&](int k0, uint2* e) {
        #pragma unroll
        for (int s = 0; s < 2; s++) {
            const short* p = Chi + ((size_t)b * 1024 + k0 + kp2 + s * 16) * 512 + n0 + n4;
            e[s * 2]     = *(const uint2*)(p);
            e[s * 2 + 1] = *(const uint2*)(p + 512);
        }
    };
    auto store_b = [&](const uint2* e, int buf) {
        #pragma unroll
        for (int s = 0; s < 2; s++) {
            const short* r0p = (const short*)&e[s * 2];
            const short* r1p = (const short*)&e[s * 2 + 1];
            #pragma unroll
            for (int l = 0; l < 4; l++)
                *(unsigned*)&Bs[buf][(n4 + l) * LDT + kp2 + s * 16] = packbf(r0p[l], r1p[l]);
        }
    };

    {   // prologue: stage k0=0 into buf 0
        uint2 e[4];
        load_e(0, e);
        store_b(e, 0);
    }
    __syncthreads();

    for (int k0 = 0; k0 < 1024; k0 += 32) {
        const int cur = (k0 >> 5) & 1;
        const bool more = (k0 + 32) < 1024;
        uint2 e[4];
        if (more) load_e(k0 + 32, e);      // issue next-tile loads early
        bf16x8 a1[4], a2[4], bg[4];
        #pragma unroll
        for (int i = 0; i < 4; i++) {
            size_t arow = (size_t)(b * 128 + wr * 64 + i * 16 + fr) * 1024 + k0 + fg * 8;
            a1[i] = *(const bf16x8*)(A1 + arow);
            a2[i] = *(const bf16x8*)(A2 + arow);
            bg[i] = *(const bf16x8*)&Bs[cur][(wc * 64 + i * 16 + fr) * LDT + fg * 8];
        }
        #pragma unroll
        for (int mi = 0; mi < 4; mi++)
        #pragma unroll
        for (int ni = 0; ni < 4; ni++) {
            acc1[mi][ni] = __builtin_amdgcn_mfma_f32_16x16x32_bf16(a1[mi], bg[ni], acc1[mi][ni], 0, 0, 0);
            acc2[mi][ni] = __builtin_amdgcn_mfma_f32_16x16x32_bf16(a2[mi], bg[ni], acc2[mi][ni], 0, 0, 0);
        }
        if (more) store_b(e, cur ^ 1);     // pack + LDS write after compute
        __syncthreads();
    }

    // transpose-bounce outputs -> coalesced [B,512,128] bf16
    const int n = t >> 1, half = t & 1;
    #pragma unroll
    for (int mi = 0; mi < 4; mi++)
    #pragma unroll
    for (int r = 0; r < 4; r++) {
        int ml = wr * 64 + mi * 16 + fg * 4 + r;
        #pragma unroll
        for (int ni = 0; ni < 4; ni++)
            TT[(wc * 64 + ni * 16 + fr) * 136 + ml] = f2bf(acc1[mi][ni][r]);
    }
    __syncthreads();
    {
        short* dst = Y1T + ((size_t)b * 512 + n0 + n) * 128 + half * 64;
        #pragma unroll
        for (int j = 0; j < 8; j++)
            *(bf16x8*)(dst + j * 8) = *(const bf16x8*)&TT[n * 136 + half * 64 + j * 8];
    }
    __syncthreads();
    #pragma unroll
    for (int mi = 0; mi < 4; mi++)
    #pragma unroll
    for (int r = 0; r < 4; r++) {
        int ml = wr * 64 + mi * 16 + fg * 4 + r;
        #pragma unroll
        for (int ni = 0; ni < 4; ni++)
            TT[(wc * 64 + ni * 16 + fr) * 136 + ml] = f2bf(acc2[mi][ni][r]);
    }
    __syncthreads();
    {
        short* dst = Y2T + ((size_t)b * 512 + n0 + n) * 128 + half * 64;
        #pragma unroll
        for (int j = 0; j < 8; j++)
            *(bf16x8*)(dst + j * 8) = *(const bf16x8*)&TT[n * 136 + half * 64 + j * 8];
    }
}

// ---------------- epilogue GEMM (K=128), direct-global fragments, fused output writes ----------------
template<bool WITHC>
__global__ __launch_bounds__(256)
void k_epi(const short* __restrict__ Pm, const short* __restrict__ BT1,
           const short* __restrict__ BT2, const float* __restrict__ Cc,
           float* __restrict__ out)
{
    const int t = threadIdx.x;
    const int hb = (int)(blockIdx.x & 3);
    const int mb = (int)((blockIdx.x >> 2) & 7);
    const int b  = (int)(blockIdx.x >> 5);
    const int m0 = mb * 128, h0 = hb * 128;
    const int lane = t & 63;
    const int wr = (t >> 7) & 1, wc = (t >> 6) & 1;
    const int fr = lane & 15, fg = lane >> 4;
    f32x4 acc1[4][4] = {}, acc2[4][4] = {};
    const short* Abase  = Pm  + ((size_t)b * 1024 + m0) * 128;
    const short* B1base = BT1 + ((size_t)b * 512 + h0) * 128;
    const short* B2base = BT2 + ((size_t)b * 512 + h0) * 128;
    #pragma unroll
    for (int kk = 0; kk < 4; kk++) {
        const int k0 = kk * 32;
        bf16x8 af[4], b1[4], b2[4];
        #pragma unroll
        for (int i = 0; i < 4; i++) {
            af[i] = *(const bf16x8*)(Abase  + (size_t)(wr * 64 + i * 16 + fr) * 128 + k0 + fg * 8);
            b1[i] = *(const bf16x8*)(B1base + (size_t)(wc * 64 + i * 16 + fr) * 128 + k0 + fg * 8);
            b2[i] = *(const bf16x8*)(B2base + (size_t)(wc * 64 + i * 16 + fr) * 128 + k0 + fg * 8);
        }
        #pragma unroll
        for (int mi = 0; mi < 4; mi++)
        #pragma unroll
        for (int ni = 0; ni < 4; ni++) {
            acc1[mi][ni] = __builtin_amdgcn_mfma_f32_16x16x32_bf16(af[mi], b1[ni], acc1[mi][ni], 0, 0, 0);
            acc2[mi][ni] = __builtin_amdgcn_mfma_f32_16x16x32_bf16(af[mi], b2[ni], acc2[mi][ni], 0, 0, 0);
        }
    }
    const size_t crow_base = (size_t)b * 1024 + m0;
    #pragma unroll
    for (int mi = 0; mi < 4; mi++)
    #pragma unroll
    for (int r = 0; r < 4; r++) {
        int rowl = wr * 64 + mi * 16 + fg * 4 + r;
        size_t obase = (crow_base + rowl) * 3072 + h0;
        #pragma unroll
        for (int ni = 0; ni < 4; ni++) {
            int col = wc * 64 + ni * 16 + fr;
            float av = acc1[mi][ni][r], bv2 = acc2[mi][ni][r];
            if (WITHC) {
                float cv = Cc[(crow_base + rowl) * 512 + h0 + col];
                out[obase + col]        = cv;
                out[obase + col + 512]  = av;
                out[obase + col + 1024] = cv * av;
                out[obase + col + 1536] = cv * bv2;
            } else {
                out[obase + col + 2048] = bv2;
                out[obase + col + 2560] = av;
            }
        }
    }
}

// ---------------- host launcher ----------------
extern "C" void kernel_launch(void* const* d_in, const int* in_sizes, int n_in,
                              void* d_out, int out_size, void* d_ws, size_t ws_size,
                              hipStream_t stream)
{
    const float* c     = (const float*)d_in[0];
    const float* q     = (const float*)d_in[1];
    const int*   cmask = (const int*)d_in[2];
    const int*   qmask = (const int*)d_in[3];
    const float* cwv   = (const float*)d_in[4];
    const float* qwv   = (const float*)d_in[5];
    const float* cqw   = (const float*)d_in[6];
    const float* bias  = (const float*)d_in[7];
    const float* W1    = (const float*)d_in[8];
    const float* b1    = (const float*)d_in[9];
    const float* W2    = (const float*)d_in[10];
    const float* b2    = (const float*)d_in[11];
    float* out = (float*)d_out;

    char* ws = (char*)d_ws;
    size_t off = 0;
    auto alloc = [&](size_t bytes) -> char* {
        char* p = ws + off;
        off = (off + bytes + 255) & ~(size_t)255;
        return p;
    };
    short* w1th = (short*)alloc(512 * 512 * 2);
    short* w1tl = (short*)alloc(512 * 512 * 2);
    short* w2th = (short*)alloc(512 * 512 * 2);
    short* w2tl = (short*)alloc(512 * 512 * 2);
    short* cqc  = (short*)alloc((size_t)64 * 1024 * 512 * 2);
    short* chi  = (short*)alloc((size_t)64 * 1024 * 512 * 2);
    short* clo  = (short*)alloc((size_t)64 * 1024 * 512 * 2);
    float* s0g  = (float*)alloc(64 * 1024 * 4);
    float* s1p  = (float*)alloc(64 * 4 * 128 * 4);
    short* q_bf = (short*)alloc((size_t)64 * 128 * 512 * 2);
    short* qT   = (short*)alloc((size_t)64 * 512 * 128 * 2);
    float* z1   = (float*)alloc((size_t)8192 * 512 * 4);     // reused for binT/bcoT
    short* qp_h = (short*)alloc((size_t)8192 * 512 * 2);
    short* qp_l = (short*)alloc((size_t)8192 * 512 * 2);
    short* qpT  = (short*)alloc((size_t)64 * 512 * 128 * 2);
    float* simb = (float*)alloc((size_t)64 * 1024 * 128 * 4);
    float2* colpart = (float2*)alloc((size_t)64 * 8 * 128 * 8);
    short* s1s  = (short*)alloc((size_t)64 * 1024 * 128 * 2);
    short* s2sT = (short*)alloc((size_t)64 * 128 * 1024 * 2);
    short* sc1  = (short*)alloc((size_t)64 * 1024 * 128 * 2);
    short* sc2T = (short*)alloc((size_t)64 * 128 * 1024 * 2);
    short* binT = (short*)z1;
    short* bcoT = ((short*)z1) + (size_t)64 * 512 * 128;

    k_prep_w<<<2048, 256, 0, stream>>>(W1, W2, w1th, w1tl, w2th, w2tl);
    k_prep_c<<<4096, 256, 0, stream>>>(c, cqw, cwv, cqc, chi, clo, s0g);
    k_prep_q<<<256, 256, 0, stream>>>(q, qwv, q_bf, qT, s1p);
    k_linear<false><<<256, 256, 0, stream>>>(q, w1th, w1tl, b1, z1, nullptr, nullptr, nullptr);
    k_linear<true><<<256, 256, 0, stream>>>(z1, w2th, w2tl, b2, nullptr, qp_h, qp_l, qpT);

    // sim pipeline (row softmax fused into the GEMM)
    k_att<false, true><<<512, 256, 0, stream>>>(
        cqc, nullptr, q_bf, nullptr, s0g, s1p, bias, qmask, cmask, simb, s1s, colpart);
    k_emit2<<<512, 512, 0, stream>>>(simb, cmask, colpart, s2sT);

    // scoat pipeline (split precision for the sharp softmax)
    k_att<true, false><<<512, 256, 0, stream>>>(
        chi, clo, qp_h, qp_l, nullptr, nullptr, nullptr, qmask, cmask, simb, sc1, colpart);
    k_emit2<<<512, 512, 0, stream>>>(simb, cmask, colpart, sc2T);

    // fused dual K=1024 GEMM (bf16 c, double-buffered staging), transposed outputs
    k_kgemm2<<<256, 256, 0, stream>>>(s2sT, sc2T, chi, binT, bcoT);

    // fused output epilogues
    k_epi<true><<<2048, 256, 0, stream>>>(s1s, qT, binT, c, out);
    k_epi<false><<<2048, 256, 0, stream>>>(sc1, qpT, bcoT, nullptr, out);
}

// Round 4
// 671.425 us; speedup vs baseline: 1.0999x; 1.0999x over previous
//
#include <hip/hip_runtime.h>
#include <cstdint>
#include <cstddef>

typedef short  bf16x8 __attribute__((ext_vector_type(8)));
typedef float  f32x4  __attribute__((ext_vector_type(4)));

#define NEGV (-1e30f)
#define LDT 40   // padded LDS row pitch (shorts) = 80B: 16B-aligned, 2-way-conflict max (free)

__device__ __forceinline__ short f2bf(float x){
    union { float f; unsigned u; } v; v.f = x;
    return (short)((v.u + 0x7fffu + ((v.u >> 16) & 1u)) >> 16);
}
__device__ __forceinline__ float bf2f(short h){
    union { float f; unsigned u; } v; v.u = ((unsigned)(unsigned short)h) << 16; return v.f;
}
__device__ __forceinline__ unsigned packbf(float a, float b){
    return (unsigned)(unsigned short)f2bf(a) | ((unsigned)(unsigned short)f2bf(b) << 16);
}

// ---------------- prep: W1,W2 -> transposed bf16 hi/lo ----------------
__global__ __launch_bounds__(256)
void k_prep_w(const float* __restrict__ W1, const float* __restrict__ W2,
              short* __restrict__ W1Th, short* __restrict__ W1Tl,
              short* __restrict__ W2Th, short* __restrict__ W2Tl)
{
    int idx = blockIdx.x * 256 + threadIdx.x;
    int w = idx >> 18;
    int e = idx & ((1 << 18) - 1);
    int n = e & 511, k = e >> 9;
    const float* W = w ? W2 : W1;
    float x = W[k * 512 + n];
    short hi = f2bf(x);
    short lo = f2bf(x - bf2f(hi));
    size_t o = (size_t)n * 512 + k;
    if (w) { W2Th[o] = hi; W2Tl[o] = lo; } else { W1Th[o] = hi; W1Tl[o] = lo; }
}

// ---------------- prep q: qT (raw, transposed), q_cq = bf16(q*cqw), s1 partials ----------------
__global__ __launch_bounds__(256)
void k_prep_q(const float* __restrict__ q, const float* __restrict__ qwv,
              const float* __restrict__ cqw, short* __restrict__ q_cq,
              short* __restrict__ qT, float* __restrict__ s1p)
{
    __shared__ short TT[128 * 136];
    __shared__ float qws[128], cqs[128];
    const int t = threadIdx.x;
    const int b = (int)(blockIdx.x >> 2), hb = (int)(blockIdx.x & 3), h0 = hb * 128;
    if (t < 128) { qws[t] = qwv[h0 + t]; cqs[t] = cqw[h0 + t]; }
    __syncthreads();
    #pragma unroll
    for (int it = 0; it < 16; it++) {
        int idx = it * 256 + t;
        int m = idx >> 5, c4 = (idx & 31) * 4;
        float4 v = *(const float4*)(q + ((size_t)b * 128 + m) * 512 + h0 + c4);
        TT[(c4 + 0) * 136 + m] = f2bf(v.x);
        TT[(c4 + 1) * 136 + m] = f2bf(v.y);
        TT[(c4 + 2) * 136 + m] = f2bf(v.z);
        TT[(c4 + 3) * 136 + m] = f2bf(v.w);
        uint2 d;
        d.x = packbf(v.x * cqs[c4],     v.y * cqs[c4 + 1]);
        d.y = packbf(v.z * cqs[c4 + 2], v.w * cqs[c4 + 3]);
        *(uint2*)(q_cq + ((size_t)b * 128 + m) * 512 + h0 + c4) = d;
        float dot = v.x * qws[c4] + v.y * qws[c4 + 1] + v.z * qws[c4 + 2] + v.w * qws[c4 + 3];
        #pragma unroll
        for (int off = 1; off < 32; off <<= 1) dot += __shfl_xor(dot, off);
        if ((t & 31) == 0) s1p[((size_t)b * 4 + hb) * 128 + m] = dot;
    }
    __syncthreads();
    const int h = t >> 1, half = t & 1;
    short* dst = qT + ((size_t)b * 512 + h0 + h) * 128 + half * 64;
    #pragma unroll
    for (int j = 0; j < 8; j++)
        *(bf16x8*)(dst + j * 8) = *(const bf16x8*)&TT[h * 136 + half * 64 + j * 8];
}

// ---------------- split-bf16 linear; WT variant writes hi/lo bf16 + transposed copy ----------------
template<bool WT>
__global__ __launch_bounds__(256)
void k_linear(const float* __restrict__ X, const short* __restrict__ WTh,
              const short* __restrict__ WTl, const float* __restrict__ bias,
              float* __restrict__ Y, short* __restrict__ Yh,
              short* __restrict__ Yl, short* __restrict__ YT)
{
    __shared__ __align__(16) short SMEM[4 * 128 * LDT];
    short* Ah = SMEM;
    short* Al = SMEM + 128 * LDT;
    short* Bh = SMEM + 2 * 128 * LDT;
    short* Bl = SMEM + 3 * 128 * LDT;
    const int t = threadIdx.x;
    const int m0 = (int)(blockIdx.x >> 2) * 128;
    const int n0 = (int)(blockIdx.x & 3) * 128;
    const int lane = t & 63;
    const int wr = (t >> 7) & 1, wc = (t >> 6) & 1;
    const int fr = lane & 15, fg = lane >> 4;
    const int srow = t >> 1, sk = (t & 1) * 16;

    f32x4 acc[4][4] = {};

    for (int k0 = 0; k0 < 512; k0 += 32) {
        __syncthreads();
        {
            const float* src = X + (size_t)(m0 + srow) * 512 + k0 + sk;
            float4 f[4];
            #pragma unroll
            for (int i = 0; i < 4; i++) f[i] = ((const float4*)src)[i];
            const float* fv = (const float*)f;
            short hi[16], lo[16];
            #pragma unroll
            for (int j = 0; j < 16; j++) {
                float x = fv[j];
                short h = f2bf(x);
                hi[j] = h; lo[j] = f2bf(x - bf2f(h));
            }
            #pragma unroll
            for (int j = 0; j < 2; j++) {
                *(bf16x8*)&Ah[srow * LDT + sk + j * 8] = *(bf16x8*)&hi[j * 8];
                *(bf16x8*)&Al[srow * LDT + sk + j * 8] = *(bf16x8*)&lo[j * 8];
            }
        }
        {
            const short* sh = WTh + (size_t)(n0 + srow) * 512 + k0 + sk;
            const short* sl = WTl + (size_t)(n0 + srow) * 512 + k0 + sk;
            #pragma unroll
            for (int j = 0; j < 2; j++) {
                *(bf16x8*)&Bh[srow * LDT + sk + j * 8] = ((const bf16x8*)sh)[j];
                *(bf16x8*)&Bl[srow * LDT + sk + j * 8] = ((const bf16x8*)sl)[j];
            }
        }
        __syncthreads();
        bf16x8 a_h[4], a_l[4], b_h[4], b_l[4];
        #pragma unroll
        for (int i = 0; i < 4; i++) {
            int ar = (wr * 64 + i * 16 + fr) * LDT + fg * 8;
            int br = (wc * 64 + i * 16 + fr) * LDT + fg * 8;
            a_h[i] = *(const bf16x8*)&Ah[ar];
            a_l[i] = *(const bf16x8*)&Al[ar];
            b_h[i] = *(const bf16x8*)&Bh[br];
            b_l[i] = *(const bf16x8*)&Bl[br];
        }
        #pragma unroll
        for (int mi = 0; mi < 4; mi++)
        #pragma unroll
        for (int ni = 0; ni < 4; ni++) {
            acc[mi][ni] = __builtin_amdgcn_mfma_f32_16x16x32_bf16(a_h[mi], b_h[ni], acc[mi][ni], 0, 0, 0);
            acc[mi][ni] = __builtin_amdgcn_mfma_f32_16x16x32_bf16(a_h[mi], b_l[ni], acc[mi][ni], 0, 0, 0);
            acc[mi][ni] = __builtin_amdgcn_mfma_f32_16x16x32_bf16(a_l[mi], b_h[ni], acc[mi][ni], 0, 0, 0);
        }
    }
    float bv[4];
    #pragma unroll
    for (int ni = 0; ni < 4; ni++) bv[ni] = bias[n0 + wc * 64 + ni * 16 + fr];

    if (!WT) {
        #pragma unroll
        for (int mi = 0; mi < 4; mi++)
        #pragma unroll
        for (int r = 0; r < 4; r++) {
            int row = m0 + wr * 64 + mi * 16 + fg * 4 + r;
            #pragma unroll
            for (int ni = 0; ni < 4; ni++)
                Y[(size_t)row * 512 + n0 + wc * 64 + ni * 16 + fr] =
                    fmaxf(acc[mi][ni][r] + bv[ni], 0.f);
        }
    } else {
        #pragma unroll
        for (int mi = 0; mi < 4; mi++)
        #pragma unroll
        for (int r = 0; r < 4; r++) {
            int row = m0 + wr * 64 + mi * 16 + fg * 4 + r;
            #pragma unroll
            for (int ni = 0; ni < 4; ni++) {
                float v = fmaxf(acc[mi][ni][r] + bv[ni], 0.f);
                short h = f2bf(v);
                size_t o = (size_t)row * 512 + n0 + wc * 64 + ni * 16 + fr;
                Yh[o] = h;
                Yl[o] = f2bf(v - bf2f(h));
            }
        }
        __syncthreads();
        short* TT = SMEM;
        #pragma unroll
        for (int mi = 0; mi < 4; mi++)
        #pragma unroll
        for (int r = 0; r < 4; r++) {
            int ml = wr * 64 + mi * 16 + fg * 4 + r;
            #pragma unroll
            for (int ni = 0; ni < 4; ni++)
                TT[(wc * 64 + ni * 16 + fr) * 136 + ml] =
                    f2bf(fmaxf(acc[mi][ni][r] + bv[ni], 0.f));
        }
        __syncthreads();
        const int n = t >> 1, half = t & 1;
        short* dst = YT + ((size_t)(m0 >> 7) * 512 + n0 + n) * 128 + half * 64;
        #pragma unroll
        for (int j = 0; j < 8; j++)
            *(bf16x8*)(dst + j * 8) = *(const bf16x8*)&TT[n * 136 + half * 64 + j * 8];
    }
}

// ---------------- logits GEMM + fused row softmax + chunk-local column exp ----------------
// A = c (fp32, converted on the fly; hi/lo if SPLIT), B = pre-staged bf16 (q_cq or qp hi/lo).
// Writes: Pr (row-softmax bf16 [B,1024,128]), Pe (exp(v-M_ch) bf16 TRANSPOSED [B,128,1024]),
// colpart (per-chunk column max/sum).
template<bool SPLIT, bool ADDS>
__global__ __launch_bounds__(256)
void k_att(const float* __restrict__ Cc, const short* __restrict__ Bhg,
           const short* __restrict__ Blg, const float* __restrict__ cwv,
           const float* __restrict__ s1pg, const float* __restrict__ biasp,
           const int* __restrict__ qmask, const int* __restrict__ cmask,
           short* __restrict__ Pr, short* __restrict__ Pe,
           float2* __restrict__ colpart)
{
    __shared__ __align__(16) short SM[4 * 128 * LDT];   // staging; reused as bounce after K-loop
    short* Ah = SM;
    short* Al = SM + 128 * LDT;
    short* Bh = SM + 2 * 128 * LDT;
    short* Bl = SM + 3 * 128 * LDT;
    short* TT = SM;                                     // bounce: 128*136 shorts = 34816 B <= 40960
    __shared__ float red[2][128];
    __shared__ float mrowL[128], rinvL[128], cmaxL[128];
    __shared__ float cws[ADDS ? 512 : 1];
    __shared__ float s0red[ADDS ? 128 : 1][2];
    __shared__ float s0L[ADDS ? 128 : 1], s1L[ADDS ? 128 : 1];
    __shared__ int qmsL[128], cmsL[128];

    const int t = threadIdx.x;
    const int b  = (int)(blockIdx.x & 63);      // 8 chunks of b land on one XCD (bid%8 == b%8)
    const int ch = (int)(blockIdx.x >> 6);
    const int m0 = ch * 128;
    const int lane = t & 63;
    const int wr = (t >> 7) & 1, wc = (t >> 6) & 1;
    const int fr = lane & 15, fg = lane >> 4;
    const int srow = t >> 1, sk = (t & 1) * 16;

    if (ADDS) { cws[t] = cwv[t]; cws[t + 256] = cwv[t + 256]; }
    if (t < 128) {
        qmsL[t] = qmask[b * 128 + t];
        cmsL[t] = cmask[b * 1024 + m0 + t];
        if (ADDS)
            s1L[t] = s1pg[((size_t)b * 4 + 0) * 128 + t] + s1pg[((size_t)b * 4 + 1) * 128 + t]
                   + s1pg[((size_t)b * 4 + 2) * 128 + t] + s1pg[((size_t)b * 4 + 3) * 128 + t];
    }

    const size_t aoff = ((size_t)b * 1024 + m0 + srow) * 512;
    const size_t boff = ((size_t)b * 128 + srow) * 512;
    float s0part = 0.f;
    f32x4 acc[4][4] = {};

    for (int k0 = 0; k0 < 512; k0 += 32) {
        __syncthreads();
        {   // A from c fp32 (convert, optional split, optional s0 dot)
            const float* src = Cc + aoff + k0 + sk;
            float4 f[4];
            #pragma unroll
            for (int i = 0; i < 4; i++) f[i] = ((const float4*)src)[i];
            const float* fv = (const float*)f;
            short hi[16], lo[16];
            #pragma unroll
            for (int j = 0; j < 16; j++) {
                float x = fv[j];
                if (ADDS) s0part += x * cws[k0 + sk + j];
                short h = f2bf(x);
                hi[j] = h;
                if (SPLIT) lo[j] = f2bf(x - bf2f(h));
            }
            #pragma unroll
            for (int j = 0; j < 2; j++) {
                *(bf16x8*)&Ah[srow * LDT + sk + j * 8] = *(bf16x8*)&hi[j * 8];
                if (SPLIT) *(bf16x8*)&Al[srow * LDT + sk + j * 8] = *(bf16x8*)&lo[j * 8];
            }
        }
        {   // B: pure bf16 copies
            *(uint4*)&Bh[srow * LDT + sk]     = *(const uint4*)(Bhg + boff + k0 + sk);
            *(uint4*)&Bh[srow * LDT + sk + 8] = *(const uint4*)(Bhg + boff + k0 + sk + 8);
            if (SPLIT) {
                *(uint4*)&Bl[srow * LDT + sk]     = *(const uint4*)(Blg + boff + k0 + sk);
                *(uint4*)&Bl[srow * LDT + sk + 8] = *(const uint4*)(Blg + boff + k0 + sk + 8);
            }
        }
        __syncthreads();
        bf16x8 a_h[4], b_h[4], a_l[4], b_l[4];
        #pragma unroll
        for (int i = 0; i < 4; i++) {
            int ar = (wr * 64 + i * 16 + fr) * LDT + fg * 8;
            int br = (wc * 64 + i * 16 + fr) * LDT + fg * 8;
            a_h[i] = *(const bf16x8*)&Ah[ar];
            b_h[i] = *(const bf16x8*)&Bh[br];
            if (SPLIT) { a_l[i] = *(const bf16x8*)&Al[ar]; b_l[i] = *(const bf16x8*)&Bl[br]; }
        }
        #pragma unroll
        for (int mi = 0; mi < 4; mi++)
        #pragma unroll
        for (int ni = 0; ni < 4; ni++) {
            acc[mi][ni] = __builtin_amdgcn_mfma_f32_16x16x32_bf16(a_h[mi], b_h[ni], acc[mi][ni], 0, 0, 0);
            if (SPLIT) {
                acc[mi][ni] = __builtin_amdgcn_mfma_f32_16x16x32_bf16(a_h[mi], b_l[ni], acc[mi][ni], 0, 0, 0);
                acc[mi][ni] = __builtin_amdgcn_mfma_f32_16x16x32_bf16(a_l[mi], b_h[ni], acc[mi][ni], 0, 0, 0);
            }
        }
    }

    // ---- s0/s1 finalize + additive terms ----
    if (ADDS) {
        s0red[srow][t & 1] = s0part;
        __syncthreads();
        if (t < 128) s0L[t] = s0red[t][0] + s0red[t][1];
        __syncthreads();
        float b0 = biasp[0];
        #pragma unroll
        for (int mi = 0; mi < 4; mi++)
        #pragma unroll
        for (int r = 0; r < 4; r++) {
            float s0r = s0L[wr * 64 + mi * 16 + fg * 4 + r] + b0;
            #pragma unroll
            for (int ni = 0; ni < 4; ni++)
                acc[mi][ni][r] += s0r + s1L[wc * 64 + ni * 16 + fr];
        }
    }

    bool qmv[4];
    #pragma unroll
    for (int ni = 0; ni < 4; ni++) qmv[ni] = qmsL[wc * 64 + ni * 16 + fr] != 0;
    bool cmb[4][4];
    #pragma unroll
    for (int mi = 0; mi < 4; mi++)
    #pragma unroll
    for (int r = 0; r < 4; r++) cmb[mi][r] = cmsL[wr * 64 + mi * 16 + fg * 4 + r] != 0;

    // ---- row softmax ----
    #pragma unroll
    for (int mi = 0; mi < 4; mi++)
    #pragma unroll
    for (int r = 0; r < 4; r++) {
        float m = NEGV;
        #pragma unroll
        for (int ni = 0; ni < 4; ni++) if (qmv[ni]) m = fmaxf(m, acc[mi][ni][r]);
        #pragma unroll
        for (int off = 1; off < 16; off <<= 1) m = fmaxf(m, __shfl_xor(m, off));
        if (fr == 0) red[wc][wr * 64 + mi * 16 + fg * 4 + r] = m;
    }
    __syncthreads();
    if (t < 128) mrowL[t] = fmaxf(red[0][t], red[1][t]);
    __syncthreads();
    #pragma unroll
    for (int mi = 0; mi < 4; mi++)
    #pragma unroll
    for (int r = 0; r < 4; r++) {
        float mr = mrowL[wr * 64 + mi * 16 + fg * 4 + r];
        float s = 0.f;
        #pragma unroll
        for (int ni = 0; ni < 4; ni++) if (qmv[ni]) s += __expf(acc[mi][ni][r] - mr);
        #pragma unroll
        for (int off = 1; off < 16; off <<= 1) s += __shfl_xor(s, off);
        if (fr == 0) red[wc][wr * 64 + mi * 16 + fg * 4 + r] = s;
    }
    __syncthreads();
    if (t < 128) rinvL[t] = 1.f / (red[0][t] + red[1][t]);
    __syncthreads();
    #pragma unroll
    for (int mi = 0; mi < 4; mi++)
    #pragma unroll
    for (int r = 0; r < 4; r++) {
        int rowl = wr * 64 + mi * 16 + fg * 4 + r;
        float mr = mrowL[rowl], iv = rinvL[rowl];
        size_t obase = ((size_t)b * 1024 + m0 + rowl) * 128;
        #pragma unroll
        for (int ni = 0; ni < 4; ni++) {
            float o = qmv[ni] ? __expf(acc[mi][ni][r] - mr) * iv : 0.f;
            Pr[obase + wc * 64 + ni * 16 + fr] = f2bf(o);
        }
    }

    // ---- column pass: chunk max, then exp(v - M_ch) into bounce (staging LDS is dead) ----
    float cpart[4];
    #pragma unroll
    for (int ni = 0; ni < 4; ni++) {
        float m = NEGV;
        #pragma unroll
        for (int mi = 0; mi < 4; mi++)
        #pragma unroll
        for (int r = 0; r < 4; r++) if (cmb[mi][r]) m = fmaxf(m, acc[mi][ni][r]);
        m = fmaxf(m, __shfl_xor(m, 16));
        m = fmaxf(m, __shfl_xor(m, 32));
        cpart[ni] = m;
    }
    if (fg == 0) {
        #pragma unroll
        for (int ni = 0; ni < 4; ni++) red[wr][wc * 64 + ni * 16 + fr] = cpart[ni];
    }
    __syncthreads();
    if (t < 128) cmaxL[t] = fmaxf(red[0][t], red[1][t]);
    __syncthreads();
    #pragma unroll
    for (int ni = 0; ni < 4; ni++) {
        const int q = wc * 64 + ni * 16 + fr;
        float cm = cmaxL[q];
        float s = 0.f;
        #pragma unroll
        for (int mi = 0; mi < 4; mi++)
        #pragma unroll
        for (int r = 0; r < 4; r++) {
            int rloc = wr * 64 + mi * 16 + fg * 4 + r;
            float e = cmb[mi][r] ? __expf(acc[mi][ni][r] - cm) : 0.f;
            s += e;
            TT[q * 136 + rloc] = f2bf(e);
        }
        s += __shfl_xor(s, 16);
        s += __shfl_xor(s, 32);
        cpart[ni] = s;
    }
    __syncthreads();
    if (fg == 0) {
        #pragma unroll
        for (int ni = 0; ni < 4; ni++) red[wr][wc * 64 + ni * 16 + fr] = cpart[ni];
    }
    __syncthreads();
    {   // coalesced transposed write of the exp-shifted chunk
        const int q2 = t >> 1, half = t & 1;
        short* dst = Pe + ((size_t)b * 128 + q2) * 1024 + m0 + half * 64;
        #pragma unroll
        for (int j = 0; j < 8; j++)
            *(bf16x8*)(dst + j * 8) = *(const bf16x8*)&TT[q2 * 136 + half * 64 + j * 8];
    }
    if (t < 128) colpart[((size_t)b * 8 + ch) * 128 + t] = make_float2(cmaxL[t], red[0][t] + red[1][t]);
}

// ---------------- in-place column-softmax normalization of Pe ----------------
__global__ __launch_bounds__(256)
void k_scale(const float2* __restrict__ colpart, short* __restrict__ P)
{
    __shared__ float fL[128];   // [q_l(16)][ch(8)]
    const int t = threadIdx.x;
    const int b = (int)(blockIdx.x >> 3), qg = (int)(blockIdx.x & 7);
    if (t < 128) {
        const int q_l = t >> 3, ch = t & 7;
        float2 p = colpart[((size_t)b * 8 + ch) * 128 + qg * 16 + q_l];
        float M = p.x;
        #pragma unroll
        for (int off = 1; off < 8; off <<= 1) M = fmaxf(M, __shfl_xor(M, off));
        float w = p.y * __expf(p.x - M);
        #pragma unroll
        for (int off = 1; off < 8; off <<= 1) w += __shfl_xor(w, off);
        fL[q_l * 8 + ch] = (w > 0.f) ? __expf(p.x - M) / w : 0.f;
    }
    __syncthreads();
    const int q_l = t >> 4, rr = (t & 15) * 64;
    const float f = fL[q_l * 8 + (rr >> 7)];
    short* p = P + ((size_t)b * 128 + qg * 16 + q_l) * 1024 + rr;
    #pragma unroll
    for (int j = 0; j < 8; j++) {
        bf16x8 v = *(bf16x8*)(p + j * 8);
        short o[8];
        #pragma unroll
        for (int l = 0; l < 8; l++) o[l] = f2bf(bf2f(v[l]) * f);
        *(bf16x8*)(p + j * 8) = *(bf16x8*)o;
    }
}

// ---------------- fused dual K=1024 GEMM, n-tile 64, reg-prefetch double buffer ----------------
__global__ __launch_bounds__(256)
void k_kgemm2(const short* __restrict__ A1, const short* __restrict__ A2,
              const float* __restrict__ Cc, short* __restrict__ Y1T,
              short* __restrict__ Y2T)
{
    __shared__ __align__(16) short Bs[2][64 * LDT];
    __shared__ __align__(16) short TT[64 * 136];
    const int t = threadIdx.x;
    const int b  = (int)(blockIdx.x & 63);
    const int n0 = (int)(blockIdx.x >> 6) * 64;
    const int lane = t & 63;
    const int w  = t >> 6;
    const int wr = w >> 1, wc = w & 1;
    const int fr = lane & 15, fg = lane >> 4;
    const int n4 = (t & 15) * 4, kk2 = (t >> 4) * 2;

    f32x4 acc1[4][2] = {}, acc2[4][2] = {};

    auto load_e = [&](int k0, float4* e) {
        const float* p = Cc + ((size_t)b * 1024 + k0 + kk2) * 512 + n0 + n4;
        e[0] = *(const float4*)(p);
        e[1] = *(const float4*)(p + 512);
    };
    auto store_b = [&](const float4* e, int buf) {
        const float* p0 = (const float*)&e[0];
        const float* p1 = (const float*)&e[1];
        #pragma unroll
        for (int l = 0; l < 4; l++)
            *(unsigned*)&Bs[buf][(n4 + l) * LDT + kk2] = packbf(p0[l], p1[l]);
    };

    {
        float4 e[2];
        load_e(0, e);
        store_b(e, 0);
    }
    __syncthreads();

    for (int k0 = 0; k0 < 1024; k0 += 32) {
        const int cur = (k0 >> 5) & 1;
        const bool more = (k0 + 32) < 1024;
        float4 e[2];
        if (more) load_e(k0 + 32, e);
        bf16x8 a1[4], a2[4], bg[2];
        #pragma unroll
        for (int i = 0; i < 4; i++) {
            size_t arow = (size_t)(b * 128 + wr * 64 + i * 16 + fr) * 1024 + k0 + fg * 8;
            a1[i] = *(const bf16x8*)(A1 + arow);
            a2[i] = *(const bf16x8*)(A2 + arow);
        }
        #pragma unroll
        for (int i = 0; i < 2; i++)
            bg[i] = *(const bf16x8*)&Bs[cur][(wc * 32 + i * 16 + fr) * LDT + fg * 8];
        #pragma unroll
        for (int mi = 0; mi < 4; mi++)
        #pragma unroll
        for (int ni = 0; ni < 2; ni++) {
            acc1[mi][ni] = __builtin_amdgcn_mfma_f32_16x16x32_bf16(a1[mi], bg[ni], acc1[mi][ni], 0, 0, 0);
            acc2[mi][ni] = __builtin_amdgcn_mfma_f32_16x16x32_bf16(a2[mi], bg[ni], acc2[mi][ni], 0, 0, 0);
        }
        if (more) store_b(e, cur ^ 1);
        __syncthreads();
    }

    // transpose-bounce both outputs -> coalesced [B,512,128] bf16
    const int n_l = t >> 2, qu = t & 3;
    #pragma unroll
    for (int mi = 0; mi < 4; mi++)
    #pragma unroll
    for (int r = 0; r < 4; r++) {
        int ml = wr * 64 + mi * 16 + fg * 4 + r;
        #pragma unroll
        for (int ni = 0; ni < 2; ni++)
            TT[(wc * 32 + ni * 16 + fr) * 136 + ml] = f2bf(acc1[mi][ni][r]);
    }
    __syncthreads();
    {
        short* dst = Y1T + ((size_t)b * 512 + n0 + n_l) * 128 + qu * 32;
        #pragma unroll
        for (int j = 0; j < 4; j++)
            *(bf16x8*)(dst + j * 8) = *(const bf16x8*)&TT[n_l * 136 + qu * 32 + j * 8];
    }
    __syncthreads();
    #pragma unroll
    for (int mi = 0; mi < 4; mi++)
    #pragma unroll
    for (int r = 0; r < 4; r++) {
        int ml = wr * 64 + mi * 16 + fg * 4 + r;
        #pragma unroll
        for (int ni = 0; ni < 2; ni++)
            TT[(wc * 32 + ni * 16 + fr) * 136 + ml] = f2bf(acc2[mi][ni][r]);
    }
    __syncthreads();
    {
        short* dst = Y2T + ((size_t)b * 512 + n0 + n_l) * 128 + qu * 32;
        #pragma unroll
        for (int j = 0; j < 4; j++)
            *(bf16x8*)(dst + j * 8) = *(const bf16x8*)&TT[n_l * 136 + qu * 32 + j * 8];
    }
}

// ---------------- epilogue GEMM (K=128), direct-global fragments, fused output writes ----------------
template<bool WITHC>
__global__ __launch_bounds__(256)
void k_epi(const short* __restrict__ Pm, const short* __restrict__ BT1,
           const short* __restrict__ BT2, const float* __restrict__ Cc,
           float* __restrict__ out)
{
    const int t = threadIdx.x;
    const int hb = (int)(blockIdx.x & 3);
    const int mb = (int)((blockIdx.x >> 2) & 7);
    const int b  = (int)(blockIdx.x >> 5);
    const int m0 = mb * 128, h0 = hb * 128;
    const int lane = t & 63;
    const int wr = (t >> 7) & 1, wc = (t >> 6) & 1;
    const int fr = lane & 15, fg = lane >> 4;
    f32x4 acc1[4][4] = {}, acc2[4][4] = {};
    const short* Abase  = Pm  + ((size_t)b * 1024 + m0) * 128;
    const short* B1base = BT1 + ((size_t)b * 512 + h0) * 128;
    const short* B2base = BT2 + ((size_t)b * 512 + h0) * 128;
    #pragma unroll
    for (int kk = 0; kk < 4; kk++) {
        const int k0 = kk * 32;
        bf16x8 af[4], b1[4], b2[4];
        #pragma unroll
        for (int i = 0; i < 4; i++) {
            af[i] = *(const bf16x8*)(Abase  + (size_t)(wr * 64 + i * 16 + fr) * 128 + k0 + fg * 8);
            b1[i] = *(const bf16x8*)(B1base + (size_t)(wc * 64 + i * 16 + fr) * 128 + k0 + fg * 8);
            b2[i] = *(const bf16x8*)(B2base + (size_t)(wc * 64 + i * 16 + fr) * 128 + k0 + fg * 8);
        }
        #pragma unroll
        for (int mi = 0; mi < 4; mi++)
        #pragma unroll
        for (int ni = 0; ni < 4; ni++) {
            acc1[mi][ni] = __builtin_amdgcn_mfma_f32_16x16x32_bf16(af[mi], b1[ni], acc1[mi][ni], 0, 0, 0);
            acc2[mi][ni] = __builtin_amdgcn_mfma_f32_16x16x32_bf16(af[mi], b2[ni], acc2[mi][ni], 0, 0, 0);
        }
    }
    const size_t crow_base = (size_t)b * 1024 + m0;
    #pragma unroll
    for (int mi = 0; mi < 4; mi++)
    #pragma unroll
    for (int r = 0; r < 4; r++) {
        int rowl = wr * 64 + mi * 16 + fg * 4 + r;
        size_t obase = (crow_base + rowl) * 3072 + h0;
        #pragma unroll
        for (int ni = 0; ni < 4; ni++) {
            int col = wc * 64 + ni * 16 + fr;
            float av = acc1[mi][ni][r], bv2 = acc2[mi][ni][r];
            if (WITHC) {
                float cv = Cc[(crow_base + rowl) * 512 + h0 + col];
                out[obase + col]        = cv;
                out[obase + col + 512]  = av;
                out[obase + col + 1024] = cv * av;
                out[obase + col + 1536] = cv * bv2;
            } else {
                out[obase + col + 2048] = bv2;
                out[obase + col + 2560] = av;
            }
        }
    }
}

// ---------------- host launcher ----------------
extern "C" void kernel_launch(void* const* d_in, const int* in_sizes, int n_in,
                              void* d_out, int out_size, void* d_ws, size_t ws_size,
                              hipStream_t stream)
{
    const float* c     = (const float*)d_in[0];
    const float* q     = (const float*)d_in[1];
    const int*   cmask = (const int*)d_in[2];
    const int*   qmask = (const int*)d_in[3];
    const float* cwv   = (const float*)d_in[4];
    const float* qwv   = (const float*)d_in[5];
    const float* cqw   = (const float*)d_in[6];
    const float* bias  = (const float*)d_in[7];
    const float* W1    = (const float*)d_in[8];
    const float* b1    = (const float*)d_in[9];
    const float* W2    = (const float*)d_in[10];
    const float* b2    = (const float*)d_in[11];
    float* out = (float*)d_out;

    char* ws = (char*)d_ws;
    size_t off = 0;
    auto alloc = [&](size_t bytes) -> char* {
        char* p = ws + off;
        off = (off + bytes + 255) & ~(size_t)255;
        return p;
    };
    short* w1th = (short*)alloc(512 * 512 * 2);
    short* w1tl = (short*)alloc(512 * 512 * 2);
    short* w2th = (short*)alloc(512 * 512 * 2);
    short* w2tl = (short*)alloc(512 * 512 * 2);
    float* s1p  = (float*)alloc(64 * 4 * 128 * 4);
    short* q_cq = (short*)alloc((size_t)64 * 128 * 512 * 2);
    short* qT   = (short*)alloc((size_t)64 * 512 * 128 * 2);
    float* z1   = (float*)alloc((size_t)8192 * 512 * 4);     // layer-1 act; reused for binT/bcoT
    short* qp_h = (short*)alloc((size_t)8192 * 512 * 2);
    short* qp_l = (short*)alloc((size_t)8192 * 512 * 2);
    short* qpT  = (short*)alloc((size_t)64 * 512 * 128 * 2);
    float2* colpartS = (float2*)alloc((size_t)64 * 8 * 128 * 8);
    float2* colpartC = (float2*)alloc((size_t)64 * 8 * 128 * 8);
    short* s1s  = (short*)alloc((size_t)64 * 1024 * 128 * 2);
    short* s2sT = (short*)alloc((size_t)64 * 128 * 1024 * 2);  // e then scaled in place
    short* sc1  = (short*)alloc((size_t)64 * 1024 * 128 * 2);
    short* sc2T = (short*)alloc((size_t)64 * 128 * 1024 * 2);  // e then scaled in place
    short* binT = (short*)z1;
    short* bcoT = ((short*)z1) + (size_t)64 * 512 * 128;

    k_prep_w<<<2048, 256, 0, stream>>>(W1, W2, w1th, w1tl, w2th, w2tl);
    k_prep_q<<<256, 256, 0, stream>>>(q, qwv, cqw, q_cq, qT, s1p);
    k_linear<false><<<256, 256, 0, stream>>>(q, w1th, w1tl, b1, z1, nullptr, nullptr, nullptr);
    k_linear<true><<<256, 256, 0, stream>>>(z1, w2th, w2tl, b2, nullptr, qp_h, qp_l, qpT);

    // sim pipeline
    k_att<false, true><<<512, 256, 0, stream>>>(
        c, q_cq, nullptr, cwv, s1p, bias, qmask, cmask, s1s, s2sT, colpartS);
    k_scale<<<512, 256, 0, stream>>>(colpartS, s2sT);

    // scoat pipeline (split precision for the sharp softmax)
    k_att<true, false><<<512, 256, 0, stream>>>(
        c, qp_h, qp_l, nullptr, nullptr, nullptr, qmask, cmask, sc1, sc2T, colpartC);
    k_scale<<<512, 256, 0, stream>>>(colpartC, sc2T);

    // fused dual K=1024 GEMM (c converted on the fly, 64-wide n-tiles, dbuf)
    k_kgemm2<<<512, 256, 0, stream>>>(s2sT, sc2T, c, binT, bcoT);

    // fused output epilogues
    k_epi<true><<<2048, 256, 0, stream>>>(s1s, qT, binT, c, out);
    k_epi<false><<<2048, 256, 0, stream>>>(sc1, qpT, bcoT, nullptr, out);
}

// Round 5
// 632.829 us; speedup vs baseline: 1.1670x; 1.0610x over previous
//
#include <hip/hip_runtime.h>
#include <cstdint>
#include <cstddef>

typedef short  bf16x8 __attribute__((ext_vector_type(8)));
typedef float  f32x4  __attribute__((ext_vector_type(4)));

#define NEGV (-1e30f)
#define LDT 40   // padded LDS row pitch (shorts) = 80B: 16B-aligned, 2-way-conflict max (free)

__device__ __forceinline__ short f2bf(float x){
    union { float f; unsigned u; } v; v.f = x;
    return (short)((v.u + 0x7fffu + ((v.u >> 16) & 1u)) >> 16);
}
__device__ __forceinline__ float bf2f(short h){
    union { float f; unsigned u; } v; v.u = ((unsigned)(unsigned short)h) << 16; return v.f;
}
__device__ __forceinline__ unsigned packbf(float a, float b){
    return (unsigned)(unsigned short)f2bf(a) | ((unsigned)(unsigned short)f2bf(b) << 16);
}
// memory row (within a 64-row group) holding logical column h:
// epi's B-fragment load at row ni*16+fr then yields logical col fr*4+ni (consecutive per thread)
__device__ __forceinline__ int p64(int x){ return ((x & 3) << 4) | (x >> 2); }

// ---------------- prep: W1,W2 -> transposed bf16 hi/lo ----------------
__global__ __launch_bounds__(256)
void k_prep_w(const float* __restrict__ W1, const float* __restrict__ W2,
              short* __restrict__ W1Th, short* __restrict__ W1Tl,
              short* __restrict__ W2Th, short* __restrict__ W2Tl)
{
    int idx = blockIdx.x * 256 + threadIdx.x;
    int w = idx >> 18;
    int e = idx & ((1 << 18) - 1);
    int n = e & 511, k = e >> 9;
    const float* W = w ? W2 : W1;
    float x = W[k * 512 + n];
    short hi = f2bf(x);
    short lo = f2bf(x - bf2f(hi));
    size_t o = (size_t)n * 512 + k;
    if (w) { W2Th[o] = hi; W2Tl[o] = lo; } else { W1Th[o] = hi; W1Tl[o] = lo; }
}

// ---------------- prep q: qT (raw, transposed, h-permuted), q_cq = bf16(q*cqw), s1 partials ----------------
__global__ __launch_bounds__(256)
void k_prep_q(const float* __restrict__ q, const float* __restrict__ qwv,
              const float* __restrict__ cqw, short* __restrict__ q_cq,
              short* __restrict__ qT, float* __restrict__ s1p)
{
    __shared__ short TT[128 * 136];
    __shared__ float qws[128], cqs[128];
    const int t = threadIdx.x;
    const int b = (int)(blockIdx.x >> 2), hb = (int)(blockIdx.x & 3), h0 = hb * 128;
    if (t < 128) { qws[t] = qwv[h0 + t]; cqs[t] = cqw[h0 + t]; }
    __syncthreads();
    #pragma unroll
    for (int it = 0; it < 16; it++) {
        int idx = it * 256 + t;
        int m = idx >> 5, c4 = (idx & 31) * 4;
        float4 v = *(const float4*)(q + ((size_t)b * 128 + m) * 512 + h0 + c4);
        TT[(c4 + 0) * 136 + m] = f2bf(v.x);
        TT[(c4 + 1) * 136 + m] = f2bf(v.y);
        TT[(c4 + 2) * 136 + m] = f2bf(v.z);
        TT[(c4 + 3) * 136 + m] = f2bf(v.w);
        uint2 d;
        d.x = packbf(v.x * cqs[c4],     v.y * cqs[c4 + 1]);
        d.y = packbf(v.z * cqs[c4 + 2], v.w * cqs[c4 + 3]);
        *(uint2*)(q_cq + ((size_t)b * 128 + m) * 512 + h0 + c4) = d;
        float dot = v.x * qws[c4] + v.y * qws[c4 + 1] + v.z * qws[c4 + 2] + v.w * qws[c4 + 3];
        #pragma unroll
        for (int off = 1; off < 32; off <<= 1) dot += __shfl_xor(dot, off);
        if ((t & 31) == 0) s1p[((size_t)b * 4 + hb) * 128 + m] = dot;
    }
    __syncthreads();
    const int h = t >> 1, half = t & 1;
    const int hm = (h & 64) + p64(h & 63);   // permuted destination row
    short* dst = qT + ((size_t)b * 512 + h0 + hm) * 128 + half * 64;
    #pragma unroll
    for (int j = 0; j < 8; j++)
        *(bf16x8*)(dst + j * 8) = *(const bf16x8*)&TT[h * 136 + half * 64 + j * 8];
}

// ---------------- split-bf16 linear; WT variant writes hi/lo bf16 + transposed (h-permuted) copy ----------------
template<bool WT>
__global__ __launch_bounds__(256)
void k_linear(const float* __restrict__ X, const short* __restrict__ WTh,
              const short* __restrict__ WTl, const float* __restrict__ bias,
              float* __restrict__ Y, short* __restrict__ Yh,
              short* __restrict__ Yl, short* __restrict__ YT)
{
    __shared__ __align__(16) short SMEM[4 * 128 * LDT];
    short* Ah = SMEM;
    short* Al = SMEM + 128 * LDT;
    short* Bh = SMEM + 2 * 128 * LDT;
    short* Bl = SMEM + 3 * 128 * LDT;
    const int t = threadIdx.x;
    const int m0 = (int)(blockIdx.x >> 2) * 128;
    const int n0 = (int)(blockIdx.x & 3) * 128;
    const int lane = t & 63;
    const int wr = (t >> 7) & 1, wc = (t >> 6) & 1;
    const int fr = lane & 15, fg = lane >> 4;
    const int srow = t >> 1, sk = (t & 1) * 16;

    f32x4 acc[4][4] = {};

    for (int k0 = 0; k0 < 512; k0 += 32) {
        __syncthreads();
        {
            const float* src = X + (size_t)(m0 + srow) * 512 + k0 + sk;
            float4 f[4];
            #pragma unroll
            for (int i = 0; i < 4; i++) f[i] = ((const float4*)src)[i];
            const float* fv = (const float*)f;
            short hi[16], lo[16];
            #pragma unroll
            for (int j = 0; j < 16; j++) {
                float x = fv[j];
                short h = f2bf(x);
                hi[j] = h; lo[j] = f2bf(x - bf2f(h));
            }
            #pragma unroll
            for (int j = 0; j < 2; j++) {
                *(bf16x8*)&Ah[srow * LDT + sk + j * 8] = *(bf16x8*)&hi[j * 8];
                *(bf16x8*)&Al[srow * LDT + sk + j * 8] = *(bf16x8*)&lo[j * 8];
            }
        }
        {
            const short* sh = WTh + (size_t)(n0 + srow) * 512 + k0 + sk;
            const short* sl = WTl + (size_t)(n0 + srow) * 512 + k0 + sk;
            #pragma unroll
            for (int j = 0; j < 2; j++) {
                *(bf16x8*)&Bh[srow * LDT + sk + j * 8] = ((const bf16x8*)sh)[j];
                *(bf16x8*)&Bl[srow * LDT + sk + j * 8] = ((const bf16x8*)sl)[j];
            }
        }
        __syncthreads();
        bf16x8 a_h[4], a_l[4], b_h[4], b_l[4];
        #pragma unroll
        for (int i = 0; i < 4; i++) {
            int ar = (wr * 64 + i * 16 + fr) * LDT + fg * 8;
            int br = (wc * 64 + i * 16 + fr) * LDT + fg * 8;
            a_h[i] = *(const bf16x8*)&Ah[ar];
            a_l[i] = *(const bf16x8*)&Al[ar];
            b_h[i] = *(const bf16x8*)&Bh[br];
            b_l[i] = *(const bf16x8*)&Bl[br];
        }
        #pragma unroll
        for (int mi = 0; mi < 4; mi++)
        #pragma unroll
        for (int ni = 0; ni < 4; ni++) {
            acc[mi][ni] = __builtin_amdgcn_mfma_f32_16x16x32_bf16(a_h[mi], b_h[ni], acc[mi][ni], 0, 0, 0);
            acc[mi][ni] = __builtin_amdgcn_mfma_f32_16x16x32_bf16(a_h[mi], b_l[ni], acc[mi][ni], 0, 0, 0);
            acc[mi][ni] = __builtin_amdgcn_mfma_f32_16x16x32_bf16(a_l[mi], b_h[ni], acc[mi][ni], 0, 0, 0);
        }
    }
    float bv[4];
    #pragma unroll
    for (int ni = 0; ni < 4; ni++) bv[ni] = bias[n0 + wc * 64 + ni * 16 + fr];

    if (!WT) {
        #pragma unroll
        for (int mi = 0; mi < 4; mi++)
        #pragma unroll
        for (int r = 0; r < 4; r++) {
            int row = m0 + wr * 64 + mi * 16 + fg * 4 + r;
            #pragma unroll
            for (int ni = 0; ni < 4; ni++)
                Y[(size_t)row * 512 + n0 + wc * 64 + ni * 16 + fr] =
                    fmaxf(acc[mi][ni][r] + bv[ni], 0.f);
        }
    } else {
        #pragma unroll
        for (int mi = 0; mi < 4; mi++)
        #pragma unroll
        for (int r = 0; r < 4; r++) {
            int row = m0 + wr * 64 + mi * 16 + fg * 4 + r;
            #pragma unroll
            for (int ni = 0; ni < 4; ni++) {
                float v = fmaxf(acc[mi][ni][r] + bv[ni], 0.f);
                short h = f2bf(v);
                size_t o = (size_t)row * 512 + n0 + wc * 64 + ni * 16 + fr;
                Yh[o] = h;
                Yl[o] = f2bf(v - bf2f(h));
            }
        }
        __syncthreads();
        short* TT = SMEM;
        #pragma unroll
        for (int mi = 0; mi < 4; mi++)
        #pragma unroll
        for (int r = 0; r < 4; r++) {
            int ml = wr * 64 + mi * 16 + fg * 4 + r;
            #pragma unroll
            for (int ni = 0; ni < 4; ni++)
                TT[(wc * 64 + ni * 16 + fr) * 136 + ml] =
                    f2bf(fmaxf(acc[mi][ni][r] + bv[ni], 0.f));
        }
        __syncthreads();
        const int n = t >> 1, half = t & 1;
        const int nm = (n & 64) + p64(n & 63);   // permuted destination row
        short* dst = YT + ((size_t)(m0 >> 7) * 512 + n0 + nm) * 128 + half * 64;
        #pragma unroll
        for (int j = 0; j < 8; j++)
            *(bf16x8*)(dst + j * 8) = *(const bf16x8*)&TT[n * 136 + half * 64 + j * 8];
    }
}

// ---------------- logits GEMM + fused row softmax + chunk-local column exp ----------------
template<bool SPLIT, bool ADDS>
__global__ __launch_bounds__(256)
void k_att(const float* __restrict__ Cc, const short* __restrict__ Bhg,
           const short* __restrict__ Blg, const float* __restrict__ cwv,
           const float* __restrict__ s1pg, const float* __restrict__ biasp,
           const int* __restrict__ qmask, const int* __restrict__ cmask,
           short* __restrict__ Pr, short* __restrict__ Pe,
           float2* __restrict__ colpart)
{
    __shared__ __align__(16) short SM[4 * 128 * LDT];   // staging; reused as bounce after K-loop
    short* Ah = SM;
    short* Al = SM + 128 * LDT;
    short* Bh = SM + 2 * 128 * LDT;
    short* Bl = SM + 3 * 128 * LDT;
    short* TT = SM;                                     // bounce: 128*136 shorts = 34816 B <= 40960
    __shared__ float red[2][128];
    __shared__ float mrowL[128], rinvL[128], cmaxL[128];
    __shared__ float cws[ADDS ? 512 : 1];
    __shared__ float s0red[ADDS ? 128 : 1][2];
    __shared__ float s0L[ADDS ? 128 : 1], s1L[ADDS ? 128 : 1];
    __shared__ int qmsL[128], cmsL[128];

    const int t = threadIdx.x;
    const int b  = (int)(blockIdx.x & 63);      // 8 chunks of b land on one XCD (bid%8 == b%8)
    const int ch = (int)(blockIdx.x >> 6);
    const int m0 = ch * 128;
    const int lane = t & 63;
    const int wr = (t >> 7) & 1, wc = (t >> 6) & 1;
    const int fr = lane & 15, fg = lane >> 4;
    const int srow = t >> 1, sk = (t & 1) * 16;

    if (ADDS) { cws[t] = cwv[t]; cws[t + 256] = cwv[t + 256]; }
    if (t < 128) {
        qmsL[t] = qmask[b * 128 + t];
        cmsL[t] = cmask[b * 1024 + m0 + t];
        if (ADDS)
            s1L[t] = s1pg[((size_t)b * 4 + 0) * 128 + t] + s1pg[((size_t)b * 4 + 1) * 128 + t]
                   + s1pg[((size_t)b * 4 + 2) * 128 + t] + s1pg[((size_t)b * 4 + 3) * 128 + t];
    }

    const size_t aoff = ((size_t)b * 1024 + m0 + srow) * 512;
    const size_t boff = ((size_t)b * 128 + srow) * 512;
    float s0part = 0.f;
    f32x4 acc[4][4] = {};

    for (int k0 = 0; k0 < 512; k0 += 32) {
        __syncthreads();
        {   // A from c fp32 (convert, optional split, optional s0 dot)
            const float* src = Cc + aoff + k0 + sk;
            float4 f[4];
            #pragma unroll
            for (int i = 0; i < 4; i++) f[i] = ((const float4*)src)[i];
            const float* fv = (const float*)f;
            short hi[16], lo[16];
            #pragma unroll
            for (int j = 0; j < 16; j++) {
                float x = fv[j];
                if (ADDS) s0part += x * cws[k0 + sk + j];
                short h = f2bf(x);
                hi[j] = h;
                if (SPLIT) lo[j] = f2bf(x - bf2f(h));
            }
            #pragma unroll
            for (int j = 0; j < 2; j++) {
                *(bf16x8*)&Ah[srow * LDT + sk + j * 8] = *(bf16x8*)&hi[j * 8];
                if (SPLIT) *(bf16x8*)&Al[srow * LDT + sk + j * 8] = *(bf16x8*)&lo[j * 8];
            }
        }
        {   // B: pure bf16 copies
            *(uint4*)&Bh[srow * LDT + sk]     = *(const uint4*)(Bhg + boff + k0 + sk);
            *(uint4*)&Bh[srow * LDT + sk + 8] = *(const uint4*)(Bhg + boff + k0 + sk + 8);
            if (SPLIT) {
                *(uint4*)&Bl[srow * LDT + sk]     = *(const uint4*)(Blg + boff + k0 + sk);
                *(uint4*)&Bl[srow * LDT + sk + 8] = *(const uint4*)(Blg + boff + k0 + sk + 8);
            }
        }
        __syncthreads();
        bf16x8 a_h[4], b_h[4], a_l[4], b_l[4];
        #pragma unroll
        for (int i = 0; i < 4; i++) {
            int ar = (wr * 64 + i * 16 + fr) * LDT + fg * 8;
            int br = (wc * 64 + i * 16 + fr) * LDT + fg * 8;
            a_h[i] = *(const bf16x8*)&Ah[ar];
            b_h[i] = *(const bf16x8*)&Bh[br];
            if (SPLIT) { a_l[i] = *(const bf16x8*)&Al[ar]; b_l[i] = *(const bf16x8*)&Bl[br]; }
        }
        #pragma unroll
        for (int mi = 0; mi < 4; mi++)
        #pragma unroll
        for (int ni = 0; ni < 4; ni++) {
            acc[mi][ni] = __builtin_amdgcn_mfma_f32_16x16x32_bf16(a_h[mi], b_h[ni], acc[mi][ni], 0, 0, 0);
            if (SPLIT) {
                acc[mi][ni] = __builtin_amdgcn_mfma_f32_16x16x32_bf16(a_h[mi], b_l[ni], acc[mi][ni], 0, 0, 0);
                acc[mi][ni] = __builtin_amdgcn_mfma_f32_16x16x32_bf16(a_l[mi], b_h[ni], acc[mi][ni], 0, 0, 0);
            }
        }
    }

    // ---- s0/s1 finalize + additive terms ----
    if (ADDS) {
        s0red[srow][t & 1] = s0part;
        __syncthreads();
        if (t < 128) s0L[t] = s0red[t][0] + s0red[t][1];
        __syncthreads();
        float b0 = biasp[0];
        #pragma unroll
        for (int mi = 0; mi < 4; mi++)
        #pragma unroll
        for (int r = 0; r < 4; r++) {
            float s0r = s0L[wr * 64 + mi * 16 + fg * 4 + r] + b0;
            #pragma unroll
            for (int ni = 0; ni < 4; ni++)
                acc[mi][ni][r] += s0r + s1L[wc * 64 + ni * 16 + fr];
        }
    }

    bool qmv[4];
    #pragma unroll
    for (int ni = 0; ni < 4; ni++) qmv[ni] = qmsL[wc * 64 + ni * 16 + fr] != 0;
    bool cmb[4][4];
    #pragma unroll
    for (int mi = 0; mi < 4; mi++)
    #pragma unroll
    for (int r = 0; r < 4; r++) cmb[mi][r] = cmsL[wr * 64 + mi * 16 + fg * 4 + r] != 0;

    // ---- row softmax ----
    #pragma unroll
    for (int mi = 0; mi < 4; mi++)
    #pragma unroll
    for (int r = 0; r < 4; r++) {
        float m = NEGV;
        #pragma unroll
        for (int ni = 0; ni < 4; ni++) if (qmv[ni]) m = fmaxf(m, acc[mi][ni][r]);
        #pragma unroll
        for (int off = 1; off < 16; off <<= 1) m = fmaxf(m, __shfl_xor(m, off));
        if (fr == 0) red[wc][wr * 64 + mi * 16 + fg * 4 + r] = m;
    }
    __syncthreads();
    if (t < 128) mrowL[t] = fmaxf(red[0][t], red[1][t]);
    __syncthreads();
    #pragma unroll
    for (int mi = 0; mi < 4; mi++)
    #pragma unroll
    for (int r = 0; r < 4; r++) {
        float mr = mrowL[wr * 64 + mi * 16 + fg * 4 + r];
        float s = 0.f;
        #pragma unroll
        for (int ni = 0; ni < 4; ni++) if (qmv[ni]) s += __expf(acc[mi][ni][r] - mr);
        #pragma unroll
        for (int off = 1; off < 16; off <<= 1) s += __shfl_xor(s, off);
        if (fr == 0) red[wc][wr * 64 + mi * 16 + fg * 4 + r] = s;
    }
    __syncthreads();
    if (t < 128) rinvL[t] = 1.f / (red[0][t] + red[1][t]);
    __syncthreads();
    #pragma unroll
    for (int mi = 0; mi < 4; mi++)
    #pragma unroll
    for (int r = 0; r < 4; r++) {
        int rowl = wr * 64 + mi * 16 + fg * 4 + r;
        float mr = mrowL[rowl], iv = rinvL[rowl];
        size_t obase = ((size_t)b * 1024 + m0 + rowl) * 128;
        #pragma unroll
        for (int ni = 0; ni < 4; ni++) {
            float o = qmv[ni] ? __expf(acc[mi][ni][r] - mr) * iv : 0.f;
            Pr[obase + wc * 64 + ni * 16 + fr] = f2bf(o);
        }
    }

    // ---- column pass: chunk max, then exp(v - M_ch) into bounce (staging LDS is dead) ----
    float cpart[4];
    #pragma unroll
    for (int ni = 0; ni < 4; ni++) {
        float m = NEGV;
        #pragma unroll
        for (int mi = 0; mi < 4; mi++)
        #pragma unroll
        for (int r = 0; r < 4; r++) if (cmb[mi][r]) m = fmaxf(m, acc[mi][ni][r]);
        m = fmaxf(m, __shfl_xor(m, 16));
        m = fmaxf(m, __shfl_xor(m, 32));
        cpart[ni] = m;
    }
    if (fg == 0) {
        #pragma unroll
        for (int ni = 0; ni < 4; ni++) red[wr][wc * 64 + ni * 16 + fr] = cpart[ni];
    }
    __syncthreads();
    if (t < 128) cmaxL[t] = fmaxf(red[0][t], red[1][t]);
    __syncthreads();
    #pragma unroll
    for (int ni = 0; ni < 4; ni++) {
        const int q = wc * 64 + ni * 16 + fr;
        float cm = cmaxL[q];
        float s = 0.f;
        #pragma unroll
        for (int mi = 0; mi < 4; mi++)
        #pragma unroll
        for (int r = 0; r < 4; r++) {
            int rloc = wr * 64 + mi * 16 + fg * 4 + r;
            float e = cmb[mi][r] ? __expf(acc[mi][ni][r] - cm) : 0.f;
            s += e;
            TT[q * 136 + rloc] = f2bf(e);
        }
        s += __shfl_xor(s, 16);
        s += __shfl_xor(s, 32);
        cpart[ni] = s;
    }
    __syncthreads();
    if (fg == 0) {
        #pragma unroll
        for (int ni = 0; ni < 4; ni++) red[wr][wc * 64 + ni * 16 + fr] = cpart[ni];
    }
    __syncthreads();
    {   // coalesced transposed write of the exp-shifted chunk
        const int q2 = t >> 1, half = t & 1;
        short* dst = Pe + ((size_t)b * 128 + q2) * 1024 + m0 + half * 64;
        #pragma unroll
        for (int j = 0; j < 8; j++)
            *(bf16x8*)(dst + j * 8) = *(const bf16x8*)&TT[q2 * 136 + half * 64 + j * 8];
    }
    if (t < 128) colpart[((size_t)b * 8 + ch) * 128 + t] = make_float2(cmaxL[t], red[0][t] + red[1][t]);
}

// ---------------- in-place column-softmax normalization (both pipelines, one launch) ----------------
__global__ __launch_bounds__(256)
void k_scale2(const float2* __restrict__ cpS, const float2* __restrict__ cpC,
              short* __restrict__ PS, short* __restrict__ PC)
{
    __shared__ float fL[128];   // [q_l(16)][ch(8)]
    const int bid = (int)blockIdx.x;
    const float2* colpart = (bid < 512) ? cpS : cpC;
    short* P = (bid < 512) ? PS : PC;
    const int lb = bid & 511;
    const int t = threadIdx.x;
    const int b = lb >> 3, qg = lb & 7;
    if (t < 128) {
        const int q_l = t >> 3, ch = t & 7;
        float2 p = colpart[((size_t)b * 8 + ch) * 128 + qg * 16 + q_l];
        float M = p.x;
        #pragma unroll
        for (int off = 1; off < 8; off <<= 1) M = fmaxf(M, __shfl_xor(M, off));
        float w = p.y * __expf(p.x - M);
        #pragma unroll
        for (int off = 1; off < 8; off <<= 1) w += __shfl_xor(w, off);
        fL[q_l * 8 + ch] = (w > 0.f) ? __expf(p.x - M) / w : 0.f;
    }
    __syncthreads();
    const int q_l = t >> 4, rr = (t & 15) * 64;
    const float f = fL[q_l * 8 + (rr >> 7)];
    short* p = P + ((size_t)b * 128 + qg * 16 + q_l) * 1024 + rr;
    #pragma unroll
    for (int j = 0; j < 8; j++) {
        bf16x8 v = *(bf16x8*)(p + j * 8);
        short o[8];
        #pragma unroll
        for (int l = 0; l < 8; l++) o[l] = f2bf(bf2f(v[l]) * f);
        *(bf16x8*)(p + j * 8) = *(bf16x8*)o;
    }
}

// ---------------- fused dual K=1024 GEMM, n-tile 64, reg-prefetch double buffer ----------------
__global__ __launch_bounds__(256)
void k_kgemm2(const short* __restrict__ A1, const short* __restrict__ A2,
              const float* __restrict__ Cc, short* __restrict__ Y1T,
              short* __restrict__ Y2T)
{
    __shared__ __align__(16) short Bs[2][64 * LDT];
    __shared__ __align__(16) short TT[64 * 136];
    const int t = threadIdx.x;
    const int b  = (int)(blockIdx.x & 63);
    const int n0 = (int)(blockIdx.x >> 6) * 64;
    const int lane = t & 63;
    const int w  = t >> 6;
    const int wr = w >> 1, wc = w & 1;
    const int fr = lane & 15, fg = lane >> 4;
    const int n4 = (t & 15) * 4, kk2 = (t >> 4) * 2;

    f32x4 acc1[4][2] = {}, acc2[4][2] = {};

    auto load_e = [&](int k0, float4* e) {
        const float* p = Cc + ((size_t)b * 1024 + k0 + kk2) * 512 + n0 + n4;
        e[0] = *(const float4*)(p);
        e[1] = *(const float4*)(p + 512);
    };
    auto store_b = [&](const float4* e, int buf) {
        const float* p0 = (const float*)&e[0];
        const float* p1 = (const float*)&e[1];
        #pragma unroll
        for (int l = 0; l < 4; l++)
            *(unsigned*)&Bs[buf][(n4 + l) * LDT + kk2] = packbf(p0[l], p1[l]);
    };

    {
        float4 e[2];
        load_e(0, e);
        store_b(e, 0);
    }
    __syncthreads();

    for (int k0 = 0; k0 < 1024; k0 += 32) {
        const int cur = (k0 >> 5) & 1;
        const bool more = (k0 + 32) < 1024;
        float4 e[2];
        if (more) load_e(k0 + 32, e);
        bf16x8 a1[4], a2[4], bg[2];
        #pragma unroll
        for (int i = 0; i < 4; i++) {
            size_t arow = (size_t)(b * 128 + wr * 64 + i * 16 + fr) * 1024 + k0 + fg * 8;
            a1[i] = *(const bf16x8*)(A1 + arow);
            a2[i] = *(const bf16x8*)(A2 + arow);
        }
        #pragma unroll
        for (int i = 0; i < 2; i++)
            bg[i] = *(const bf16x8*)&Bs[cur][(wc * 32 + i * 16 + fr) * LDT + fg * 8];
        #pragma unroll
        for (int mi = 0; mi < 4; mi++)
        #pragma unroll
        for (int ni = 0; ni < 2; ni++) {
            acc1[mi][ni] = __builtin_amdgcn_mfma_f32_16x16x32_bf16(a1[mi], bg[ni], acc1[mi][ni], 0, 0, 0);
            acc2[mi][ni] = __builtin_amdgcn_mfma_f32_16x16x32_bf16(a2[mi], bg[ni], acc2[mi][ni], 0, 0, 0);
        }
        if (more) store_b(e, cur ^ 1);
        __syncthreads();
    }

    // transpose-bounce both outputs -> coalesced [B,512,128] bf16 (h-permuted rows)
    const int n_l = t >> 2, qu = t & 3;
    const int nm = p64(n_l);
    #pragma unroll
    for (int mi = 0; mi < 4; mi++)
    #pragma unroll
    for (int r = 0; r < 4; r++) {
        int ml = wr * 64 + mi * 16 + fg * 4 + r;
        #pragma unroll
        for (int ni = 0; ni < 2; ni++)
            TT[(wc * 32 + ni * 16 + fr) * 136 + ml] = f2bf(acc1[mi][ni][r]);
    }
    __syncthreads();
    {
        short* dst = Y1T + ((size_t)b * 512 + n0 + nm) * 128 + qu * 32;
        #pragma unroll
        for (int j = 0; j < 4; j++)
            *(bf16x8*)(dst + j * 8) = *(const bf16x8*)&TT[n_l * 136 + qu * 32 + j * 8];
    }
    __syncthreads();
    #pragma unroll
    for (int mi = 0; mi < 4; mi++)
    #pragma unroll
    for (int r = 0; r < 4; r++) {
        int ml = wr * 64 + mi * 16 + fg * 4 + r;
        #pragma unroll
        for (int ni = 0; ni < 2; ni++)
            TT[(wc * 32 + ni * 16 + fr) * 136 + ml] = f2bf(acc2[mi][ni][r]);
    }
    __syncthreads();
    {
        short* dst = Y2T + ((size_t)b * 512 + n0 + nm) * 128 + qu * 32;
        #pragma unroll
        for (int j = 0; j < 4; j++)
            *(bf16x8*)(dst + j * 8) = *(const bf16x8*)&TT[n_l * 136 + qu * 32 + j * 8];
    }
}

// ---------------- epilogue GEMM (K=128), direct-global fragments, float4 fused output writes ----------------
// B-operands are h-permuted: fragment row ni*16+fr holds logical column fr*4+ni,
// so each thread's 4 ni-accumulators are 4 CONSECUTIVE output columns -> float4 stores.
template<bool WITHC>
__global__ __launch_bounds__(256)
void k_epi(const short* __restrict__ Pm, const short* __restrict__ BT1,
           const short* __restrict__ BT2, const float* __restrict__ Cc,
           float* __restrict__ out)
{
    const int t = threadIdx.x;
    const int hb = (int)(blockIdx.x & 3);
    const int mb = (int)((blockIdx.x >> 2) & 7);
    const int b  = (int)(blockIdx.x >> 5);
    const int m0 = mb * 128, h0 = hb * 128;
    const int lane = t & 63;
    const int wr = (t >> 7) & 1, wc = (t >> 6) & 1;
    const int fr = lane & 15, fg = lane >> 4;
    f32x4 acc1[4][4] = {}, acc2[4][4] = {};
    const short* Abase  = Pm  + ((size_t)b * 1024 + m0) * 128;
    const short* B1base = BT1 + ((size_t)b * 512 + h0) * 128;
    const short* B2base = BT2 + ((size_t)b * 512 + h0) * 128;
    #pragma unroll
    for (int kk = 0; kk < 4; kk++) {
        const int k0 = kk * 32;
        bf16x8 af[4], b1[4], b2[4];
        #pragma unroll
        for (int i = 0; i < 4; i++) {
            af[i] = *(const bf16x8*)(Abase  + (size_t)(wr * 64 + i * 16 + fr) * 128 + k0 + fg * 8);
            b1[i] = *(const bf16x8*)(B1base + (size_t)(wc * 64 + i * 16 + fr) * 128 + k0 + fg * 8);
            b2[i] = *(const bf16x8*)(B2base + (size_t)(wc * 64 + i * 16 + fr) * 128 + k0 + fg * 8);
        }
        #pragma unroll
        for (int mi = 0; mi < 4; mi++)
        #pragma unroll
        for (int ni = 0; ni < 4; ni++) {
            acc1[mi][ni] = __builtin_amdgcn_mfma_f32_16x16x32_bf16(af[mi], b1[ni], acc1[mi][ni], 0, 0, 0);
            acc2[mi][ni] = __builtin_amdgcn_mfma_f32_16x16x32_bf16(af[mi], b2[ni], acc2[mi][ni], 0, 0, 0);
        }
    }
    const size_t crow_base = (size_t)b * 1024 + m0;
    const int colb = wc * 64 + fr * 4;       // logical column base (4 consecutive)
    #pragma unroll
    for (int mi = 0; mi < 4; mi++)
    #pragma unroll
    for (int r = 0; r < 4; r++) {
        int rowl = wr * 64 + mi * 16 + fg * 4 + r;
        size_t obase = (crow_base + rowl) * 3072 + h0 + colb;
        float4 av, bv;
        av.x = acc1[mi][0][r]; av.y = acc1[mi][1][r]; av.z = acc1[mi][2][r]; av.w = acc1[mi][3][r];
        bv.x = acc2[mi][0][r]; bv.y = acc2[mi][1][r]; bv.z = acc2[mi][2][r]; bv.w = acc2[mi][3][r];
        if (WITHC) {
            float4 cv = *(const float4*)(Cc + (crow_base + rowl) * 512 + h0 + colb);
            *(float4*)(out + obase) = cv;
            *(float4*)(out + obase + 512) = av;
            float4 ca; ca.x = cv.x * av.x; ca.y = cv.y * av.y; ca.z = cv.z * av.z; ca.w = cv.w * av.w;
            *(float4*)(out + obase + 1024) = ca;
            float4 cb; cb.x = cv.x * bv.x; cb.y = cv.y * bv.y; cb.z = cv.z * bv.z; cb.w = cv.w * bv.w;
            *(float4*)(out + obase + 1536) = cb;
        } else {
            *(float4*)(out + obase + 2048) = bv;
            *(float4*)(out + obase + 2560) = av;
        }
    }
}

// ---------------- host launcher ----------------
extern "C" void kernel_launch(void* const* d_in, const int* in_sizes, int n_in,
                              void* d_out, int out_size, void* d_ws, size_t ws_size,
                              hipStream_t stream)
{
    const float* c     = (const float*)d_in[0];
    const float* q     = (const float*)d_in[1];
    const int*   cmask = (const int*)d_in[2];
    const int*   qmask = (const int*)d_in[3];
    const float* cwv   = (const float*)d_in[4];
    const float* qwv   = (const float*)d_in[5];
    const float* cqw   = (const float*)d_in[6];
    const float* bias  = (const float*)d_in[7];
    const float* W1    = (const float*)d_in[8];
    const float* b1    = (const float*)d_in[9];
    const float* W2    = (const float*)d_in[10];
    const float* b2    = (const float*)d_in[11];
    float* out = (float*)d_out;

    char* ws = (char*)d_ws;
    size_t off = 0;
    auto alloc = [&](size_t bytes) -> char* {
        char* p = ws + off;
        off = (off + bytes + 255) & ~(size_t)255;
        return p;
    };
    short* w1th = (short*)alloc(512 * 512 * 2);
    short* w1tl = (short*)alloc(512 * 512 * 2);
    short* w2th = (short*)alloc(512 * 512 * 2);
    short* w2tl = (short*)alloc(512 * 512 * 2);
    float* s1p  = (float*)alloc(64 * 4 * 128 * 4);
    short* q_cq = (short*)alloc((size_t)64 * 128 * 512 * 2);
    short* qT   = (short*)alloc((size_t)64 * 512 * 128 * 2);
    float* z1   = (float*)alloc((size_t)8192 * 512 * 4);     // layer-1 act; reused for binT/bcoT
    short* qp_h = (short*)alloc((size_t)8192 * 512 * 2);
    short* qp_l = (short*)alloc((size_t)8192 * 512 * 2);
    short* qpT  = (short*)alloc((size_t)64 * 512 * 128 * 2);
    float2* colpartS = (float2*)alloc((size_t)64 * 8 * 128 * 8);
    float2* colpartC = (float2*)alloc((size_t)64 * 8 * 128 * 8);
    short* s1s  = (short*)alloc((size_t)64 * 1024 * 128 * 2);
    short* s2sT = (short*)alloc((size_t)64 * 128 * 1024 * 2);  // e then scaled in place
    short* sc1  = (short*)alloc((size_t)64 * 1024 * 128 * 2);
    short* sc2T = (short*)alloc((size_t)64 * 128 * 1024 * 2);  // e then scaled in place
    short* binT = (short*)z1;
    short* bcoT = ((short*)z1) + (size_t)64 * 512 * 128;

    k_prep_w<<<2048, 256, 0, stream>>>(W1, W2, w1th, w1tl, w2th, w2tl);
    k_prep_q<<<256, 256, 0, stream>>>(q, qwv, cqw, q_cq, qT, s1p);
    k_linear<false><<<256, 256, 0, stream>>>(q, w1th, w1tl, b1, z1, nullptr, nullptr, nullptr);
    k_linear<true><<<256, 256, 0, stream>>>(z1, w2th, w2tl, b2, nullptr, qp_h, qp_l, qpT);

    // sim pipeline
    k_att<false, true><<<512, 256, 0, stream>>>(
        c, q_cq, nullptr, cwv, s1p, bias, qmask, cmask, s1s, s2sT, colpartS);

    // scoat pipeline (split precision for the sharp softmax)
    k_att<true, false><<<512, 256, 0, stream>>>(
        c, qp_h, qp_l, nullptr, nullptr, nullptr, qmask, cmask, sc1, sc2T, colpartC);

    // both column normalizations in one launch
    k_scale2<<<1024, 256, 0, stream>>>(colpartS, colpartC, s2sT, sc2T);

    // fused dual K=1024 GEMM (c converted on the fly, 64-wide n-tiles, dbuf)
    k_kgemm2<<<512, 256, 0, stream>>>(s2sT, sc2T, c, binT, bcoT);

    // fused output epilogues (float4 stores via h-permutation)
    k_epi<true><<<2048, 256, 0, stream>>>(s1s, qT, binT, c, out);
    k_epi<false><<<2048, 256, 0, stream>>>(sc1, qpT, bcoT, nullptr, out);
}

// Round 6
// 589.206 us; speedup vs baseline: 1.2534x; 1.0740x over previous
//
#include <hip/hip_runtime.h>
#include <cstdint>
#include <cstddef>

typedef short    bf16x8 __attribute__((ext_vector_type(8)));
typedef _Float16 f16x8  __attribute__((ext_vector_type(8)));
typedef float    f32x4  __attribute__((ext_vector_type(4)));

#define NEGV (-1e30f)
#define LDT 40   // padded LDS row pitch (shorts) = 80B: 16B-aligned, 2-way-conflict max (free)

__device__ __forceinline__ short f2bf(float x){
    union { float f; unsigned u; } v; v.f = x;
    return (short)((v.u + 0x7fffu + ((v.u >> 16) & 1u)) >> 16);
}
__device__ __forceinline__ float bf2f(short h){
    union { float f; unsigned u; } v; v.u = ((unsigned)(unsigned short)h) << 16; return v.f;
}
__device__ __forceinline__ unsigned packbf(float a, float b){
    return (unsigned)(unsigned short)f2bf(a) | ((unsigned)(unsigned short)f2bf(b) << 16);
}
__device__ __forceinline__ short f2h(float x){
    _Float16 h = (_Float16)x;
    union { _Float16 h; unsigned short u; } v; v.h = h;
    return (short)v.u;
}
// memory row (within a 64-row group) holding logical column h:
// epi's B-fragment load at row ni*16+fr then yields logical col fr*4+ni (consecutive per thread)
__device__ __forceinline__ int p64(int x){ return ((x & 3) << 4) | (x >> 2); }

// ---------------- prep: W1,W2 -> transposed bf16 hi/lo ----------------
__global__ __launch_bounds__(256)
void k_prep_w(const float* __restrict__ W1, const float* __restrict__ W2,
              short* __restrict__ W1Th, short* __restrict__ W1Tl,
              short* __restrict__ W2Th, short* __restrict__ W2Tl)
{
    int idx = blockIdx.x * 256 + threadIdx.x;
    int w = idx >> 18;
    int e = idx & ((1 << 18) - 1);
    int n = e & 511, k = e >> 9;
    const float* W = w ? W2 : W1;
    float x = W[k * 512 + n];
    short hi = f2bf(x);
    short lo = f2bf(x - bf2f(hi));
    size_t o = (size_t)n * 512 + k;
    if (w) { W2Th[o] = hi; W2Tl[o] = lo; } else { W1Th[o] = hi; W1Tl[o] = lo; }
}

// ---------------- prep q: qT (raw, transposed, h-permuted), q_cq = bf16(q*cqw), s1 partials ----------------
__global__ __launch_bounds__(256)
void k_prep_q(const float* __restrict__ q, const float* __restrict__ qwv,
              const float* __restrict__ cqw, short* __restrict__ q_cq,
              short* __restrict__ qT, float* __restrict__ s1p)
{
    __shared__ short TT[128 * 136];
    __shared__ float qws[128], cqs[128];
    const int t = threadIdx.x;
    const int b = (int)(blockIdx.x >> 2), hb = (int)(blockIdx.x & 3), h0 = hb * 128;
    if (t < 128) { qws[t] = qwv[h0 + t]; cqs[t] = cqw[h0 + t]; }
    __syncthreads();
    #pragma unroll
    for (int it = 0; it < 16; it++) {
        int idx = it * 256 + t;
        int m = idx >> 5, c4 = (idx & 31) * 4;
        float4 v = *(const float4*)(q + ((size_t)b * 128 + m) * 512 + h0 + c4);
        TT[(c4 + 0) * 136 + m] = f2bf(v.x);
        TT[(c4 + 1) * 136 + m] = f2bf(v.y);
        TT[(c4 + 2) * 136 + m] = f2bf(v.z);
        TT[(c4 + 3) * 136 + m] = f2bf(v.w);
        uint2 d;
        d.x = packbf(v.x * cqs[c4],     v.y * cqs[c4 + 1]);
        d.y = packbf(v.z * cqs[c4 + 2], v.w * cqs[c4 + 3]);
        *(uint2*)(q_cq + ((size_t)b * 128 + m) * 512 + h0 + c4) = d;
        float dot = v.x * qws[c4] + v.y * qws[c4 + 1] + v.z * qws[c4 + 2] + v.w * qws[c4 + 3];
        #pragma unroll
        for (int off = 1; off < 32; off <<= 1) dot += __shfl_xor(dot, off);
        if ((t & 31) == 0) s1p[((size_t)b * 4 + hb) * 128 + m] = dot;
    }
    __syncthreads();
    const int h = t >> 1, half = t & 1;
    const int hm = (h & 64) + p64(h & 63);   // permuted destination row
    short* dst = qT + ((size_t)b * 512 + h0 + hm) * 128 + half * 64;
    #pragma unroll
    for (int j = 0; j < 8; j++)
        *(bf16x8*)(dst + j * 8) = *(const bf16x8*)&TT[h * 136 + half * 64 + j * 8];
}

// ---------------- split-bf16 linear; WT variant writes fp16 copy + transposed (h-permuted) bf16 copy ----------------
template<bool WT>
__global__ __launch_bounds__(256)
void k_linear(const float* __restrict__ X, const short* __restrict__ WTh,
              const short* __restrict__ WTl, const float* __restrict__ bias,
              float* __restrict__ Y, short* __restrict__ Yf,
              short* __restrict__ YT)
{
    __shared__ __align__(16) short SMEM[4 * 128 * LDT];
    short* Ah = SMEM;
    short* Al = SMEM + 128 * LDT;
    short* Bh = SMEM + 2 * 128 * LDT;
    short* Bl = SMEM + 3 * 128 * LDT;
    const int t = threadIdx.x;
    const int m0 = (int)(blockIdx.x >> 2) * 128;
    const int n0 = (int)(blockIdx.x & 3) * 128;
    const int lane = t & 63;
    const int wr = (t >> 7) & 1, wc = (t >> 6) & 1;
    const int fr = lane & 15, fg = lane >> 4;
    const int srow = t >> 1, sk = (t & 1) * 16;

    f32x4 acc[4][4] = {};

    for (int k0 = 0; k0 < 512; k0 += 32) {
        __syncthreads();
        {
            const float* src = X + (size_t)(m0 + srow) * 512 + k0 + sk;
            float4 f[4];
            #pragma unroll
            for (int i = 0; i < 4; i++) f[i] = ((const float4*)src)[i];
            const float* fv = (const float*)f;
            short hi[16], lo[16];
            #pragma unroll
            for (int j = 0; j < 16; j++) {
                float x = fv[j];
                short h = f2bf(x);
                hi[j] = h; lo[j] = f2bf(x - bf2f(h));
            }
            #pragma unroll
            for (int j = 0; j < 2; j++) {
                *(bf16x8*)&Ah[srow * LDT + sk + j * 8] = *(bf16x8*)&hi[j * 8];
                *(bf16x8*)&Al[srow * LDT + sk + j * 8] = *(bf16x8*)&lo[j * 8];
            }
        }
        {
            const short* sh = WTh + (size_t)(n0 + srow) * 512 + k0 + sk;
            const short* sl = WTl + (size_t)(n0 + srow) * 512 + k0 + sk;
            #pragma unroll
            for (int j = 0; j < 2; j++) {
                *(bf16x8*)&Bh[srow * LDT + sk + j * 8] = ((const bf16x8*)sh)[j];
                *(bf16x8*)&Bl[srow * LDT + sk + j * 8] = ((const bf16x8*)sl)[j];
            }
        }
        __syncthreads();
        bf16x8 a_h[4], a_l[4], b_h[4], b_l[4];
        #pragma unroll
        for (int i = 0; i < 4; i++) {
            int ar = (wr * 64 + i * 16 + fr) * LDT + fg * 8;
            int br = (wc * 64 + i * 16 + fr) * LDT + fg * 8;
            a_h[i] = *(const bf16x8*)&Ah[ar];
            a_l[i] = *(const bf16x8*)&Al[ar];
            b_h[i] = *(const bf16x8*)&Bh[br];
            b_l[i] = *(const bf16x8*)&Bl[br];
        }
        #pragma unroll
        for (int mi = 0; mi < 4; mi++)
        #pragma unroll
        for (int ni = 0; ni < 4; ni++) {
            acc[mi][ni] = __builtin_amdgcn_mfma_f32_16x16x32_bf16(a_h[mi], b_h[ni], acc[mi][ni], 0, 0, 0);
            acc[mi][ni] = __builtin_amdgcn_mfma_f32_16x16x32_bf16(a_h[mi], b_l[ni], acc[mi][ni], 0, 0, 0);
            acc[mi][ni] = __builtin_amdgcn_mfma_f32_16x16x32_bf16(a_l[mi], b_h[ni], acc[mi][ni], 0, 0, 0);
        }
    }
    float bv[4];
    #pragma unroll
    for (int ni = 0; ni < 4; ni++) bv[ni] = bias[n0 + wc * 64 + ni * 16 + fr];

    if (!WT) {
        #pragma unroll
        for (int mi = 0; mi < 4; mi++)
        #pragma unroll
        for (int r = 0; r < 4; r++) {
            int row = m0 + wr * 64 + mi * 16 + fg * 4 + r;
            #pragma unroll
            for (int ni = 0; ni < 4; ni++)
                Y[(size_t)row * 512 + n0 + wc * 64 + ni * 16 + fr] =
                    fmaxf(acc[mi][ni][r] + bv[ni], 0.f);
        }
    } else {
        #pragma unroll
        for (int mi = 0; mi < 4; mi++)
        #pragma unroll
        for (int r = 0; r < 4; r++) {
            int row = m0 + wr * 64 + mi * 16 + fg * 4 + r;
            #pragma unroll
            for (int ni = 0; ni < 4; ni++) {
                float v = fmaxf(acc[mi][ni][r] + bv[ni], 0.f);
                size_t o = (size_t)row * 512 + n0 + wc * 64 + ni * 16 + fr;
                Yf[o] = f2h(v);     // fp16 copy for the scoat logits GEMM
            }
        }
        __syncthreads();
        short* TT = SMEM;
        #pragma unroll
        for (int mi = 0; mi < 4; mi++)
        #pragma unroll
        for (int r = 0; r < 4; r++) {
            int ml = wr * 64 + mi * 16 + fg * 4 + r;
            #pragma unroll
            for (int ni = 0; ni < 4; ni++)
                TT[(wc * 64 + ni * 16 + fr) * 136 + ml] =
                    f2bf(fmaxf(acc[mi][ni][r] + bv[ni], 0.f));
        }
        __syncthreads();
        const int n = t >> 1, half = t & 1;
        const int nm = (n & 64) + p64(n & 63);   // permuted destination row
        short* dst = YT + ((size_t)(m0 >> 7) * 512 + n0 + nm) * 128 + half * 64;
        #pragma unroll
        for (int j = 0; j < 8; j++)
            *(bf16x8*)(dst + j * 8) = *(const bf16x8*)&TT[n * 136 + half * 64 + j * 8];
    }
}

// ---------------- logits GEMM + fused row softmax + chunk-local column exp ----------------
// F16=false (sim): A = c -> bf16, B = q_cq bf16, + s0/s1/bias adds.
// F16=true (scoat): A = c -> fp16, B = qp fp16, single-pass fp16 MFMA (err ~1e-2 logits).
template<bool F16, bool ADDS>
__global__ __launch_bounds__(256)
void k_att(const float* __restrict__ Cc, const short* __restrict__ Bhg,
           const float* __restrict__ cwv, const float* __restrict__ s1pg,
           const float* __restrict__ biasp, const int* __restrict__ qmask,
           const int* __restrict__ cmask, short* __restrict__ Pr,
           short* __restrict__ Pe, float2* __restrict__ colpart)
{
    __shared__ __align__(16) short SM[128 * 136];   // staging (2x 128*LDT=10240) | bounce (17408) -> max
    short* Ah = SM;
    short* Bh = SM + 128 * LDT;
    short* TT = SM;
    __shared__ float red[2][128];
    __shared__ float mrowL[128], rinvL[128], cmaxL[128];
    __shared__ float cws[ADDS ? 512 : 1];
    __shared__ float s0red[ADDS ? 128 : 1][2];
    __shared__ float s0L[ADDS ? 128 : 1], s1L[ADDS ? 128 : 1];
    __shared__ int qmsL[128], cmsL[128];

    const int t = threadIdx.x;
    const int b  = (int)(blockIdx.x & 63);      // 8 chunks of b land on one XCD (bid%8 == b%8)
    const int ch = (int)(blockIdx.x >> 6);
    const int m0 = ch * 128;
    const int lane = t & 63;
    const int wr = (t >> 7) & 1, wc = (t >> 6) & 1;
    const int fr = lane & 15, fg = lane >> 4;
    const int srow = t >> 1, sk = (t & 1) * 16;

    if (ADDS) { cws[t] = cwv[t]; cws[t + 256] = cwv[t + 256]; }
    if (t < 128) {
        qmsL[t] = qmask[b * 128 + t];
        cmsL[t] = cmask[b * 1024 + m0 + t];
        if (ADDS)
            s1L[t] = s1pg[((size_t)b * 4 + 0) * 128 + t] + s1pg[((size_t)b * 4 + 1) * 128 + t]
                   + s1pg[((size_t)b * 4 + 2) * 128 + t] + s1pg[((size_t)b * 4 + 3) * 128 + t];
    }

    const size_t aoff = ((size_t)b * 1024 + m0 + srow) * 512;
    const size_t boff = ((size_t)b * 128 + srow) * 512;
    float s0part = 0.f;
    f32x4 acc[4][4] = {};

    for (int k0 = 0; k0 < 512; k0 += 32) {
        __syncthreads();
        {   // A from c fp32: convert to bf16 or fp16, optional s0 dot
            const float* src = Cc + aoff + k0 + sk;
            float4 f[4];
            #pragma unroll
            for (int i = 0; i < 4; i++) f[i] = ((const float4*)src)[i];
            const float* fv = (const float*)f;
            short hv[16];
            #pragma unroll
            for (int j = 0; j < 16; j++) {
                float x = fv[j];
                if (ADDS) s0part += x * cws[k0 + sk + j];
                hv[j] = F16 ? f2h(x) : f2bf(x);
            }
            #pragma unroll
            for (int j = 0; j < 2; j++)
                *(bf16x8*)&Ah[srow * LDT + sk + j * 8] = *(bf16x8*)&hv[j * 8];
        }
        {   // B: pure 16-bit copies
            *(uint4*)&Bh[srow * LDT + sk]     = *(const uint4*)(Bhg + boff + k0 + sk);
            *(uint4*)&Bh[srow * LDT + sk + 8] = *(const uint4*)(Bhg + boff + k0 + sk + 8);
        }
        __syncthreads();
        #pragma unroll
        for (int i = 0; i < 4; i++) {
            int ar = (wr * 64 + i * 16 + fr) * LDT + fg * 8;
            int br = (wc * 64 + i * 16 + fr) * LDT + fg * 8;
            if (F16) {
                f16x8 a_ = *(const f16x8*)&Ah[ar];
                #pragma unroll
                for (int ni = 0; ni < 4; ni++) {
                    f16x8 b_ = *(const f16x8*)&Bh[(wc * 64 + ni * 16 + fr) * LDT + fg * 8];
                    acc[i][ni] = __builtin_amdgcn_mfma_f32_16x16x32_f16(a_, b_, acc[i][ni], 0, 0, 0);
                }
            } else {
                bf16x8 a_ = *(const bf16x8*)&Ah[ar];
                #pragma unroll
                for (int ni = 0; ni < 4; ni++) {
                    bf16x8 b_ = *(const bf16x8*)&Bh[(wc * 64 + ni * 16 + fr) * LDT + fg * 8];
                    acc[i][ni] = __builtin_amdgcn_mfma_f32_16x16x32_bf16(a_, b_, acc[i][ni], 0, 0, 0);
                }
            }
            (void)br;
        }
    }

    // ---- s0/s1 finalize + additive terms ----
    if (ADDS) {
        s0red[srow][t & 1] = s0part;
        __syncthreads();
        if (t < 128) s0L[t] = s0red[t][0] + s0red[t][1];
        __syncthreads();
        float b0 = biasp[0];
        #pragma unroll
        for (int mi = 0; mi < 4; mi++)
        #pragma unroll
        for (int r = 0; r < 4; r++) {
            float s0r = s0L[wr * 64 + mi * 16 + fg * 4 + r] + b0;
            #pragma unroll
            for (int ni = 0; ni < 4; ni++)
                acc[mi][ni][r] += s0r + s1L[wc * 64 + ni * 16 + fr];
        }
    }

    bool qmv[4];
    #pragma unroll
    for (int ni = 0; ni < 4; ni++) qmv[ni] = qmsL[wc * 64 + ni * 16 + fr] != 0;
    bool cmb[4][4];
    #pragma unroll
    for (int mi = 0; mi < 4; mi++)
    #pragma unroll
    for (int r = 0; r < 4; r++) cmb[mi][r] = cmsL[wr * 64 + mi * 16 + fg * 4 + r] != 0;

    // ---- row softmax ----
    #pragma unroll
    for (int mi = 0; mi < 4; mi++)
    #pragma unroll
    for (int r = 0; r < 4; r++) {
        float m = NEGV;
        #pragma unroll
        for (int ni = 0; ni < 4; ni++) if (qmv[ni]) m = fmaxf(m, acc[mi][ni][r]);
        #pragma unroll
        for (int off = 1; off < 16; off <<= 1) m = fmaxf(m, __shfl_xor(m, off));
        if (fr == 0) red[wc][wr * 64 + mi * 16 + fg * 4 + r] = m;
    }
    __syncthreads();
    if (t < 128) mrowL[t] = fmaxf(red[0][t], red[1][t]);
    __syncthreads();
    #pragma unroll
    for (int mi = 0; mi < 4; mi++)
    #pragma unroll
    for (int r = 0; r < 4; r++) {
        float mr = mrowL[wr * 64 + mi * 16 + fg * 4 + r];
        float s = 0.f;
        #pragma unroll
        for (int ni = 0; ni < 4; ni++) if (qmv[ni]) s += __expf(acc[mi][ni][r] - mr);
        #pragma unroll
        for (int off = 1; off < 16; off <<= 1) s += __shfl_xor(s, off);
        if (fr == 0) red[wc][wr * 64 + mi * 16 + fg * 4 + r] = s;
    }
    __syncthreads();
    if (t < 128) rinvL[t] = 1.f / (red[0][t] + red[1][t]);
    __syncthreads();
    #pragma unroll
    for (int mi = 0; mi < 4; mi++)
    #pragma unroll
    for (int r = 0; r < 4; r++) {
        int rowl = wr * 64 + mi * 16 + fg * 4 + r;
        float mr = mrowL[rowl], iv = rinvL[rowl];
        size_t obase = ((size_t)b * 1024 + m0 + rowl) * 128;
        #pragma unroll
        for (int ni = 0; ni < 4; ni++) {
            float o = qmv[ni] ? __expf(acc[mi][ni][r] - mr) * iv : 0.f;
            Pr[obase + wc * 64 + ni * 16 + fr] = f2bf(o);
        }
    }

    // ---- column pass: chunk max, then exp(v - M_ch) into bounce (staging LDS is dead) ----
    float cpart[4];
    #pragma unroll
    for (int ni = 0; ni < 4; ni++) {
        float m = NEGV;
        #pragma unroll
        for (int mi = 0; mi < 4; mi++)
        #pragma unroll
        for (int r = 0; r < 4; r++) if (cmb[mi][r]) m = fmaxf(m, acc[mi][ni][r]);
        m = fmaxf(m, __shfl_xor(m, 16));
        m = fmaxf(m, __shfl_xor(m, 32));
        cpart[ni] = m;
    }
    if (fg == 0) {
        #pragma unroll
        for (int ni = 0; ni < 4; ni++) red[wr][wc * 64 + ni * 16 + fr] = cpart[ni];
    }
    __syncthreads();
    if (t < 128) cmaxL[t] = fmaxf(red[0][t], red[1][t]);
    __syncthreads();
    #pragma unroll
    for (int ni = 0; ni < 4; ni++) {
        const int q = wc * 64 + ni * 16 + fr;
        float cm = cmaxL[q];
        float s = 0.f;
        #pragma unroll
        for (int mi = 0; mi < 4; mi++)
        #pragma unroll
        for (int r = 0; r < 4; r++) {
            int rloc = wr * 64 + mi * 16 + fg * 4 + r;
            float e = cmb[mi][r] ? __expf(acc[mi][ni][r] - cm) : 0.f;
            s += e;
            TT[q * 136 + rloc] = f2bf(e);
        }
        s += __shfl_xor(s, 16);
        s += __shfl_xor(s, 32);
        cpart[ni] = s;
    }
    __syncthreads();
    if (fg == 0) {
        #pragma unroll
        for (int ni = 0; ni < 4; ni++) red[wr][wc * 64 + ni * 16 + fr] = cpart[ni];
    }
    __syncthreads();
    {   // coalesced transposed write of the exp-shifted chunk
        const int q2 = t >> 1, half = t & 1;
        short* dst = Pe + ((size_t)b * 128 + q2) * 1024 + m0 + half * 64;
        #pragma unroll
        for (int j = 0; j < 8; j++)
            *(bf16x8*)(dst + j * 8) = *(const bf16x8*)&TT[q2 * 136 + half * 64 + j * 8];
    }
    if (t < 128) colpart[((size_t)b * 8 + ch) * 128 + t] = make_float2(cmaxL[t], red[0][t] + red[1][t]);
}

// ---------------- in-place column-softmax normalization (both pipelines, one launch) ----------------
__global__ __launch_bounds__(256)
void k_scale2(const float2* __restrict__ cpS, const float2* __restrict__ cpC,
              short* __restrict__ PS, short* __restrict__ PC)
{
    __shared__ float fL[128];   // [q_l(16)][ch(8)]
    const int bid = (int)blockIdx.x;
    const float2* colpart = (bid < 512) ? cpS : cpC;
    short* P = (bid < 512) ? PS : PC;
    const int lb = bid & 511;
    const int t = threadIdx.x;
    const int b = lb >> 3, qg = lb & 7;
    if (t < 128) {
        const int q_l = t >> 3, ch = t & 7;
        float2 p = colpart[((size_t)b * 8 + ch) * 128 + qg * 16 + q_l];
        float M = p.x;
        #pragma unroll
        for (int off = 1; off < 8; off <<= 1) M = fmaxf(M, __shfl_xor(M, off));
        float w = p.y * __expf(p.x - M);
        #pragma unroll
        for (int off = 1; off < 8; off <<= 1) w += __shfl_xor(w, off);
        fL[q_l * 8 + ch] = (w > 0.f) ? __expf(p.x - M) / w : 0.f;
    }
    __syncthreads();
    const int q_l = t >> 4, rr = (t & 15) * 64;
    const float f = fL[q_l * 8 + (rr >> 7)];
    short* p = P + ((size_t)b * 128 + qg * 16 + q_l) * 1024 + rr;
    #pragma unroll
    for (int j = 0; j < 8; j++) {
        bf16x8 v = *(bf16x8*)(p + j * 8);
        short o[8];
        #pragma unroll
        for (int l = 0; l < 8; l++) o[l] = f2bf(bf2f(v[l]) * f);
        *(bf16x8*)(p + j * 8) = *(bf16x8*)o;
    }
}

// ---------------- fused dual K=1024 GEMM, n-tile 64, reg-prefetch double buffer ----------------
__global__ __launch_bounds__(256)
void k_kgemm2(const short* __restrict__ A1, const short* __restrict__ A2,
              const float* __restrict__ Cc, short* __restrict__ Y1T,
              short* __restrict__ Y2T)
{
    __shared__ __align__(16) short Bs[2][64 * LDT];
    __shared__ __align__(16) short TT[64 * 136];
    const int t = threadIdx.x;
    const int b  = (int)(blockIdx.x & 63);
    const int n0 = (int)(blockIdx.x >> 6) * 64;
    const int lane = t & 63;
    const int w  = t >> 6;
    const int wr = w >> 1, wc = w & 1;
    const int fr = lane & 15, fg = lane >> 4;
    const int n4 = (t & 15) * 4, kk2 = (t >> 4) * 2;

    f32x4 acc1[4][2] = {}, acc2[4][2] = {};

    auto load_e = [&](int k0, float4* e) {
        const float* p = Cc + ((size_t)b * 1024 + k0 + kk2) * 512 + n0 + n4;
        e[0] = *(const float4*)(p);
        e[1] = *(const float4*)(p + 512);
    };
    auto store_b = [&](const float4* e, int buf) {
        const float* p0 = (const float*)&e[0];
        const float* p1 = (const float*)&e[1];
        #pragma unroll
        for (int l = 0; l < 4; l++)
            *(unsigned*)&Bs[buf][(n4 + l) * LDT + kk2] = packbf(p0[l], p1[l]);
    };

    {
        float4 e[2];
        load_e(0, e);
        store_b(e, 0);
    }
    __syncthreads();

    for (int k0 = 0; k0 < 1024; k0 += 32) {
        const int cur = (k0 >> 5) & 1;
        const bool more = (k0 + 32) < 1024;
        float4 e[2];
        if (more) load_e(k0 + 32, e);
        bf16x8 a1[4], a2[4], bg[2];
        #pragma unroll
        for (int i = 0; i < 4; i++) {
            size_t arow = (size_t)(b * 128 + wr * 64 + i * 16 + fr) * 1024 + k0 + fg * 8;
            a1[i] = *(const bf16x8*)(A1 + arow);
            a2[i] = *(const bf16x8*)(A2 + arow);
        }
        #pragma unroll
        for (int i = 0; i < 2; i++)
            bg[i] = *(const bf16x8*)&Bs[cur][(wc * 32 + i * 16 + fr) * LDT + fg * 8];
        #pragma unroll
        for (int mi = 0; mi < 4; mi++)
        #pragma unroll
        for (int ni = 0; ni < 2; ni++) {
            acc1[mi][ni] = __builtin_amdgcn_mfma_f32_16x16x32_bf16(a1[mi], bg[ni], acc1[mi][ni], 0, 0, 0);
            acc2[mi][ni] = __builtin_amdgcn_mfma_f32_16x16x32_bf16(a2[mi], bg[ni], acc2[mi][ni], 0, 0, 0);
        }
        if (more) store_b(e, cur ^ 1);
        __syncthreads();
    }

    // transpose-bounce both outputs -> coalesced [B,512,128] bf16 (h-permuted rows)
    const int n_l = t >> 2, qu = t & 3;
    const int nm = p64(n_l);
    #pragma unroll
    for (int mi = 0; mi < 4; mi++)
    #pragma unroll
    for (int r = 0; r < 4; r++) {
        int ml = wr * 64 + mi * 16 + fg * 4 + r;
        #pragma unroll
        for (int ni = 0; ni < 2; ni++)
            TT[(wc * 32 + ni * 16 + fr) * 136 + ml] = f2bf(acc1[mi][ni][r]);
    }
    __syncthreads();
    {
        short* dst = Y1T + ((size_t)b * 512 + n0 + nm) * 128 + qu * 32;
        #pragma unroll
        for (int j = 0; j < 4; j++)
            *(bf16x8*)(dst + j * 8) = *(const bf16x8*)&TT[n_l * 136 + qu * 32 + j * 8];
    }
    __syncthreads();
    #pragma unroll
    for (int mi = 0; mi < 4; mi++)
    #pragma unroll
    for (int r = 0; r < 4; r++) {
        int ml = wr * 64 + mi * 16 + fg * 4 + r;
        #pragma unroll
        for (int ni = 0; ni < 2; ni++)
            TT[(wc * 32 + ni * 16 + fr) * 136 + ml] = f2bf(acc2[mi][ni][r]);
    }
    __syncthreads();
    {
        short* dst = Y2T + ((size_t)b * 512 + n0 + nm) * 128 + qu * 32;
        #pragma unroll
        for (int j = 0; j < 4; j++)
            *(bf16x8*)(dst + j * 8) = *(const bf16x8*)&TT[n_l * 136 + qu * 32 + j * 8];
    }
}

// ---------------- epilogue GEMM (K=128), direct-global fragments, float4 fused output writes ----------------
template<bool WITHC>
__global__ __launch_bounds__(256)
void k_epi(const short* __restrict__ Pm, const short* __restrict__ BT1,
           const short* __restrict__ BT2, const float* __restrict__ Cc,
           float* __restrict__ out)
{
    const int t = threadIdx.x;
    const int hb = (int)(blockIdx.x & 3);
    const int mb = (int)((blockIdx.x >> 2) & 7);
    const int b  = (int)(blockIdx.x >> 5);
    const int m0 = mb * 128, h0 = hb * 128;
    const int lane = t & 63;
    const int wr = (t >> 7) & 1, wc = (t >> 6) & 1;
    const int fr = lane & 15, fg = lane >> 4;
    f32x4 acc1[4][4] = {}, acc2[4][4] = {};
    const short* Abase  = Pm  + ((size_t)b * 1024 + m0) * 128;
    const short* B1base = BT1 + ((size_t)b * 512 + h0) * 128;
    const short* B2base = BT2 + ((size_t)b * 512 + h0) * 128;
    #pragma unroll
    for (int kk = 0; kk < 4; kk++) {
        const int k0 = kk * 32;
        bf16x8 af[4], b1[4], b2[4];
        #pragma unroll
        for (int i = 0; i < 4; i++) {
            af[i] = *(const bf16x8*)(Abase  + (size_t)(wr * 64 + i * 16 + fr) * 128 + k0 + fg * 8);
            b1[i] = *(const bf16x8*)(B1base + (size_t)(wc * 64 + i * 16 + fr) * 128 + k0 + fg * 8);
            b2[i] = *(const bf16x8*)(B2base + (size_t)(wc * 64 + i * 16 + fr) * 128 + k0 + fg * 8);
        }
        #pragma unroll
        for (int mi = 0; mi < 4; mi++)
        #pragma unroll
        for (int ni = 0; ni < 4; ni++) {
            acc1[mi][ni] = __builtin_amdgcn_mfma_f32_16x16x32_bf16(af[mi], b1[ni], acc1[mi][ni], 0, 0, 0);
            acc2[mi][ni] = __builtin_amdgcn_mfma_f32_16x16x32_bf16(af[mi], b2[ni], acc2[mi][ni], 0, 0, 0);
        }
    }
    const size_t crow_base = (size_t)b * 1024 + m0;
    const int colb = wc * 64 + fr * 4;       // logical column base (4 consecutive)
    #pragma unroll
    for (int mi = 0; mi < 4; mi++)
    #pragma unroll
    for (int r = 0; r < 4; r++) {
        int rowl = wr * 64 + mi * 16 + fg * 4 + r;
        size_t obase = (crow_base + rowl) * 3072 + h0 + colb;
        float4 av, bv;
        av.x = acc1[mi][0][r]; av.y = acc1[mi][1][r]; av.z = acc1[mi][2][r]; av.w = acc1[mi][3][r];
        bv.x = acc2[mi][0][r]; bv.y = acc2[mi][1][r]; bv.z = acc2[mi][2][r]; bv.w = acc2[mi][3][r];
        if (WITHC) {
            float4 cv = *(const float4*)(Cc + (crow_base + rowl) * 512 + h0 + colb);
            *(float4*)(out + obase) = cv;
            *(float4*)(out + obase + 512) = av;
            float4 ca; ca.x = cv.x * av.x; ca.y = cv.y * av.y; ca.z = cv.z * av.z; ca.w = cv.w * av.w;
            *(float4*)(out + obase + 1024) = ca;
            float4 cb; cb.x = cv.x * bv.x; cb.y = cv.y * bv.y; cb.z = cv.z * bv.z; cb.w = cv.w * bv.w;
            *(float4*)(out + obase + 1536) = cb;
        } else {
            *(float4*)(out + obase + 2048) = bv;
            *(float4*)(out + obase + 2560) = av;
        }
    }
}

// ---------------- host launcher ----------------
extern "C" void kernel_launch(void* const* d_in, const int* in_sizes, int n_in,
                              void* d_out, int out_size, void* d_ws, size_t ws_size,
                              hipStream_t stream)
{
    const float* c     = (const float*)d_in[0];
    const float* q     = (const float*)d_in[1];
    const int*   cmask = (const int*)d_in[2];
    const int*   qmask = (const int*)d_in[3];
    const float* cwv   = (const float*)d_in[4];
    const float* qwv   = (const float*)d_in[5];
    const float* cqw   = (const float*)d_in[6];
    const float* bias  = (const float*)d_in[7];
    const float* W1    = (const float*)d_in[8];
    const float* b1    = (const float*)d_in[9];
    const float* W2    = (const float*)d_in[10];
    const float* b2    = (const float*)d_in[11];
    float* out = (float*)d_out;

    char* ws = (char*)d_ws;
    size_t off = 0;
    auto alloc = [&](size_t bytes) -> char* {
        char* p = ws + off;
        off = (off + bytes + 255) & ~(size_t)255;
        return p;
    };
    short* w1th = (short*)alloc(512 * 512 * 2);
    short* w1tl = (short*)alloc(512 * 512 * 2);
    short* w2th = (short*)alloc(512 * 512 * 2);
    short* w2tl = (short*)alloc(512 * 512 * 2);
    float* s1p  = (float*)alloc(64 * 4 * 128 * 4);
    short* q_cq = (short*)alloc((size_t)64 * 128 * 512 * 2);
    short* qT   = (short*)alloc((size_t)64 * 512 * 128 * 2);
    float* z1   = (float*)alloc((size_t)8192 * 512 * 4);     // layer-1 act; reused for binT/bcoT
    short* qp_f = (short*)alloc((size_t)8192 * 512 * 2);     // fp16 qp
    short* qpT  = (short*)alloc((size_t)64 * 512 * 128 * 2);
    float2* colpartS = (float2*)alloc((size_t)64 * 8 * 128 * 8);
    float2* colpartC = (float2*)alloc((size_t)64 * 8 * 128 * 8);
    short* s1s  = (short*)alloc((size_t)64 * 1024 * 128 * 2);
    short* s2sT = (short*)alloc((size_t)64 * 128 * 1024 * 2);  // e then scaled in place
    short* sc1  = (short*)alloc((size_t)64 * 1024 * 128 * 2);
    short* sc2T = (short*)alloc((size_t)64 * 128 * 1024 * 2);  // e then scaled in place
    short* binT = (short*)z1;
    short* bcoT = ((short*)z1) + (size_t)64 * 512 * 128;

    k_prep_w<<<2048, 256, 0, stream>>>(W1, W2, w1th, w1tl, w2th, w2tl);
    k_prep_q<<<256, 256, 0, stream>>>(q, qwv, cqw, q_cq, qT, s1p);
    k_linear<false><<<256, 256, 0, stream>>>(q, w1th, w1tl, b1, z1, nullptr, nullptr);
    k_linear<true><<<256, 256, 0, stream>>>(z1, w2th, w2tl, b2, nullptr, qp_f, qpT);

    // sim pipeline (bf16, with additive terms)
    k_att<false, true><<<512, 256, 0, stream>>>(
        c, q_cq, cwv, s1p, bias, qmask, cmask, s1s, s2sT, colpartS);

    // scoat pipeline (single-pass fp16 for the sharp softmax)
    k_att<true, false><<<512, 256, 0, stream>>>(
        c, qp_f, nullptr, nullptr, nullptr, qmask, cmask, sc1, sc2T, colpartC);

    // both column normalizations in one launch
    k_scale2<<<1024, 256, 0, stream>>>(colpartS, colpartC, s2sT, sc2T);

    // fused dual K=1024 GEMM (c converted on the fly, 64-wide n-tiles, dbuf)
    k_kgemm2<<<512, 256, 0, stream>>>(s2sT, sc2T, c, binT, bcoT);

    // fused output epilogues (float4 stores via h-permutation)
    k_epi<true><<<2048, 256, 0, stream>>>(s1s, qT, binT, c, out);
    k_epi<false><<<2048, 256, 0, stream>>>(sc1, qpT, bcoT, nullptr, out);
}

// Round 7
// 571.446 us; speedup vs baseline: 1.2924x; 1.0311x over previous
//
#include <hip/hip_runtime.h>
#include <cstdint>
#include <cstddef>

typedef short    bf16x8 __attribute__((ext_vector_type(8)));
typedef _Float16 f16x8  __attribute__((ext_vector_type(8)));
typedef float    f32x4  __attribute__((ext_vector_type(4)));

#define NEGV (-1e30f)
#define LDT 40   // padded LDS row pitch (shorts) = 80B: 16B-aligned, 2-way-conflict max (free)

__device__ __forceinline__ short f2bf(float x){
    union { float f; unsigned u; } v; v.f = x;
    return (short)((v.u + 0x7fffu + ((v.u >> 16) & 1u)) >> 16);
}
__device__ __forceinline__ float bf2f(short h){
    union { float f; unsigned u; } v; v.u = ((unsigned)(unsigned short)h) << 16; return v.f;
}
__device__ __forceinline__ short f2h(float x){
    _Float16 h = (_Float16)x;
    union { _Float16 h; unsigned short u; } v; v.h = h;
    return (short)v.u;
}
__device__ __forceinline__ unsigned packh(float a, float b){
    return (unsigned)(unsigned short)f2h(a) | ((unsigned)(unsigned short)f2h(b) << 16);
}
// memory row (within a 64-row group) holding logical column h:
// epi's B-fragment load at row ni*16+fr then yields logical col fr*4+ni (consecutive per thread)
__device__ __forceinline__ int p64(int x){ return ((x & 3) << 4) | (x >> 2); }

// ---------------- prep: W1,W2 -> transposed bf16 hi/lo (MLP stays split-bf16) ----------------
__global__ __launch_bounds__(256)
void k_prep_w(const float* __restrict__ W1, const float* __restrict__ W2,
              short* __restrict__ W1Th, short* __restrict__ W1Tl,
              short* __restrict__ W2Th, short* __restrict__ W2Tl)
{
    int idx = blockIdx.x * 256 + threadIdx.x;
    int w = idx >> 18;
    int e = idx & ((1 << 18) - 1);
    int n = e & 511, k = e >> 9;
    const float* W = w ? W2 : W1;
    float x = W[k * 512 + n];
    short hi = f2bf(x);
    short lo = f2bf(x - bf2f(hi));
    size_t o = (size_t)n * 512 + k;
    if (w) { W2Th[o] = hi; W2Tl[o] = lo; } else { W1Th[o] = hi; W1Tl[o] = lo; }
}

// ---------------- prep q: qT (fp16, transposed, h-permuted), q_cq = f16(q*cqw), s1 partials ----------------
__global__ __launch_bounds__(256)
void k_prep_q(const float* __restrict__ q, const float* __restrict__ qwv,
              const float* __restrict__ cqw, short* __restrict__ q_cq,
              short* __restrict__ qT, float* __restrict__ s1p)
{
    __shared__ short TT[128 * 136];
    __shared__ float qws[128], cqs[128];
    const int t = threadIdx.x;
    const int b = (int)(blockIdx.x >> 2), hb = (int)(blockIdx.x & 3), h0 = hb * 128;
    if (t < 128) { qws[t] = qwv[h0 + t]; cqs[t] = cqw[h0 + t]; }
    __syncthreads();
    #pragma unroll
    for (int it = 0; it < 16; it++) {
        int idx = it * 256 + t;
        int m = idx >> 5, c4 = (idx & 31) * 4;
        float4 v = *(const float4*)(q + ((size_t)b * 128 + m) * 512 + h0 + c4);
        TT[(c4 + 0) * 136 + m] = f2h(v.x);
        TT[(c4 + 1) * 136 + m] = f2h(v.y);
        TT[(c4 + 2) * 136 + m] = f2h(v.z);
        TT[(c4 + 3) * 136 + m] = f2h(v.w);
        uint2 d;
        d.x = packh(v.x * cqs[c4],     v.y * cqs[c4 + 1]);
        d.y = packh(v.z * cqs[c4 + 2], v.w * cqs[c4 + 3]);
        *(uint2*)(q_cq + ((size_t)b * 128 + m) * 512 + h0 + c4) = d;
        float dot = v.x * qws[c4] + v.y * qws[c4 + 1] + v.z * qws[c4 + 2] + v.w * qws[c4 + 3];
        #pragma unroll
        for (int off = 1; off < 32; off <<= 1) dot += __shfl_xor(dot, off);
        if ((t & 31) == 0) s1p[((size_t)b * 4 + hb) * 128 + m] = dot;
    }
    __syncthreads();
    const int h = t >> 1, half = t & 1;
    const int hm = (h & 64) + p64(h & 63);   // permuted destination row
    short* dst = qT + ((size_t)b * 512 + h0 + hm) * 128 + half * 64;
    #pragma unroll
    for (int j = 0; j < 8; j++)
        *(bf16x8*)(dst + j * 8) = *(const bf16x8*)&TT[h * 136 + half * 64 + j * 8];
}

// ---------------- split-bf16 linear; WT variant writes fp16 copy + transposed (h-permuted) fp16 copy ----------------
template<bool WT>
__global__ __launch_bounds__(256)
void k_linear(const float* __restrict__ X, const short* __restrict__ WTh,
              const short* __restrict__ WTl, const float* __restrict__ bias,
              float* __restrict__ Y, short* __restrict__ Yf,
              short* __restrict__ YT)
{
    __shared__ __align__(16) short SMEM[4 * 128 * LDT];
    short* Ah = SMEM;
    short* Al = SMEM + 128 * LDT;
    short* Bh = SMEM + 2 * 128 * LDT;
    short* Bl = SMEM + 3 * 128 * LDT;
    const int t = threadIdx.x;
    const int m0 = (int)(blockIdx.x >> 2) * 128;
    const int n0 = (int)(blockIdx.x & 3) * 128;
    const int lane = t & 63;
    const int wr = (t >> 7) & 1, wc = (t >> 6) & 1;
    const int fr = lane & 15, fg = lane >> 4;
    const int srow = t >> 1, sk = (t & 1) * 16;

    f32x4 acc[4][4] = {};

    for (int k0 = 0; k0 < 512; k0 += 32) {
        __syncthreads();
        {
            const float* src = X + (size_t)(m0 + srow) * 512 + k0 + sk;
            float4 f[4];
            #pragma unroll
            for (int i = 0; i < 4; i++) f[i] = ((const float4*)src)[i];
            const float* fv = (const float*)f;
            short hi[16], lo[16];
            #pragma unroll
            for (int j = 0; j < 16; j++) {
                float x = fv[j];
                short h = f2bf(x);
                hi[j] = h; lo[j] = f2bf(x - bf2f(h));
            }
            #pragma unroll
            for (int j = 0; j < 2; j++) {
                *(bf16x8*)&Ah[srow * LDT + sk + j * 8] = *(bf16x8*)&hi[j * 8];
                *(bf16x8*)&Al[srow * LDT + sk + j * 8] = *(bf16x8*)&lo[j * 8];
            }
        }
        {
            const short* sh = WTh + (size_t)(n0 + srow) * 512 + k0 + sk;
            const short* sl = WTl + (size_t)(n0 + srow) * 512 + k0 + sk;
            #pragma unroll
            for (int j = 0; j < 2; j++) {
                *(bf16x8*)&Bh[srow * LDT + sk + j * 8] = ((const bf16x8*)sh)[j];
                *(bf16x8*)&Bl[srow * LDT + sk + j * 8] = ((const bf16x8*)sl)[j];
            }
        }
        __syncthreads();
        bf16x8 a_h[4], a_l[4], b_h[4], b_l[4];
        #pragma unroll
        for (int i = 0; i < 4; i++) {
            int ar = (wr * 64 + i * 16 + fr) * LDT + fg * 8;
            int br = (wc * 64 + i * 16 + fr) * LDT + fg * 8;
            a_h[i] = *(const bf16x8*)&Ah[ar];
            a_l[i] = *(const bf16x8*)&Al[ar];
            b_h[i] = *(const bf16x8*)&Bh[br];
            b_l[i] = *(const bf16x8*)&Bl[br];
        }
        #pragma unroll
        for (int mi = 0; mi < 4; mi++)
        #pragma unroll
        for (int ni = 0; ni < 4; ni++) {
            acc[mi][ni] = __builtin_amdgcn_mfma_f32_16x16x32_bf16(a_h[mi], b_h[ni], acc[mi][ni], 0, 0, 0);
            acc[mi][ni] = __builtin_amdgcn_mfma_f32_16x16x32_bf16(a_h[mi], b_l[ni], acc[mi][ni], 0, 0, 0);
            acc[mi][ni] = __builtin_amdgcn_mfma_f32_16x16x32_bf16(a_l[mi], b_h[ni], acc[mi][ni], 0, 0, 0);
        }
    }
    float bv[4];
    #pragma unroll
    for (int ni = 0; ni < 4; ni++) bv[ni] = bias[n0 + wc * 64 + ni * 16 + fr];

    if (!WT) {
        #pragma unroll
        for (int mi = 0; mi < 4; mi++)
        #pragma unroll
        for (int r = 0; r < 4; r++) {
            int row = m0 + wr * 64 + mi * 16 + fg * 4 + r;
            #pragma unroll
            for (int ni = 0; ni < 4; ni++)
                Y[(size_t)row * 512 + n0 + wc * 64 + ni * 16 + fr] =
                    fmaxf(acc[mi][ni][r] + bv[ni], 0.f);
        }
    } else {
        #pragma unroll
        for (int mi = 0; mi < 4; mi++)
        #pragma unroll
        for (int r = 0; r < 4; r++) {
            int row = m0 + wr * 64 + mi * 16 + fg * 4 + r;
            #pragma unroll
            for (int ni = 0; ni < 4; ni++) {
                float v = fmaxf(acc[mi][ni][r] + bv[ni], 0.f);
                size_t o = (size_t)row * 512 + n0 + wc * 64 + ni * 16 + fr;
                Yf[o] = f2h(v);     // fp16 copy for the scoat logits GEMM
            }
        }
        __syncthreads();
        short* TT = SMEM;
        #pragma unroll
        for (int mi = 0; mi < 4; mi++)
        #pragma unroll
        for (int r = 0; r < 4; r++) {
            int ml = wr * 64 + mi * 16 + fg * 4 + r;
            #pragma unroll
            for (int ni = 0; ni < 4; ni++)
                TT[(wc * 64 + ni * 16 + fr) * 136 + ml] =
                    f2h(fmaxf(acc[mi][ni][r] + bv[ni], 0.f));
        }
        __syncthreads();
        const int n = t >> 1, half = t & 1;
        const int nm = (n & 64) + p64(n & 63);   // permuted destination row
        short* dst = YT + ((size_t)(m0 >> 7) * 512 + n0 + nm) * 128 + half * 64;
        #pragma unroll
        for (int j = 0; j < 8; j++)
            *(bf16x8*)(dst + j * 8) = *(const bf16x8*)&TT[n * 136 + half * 64 + j * 8];
    }
}

// ---------------- logits GEMM (fp16) + fused row softmax + chunk-local column exp ----------------
// A = c fp32 -> fp16 on the fly (v_cvt, cheap); B = pre-staged fp16 (q_cq or qp).
template<bool ADDS>
__global__ __launch_bounds__(256)
void k_att(const float* __restrict__ Cc, const short* __restrict__ Bhg,
           const float* __restrict__ cwv, const float* __restrict__ s1pg,
           const float* __restrict__ biasp, const int* __restrict__ qmask,
           const int* __restrict__ cmask, short* __restrict__ Pr,
           short* __restrict__ Pe, float2* __restrict__ colpart)
{
    __shared__ __align__(16) short SM[128 * 136];   // staging (2x 128*LDT=10240) | bounce (17408)
    short* Ah = SM;
    short* Bh = SM + 128 * LDT;
    short* TT = SM;
    __shared__ float red[2][128];
    __shared__ float mrowL[128], rinvL[128], cmaxL[128];
    __shared__ float cws[ADDS ? 512 : 1];
    __shared__ float s0red[ADDS ? 128 : 1][2];
    __shared__ float s0L[ADDS ? 128 : 1], s1L[ADDS ? 128 : 1];
    __shared__ int qmsL[128], cmsL[128];

    const int t = threadIdx.x;
    const int b  = (int)(blockIdx.x & 63);      // 8 chunks of b land on one XCD (bid%8 == b%8)
    const int ch = (int)(blockIdx.x >> 6);
    const int m0 = ch * 128;
    const int lane = t & 63;
    const int wr = (t >> 7) & 1, wc = (t >> 6) & 1;
    const int fr = lane & 15, fg = lane >> 4;
    const int srow = t >> 1, sk = (t & 1) * 16;

    if (ADDS) { cws[t] = cwv[t]; cws[t + 256] = cwv[t + 256]; }
    if (t < 128) {
        qmsL[t] = qmask[b * 128 + t];
        cmsL[t] = cmask[b * 1024 + m0 + t];
        if (ADDS)
            s1L[t] = s1pg[((size_t)b * 4 + 0) * 128 + t] + s1pg[((size_t)b * 4 + 1) * 128 + t]
                   + s1pg[((size_t)b * 4 + 2) * 128 + t] + s1pg[((size_t)b * 4 + 3) * 128 + t];
    }

    const size_t aoff = ((size_t)b * 1024 + m0 + srow) * 512;
    const size_t boff = ((size_t)b * 128 + srow) * 512;
    float s0part = 0.f;
    f32x4 acc[4][4] = {};

    for (int k0 = 0; k0 < 512; k0 += 32) {
        __syncthreads();
        {   // A from c fp32 -> fp16 (single-instr cvt), optional s0 dot
            const float* src = Cc + aoff + k0 + sk;
            float4 f[4];
            #pragma unroll
            for (int i = 0; i < 4; i++) f[i] = ((const float4*)src)[i];
            const float* fv = (const float*)f;
            short hv[16];
            #pragma unroll
            for (int j = 0; j < 16; j++) {
                float x = fv[j];
                if (ADDS) s0part += x * cws[k0 + sk + j];
                hv[j] = f2h(x);
            }
            #pragma unroll
            for (int j = 0; j < 2; j++)
                *(bf16x8*)&Ah[srow * LDT + sk + j * 8] = *(bf16x8*)&hv[j * 8];
        }
        {   // B: pure 16-bit copies
            *(uint4*)&Bh[srow * LDT + sk]     = *(const uint4*)(Bhg + boff + k0 + sk);
            *(uint4*)&Bh[srow * LDT + sk + 8] = *(const uint4*)(Bhg + boff + k0 + sk + 8);
        }
        __syncthreads();
        #pragma unroll
        for (int i = 0; i < 4; i++) {
            f16x8 a_ = *(const f16x8*)&Ah[(wr * 64 + i * 16 + fr) * LDT + fg * 8];
            #pragma unroll
            for (int ni = 0; ni < 4; ni++) {
                f16x8 b_ = *(const f16x8*)&Bh[(wc * 64 + ni * 16 + fr) * LDT + fg * 8];
                acc[i][ni] = __builtin_amdgcn_mfma_f32_16x16x32_f16(a_, b_, acc[i][ni], 0, 0, 0);
            }
        }
    }

    // ---- s0/s1 finalize + additive terms ----
    if (ADDS) {
        s0red[srow][t & 1] = s0part;
        __syncthreads();
        if (t < 128) s0L[t] = s0red[t][0] + s0red[t][1];
        __syncthreads();
        float b0 = biasp[0];
        #pragma unroll
        for (int mi = 0; mi < 4; mi++)
        #pragma unroll
        for (int r = 0; r < 4; r++) {
            float s0r = s0L[wr * 64 + mi * 16 + fg * 4 + r] + b0;
            #pragma unroll
            for (int ni = 0; ni < 4; ni++)
                acc[mi][ni][r] += s0r + s1L[wc * 64 + ni * 16 + fr];
        }
    }

    bool qmv[4];
    #pragma unroll
    for (int ni = 0; ni < 4; ni++) qmv[ni] = qmsL[wc * 64 + ni * 16 + fr] != 0;
    bool cmb[4][4];
    #pragma unroll
    for (int mi = 0; mi < 4; mi++)
    #pragma unroll
    for (int r = 0; r < 4; r++) cmb[mi][r] = cmsL[wr * 64 + mi * 16 + fg * 4 + r] != 0;

    // ---- row softmax ----
    #pragma unroll
    for (int mi = 0; mi < 4; mi++)
    #pragma unroll
    for (int r = 0; r < 4; r++) {
        float m = NEGV;
        #pragma unroll
        for (int ni = 0; ni < 4; ni++) if (qmv[ni]) m = fmaxf(m, acc[mi][ni][r]);
        #pragma unroll
        for (int off = 1; off < 16; off <<= 1) m = fmaxf(m, __shfl_xor(m, off));
        if (fr == 0) red[wc][wr * 64 + mi * 16 + fg * 4 + r] = m;
    }
    __syncthreads();
    if (t < 128) mrowL[t] = fmaxf(red[0][t], red[1][t]);
    __syncthreads();
    #pragma unroll
    for (int mi = 0; mi < 4; mi++)
    #pragma unroll
    for (int r = 0; r < 4; r++) {
        float mr = mrowL[wr * 64 + mi * 16 + fg * 4 + r];
        float s = 0.f;
        #pragma unroll
        for (int ni = 0; ni < 4; ni++) if (qmv[ni]) s += __expf(acc[mi][ni][r] - mr);
        #pragma unroll
        for (int off = 1; off < 16; off <<= 1) s += __shfl_xor(s, off);
        if (fr == 0) red[wc][wr * 64 + mi * 16 + fg * 4 + r] = s;
    }
    __syncthreads();
    if (t < 128) rinvL[t] = 1.f / (red[0][t] + red[1][t]);
    __syncthreads();
    #pragma unroll
    for (int mi = 0; mi < 4; mi++)
    #pragma unroll
    for (int r = 0; r < 4; r++) {
        int rowl = wr * 64 + mi * 16 + fg * 4 + r;
        float mr = mrowL[rowl], iv = rinvL[rowl];
        size_t obase = ((size_t)b * 1024 + m0 + rowl) * 128;
        #pragma unroll
        for (int ni = 0; ni < 4; ni++) {
            float o = qmv[ni] ? __expf(acc[mi][ni][r] - mr) * iv : 0.f;
            Pr[obase + wc * 64 + ni * 16 + fr] = f2h(o);
        }
    }

    // ---- column pass: chunk max, then RAW exp(v - M_ch) transposed out (normalized later in kgemm2) ----
    float cpart[4];
    #pragma unroll
    for (int ni = 0; ni < 4; ni++) {
        float m = NEGV;
        #pragma unroll
        for (int mi = 0; mi < 4; mi++)
        #pragma unroll
        for (int r = 0; r < 4; r++) if (cmb[mi][r]) m = fmaxf(m, acc[mi][ni][r]);
        m = fmaxf(m, __shfl_xor(m, 16));
        m = fmaxf(m, __shfl_xor(m, 32));
        cpart[ni] = m;
    }
    if (fg == 0) {
        #pragma unroll
        for (int ni = 0; ni < 4; ni++) red[wr][wc * 64 + ni * 16 + fr] = cpart[ni];
    }
    __syncthreads();
    if (t < 128) cmaxL[t] = fmaxf(red[0][t], red[1][t]);
    __syncthreads();
    #pragma unroll
    for (int ni = 0; ni < 4; ni++) {
        const int q = wc * 64 + ni * 16 + fr;
        float cm = cmaxL[q];
        float s = 0.f;
        #pragma unroll
        for (int mi = 0; mi < 4; mi++)
        #pragma unroll
        for (int r = 0; r < 4; r++) {
            int rloc = wr * 64 + mi * 16 + fg * 4 + r;
            float e = cmb[mi][r] ? __expf(acc[mi][ni][r] - cm) : 0.f;
            s += e;
            TT[q * 136 + rloc] = f2h(e);
        }
        s += __shfl_xor(s, 16);
        s += __shfl_xor(s, 32);
        cpart[ni] = s;
    }
    __syncthreads();
    if (fg == 0) {
        #pragma unroll
        for (int ni = 0; ni < 4; ni++) red[wr][wc * 64 + ni * 16 + fr] = cpart[ni];
    }
    __syncthreads();
    {   // coalesced transposed write of the exp-shifted chunk
        const int q2 = t >> 1, half = t & 1;
        short* dst = Pe + ((size_t)b * 128 + q2) * 1024 + m0 + half * 64;
        #pragma unroll
        for (int j = 0; j < 8; j++)
            *(bf16x8*)(dst + j * 8) = *(const bf16x8*)&TT[q2 * 136 + half * 64 + j * 8];
    }
    if (t < 128) colpart[((size_t)b * 8 + ch) * 128 + t] = make_float2(cmaxL[t], red[0][t] + red[1][t]);
}

// ---------------- fused dual K=1024 GEMM with inline column-softmax normalization ----------------
// A1/A2 hold raw per-chunk exp values; accumulators are rescaled at each 128-K chunk
// boundary (online softmax over the known chunk maxima) and finalized with exp(mh7-Mg)/Sg.
__global__ __launch_bounds__(256)
void k_kgemm2(const short* __restrict__ A1, const short* __restrict__ A2,
              const float* __restrict__ Cc, const float2* __restrict__ cpS,
              const float2* __restrict__ cpC, short* __restrict__ Y1T,
              short* __restrict__ Y2T)
{
    __shared__ __align__(16) short Bs[2][64 * LDT];
    __shared__ __align__(16) short TT[64 * 136];
    __shared__ float wtr[2][8][128];
    __shared__ float fin[2][128];
    const int t = threadIdx.x;
    const int b  = (int)(blockIdx.x & 63);
    const int n0 = (int)(blockIdx.x >> 6) * 64;
    const int lane = t & 63;
    const int w  = t >> 6;
    const int wr = w >> 1, wc = w & 1;
    const int fr = lane & 15, fg = lane >> 4;
    const int n4 = (t & 15) * 4, kk2 = (t >> 4) * 2;

    {   // normalization tables: per (table, q): chunk transition ratios + final scale
        const int tb = t >> 7, qq = t & 127;
        const float2* cp = tb ? cpC : cpS;
        float2 pc[8];
        #pragma unroll
        for (int c2 = 0; c2 < 8; c2++) pc[c2] = cp[((size_t)b * 8 + c2) * 128 + qq];
        float Mg = NEGV;
        #pragma unroll
        for (int c2 = 0; c2 < 8; c2++) Mg = fmaxf(Mg, pc[c2].x);
        float Sg = 0.f;
        #pragma unroll
        for (int c2 = 0; c2 < 8; c2++) Sg += pc[c2].y * __expf(pc[c2].x - Mg);
        const float clampv = Mg - 60.f;
        float mh[8];
        #pragma unroll
        for (int c2 = 0; c2 < 8; c2++) mh[c2] = fmaxf(pc[c2].x, clampv);
        wtr[tb][0][qq] = 1.f;
        #pragma unroll
        for (int c2 = 1; c2 < 8; c2++) wtr[tb][c2][qq] = __expf(mh[c2 - 1] - mh[c2]);
        fin[tb][qq] = (Sg > 0.f) ? __expf(mh[7] - Mg) / Sg : 0.f;
    }

    f32x4 acc1[4][2] = {}, acc2[4][2] = {};

    auto load_e = [&](int k0, float4* e) {
        const float* p = Cc + ((size_t)b * 1024 + k0 + kk2) * 512 + n0 + n4;
        e[0] = *(const float4*)(p);
        e[1] = *(const float4*)(p + 512);
    };
    auto store_b = [&](const float4* e, int buf) {
        const float* p0 = (const float*)&e[0];
        const float* p1 = (const float*)&e[1];
        #pragma unroll
        for (int l = 0; l < 4; l++)
            *(unsigned*)&Bs[buf][(n4 + l) * LDT + kk2] = packh(p0[l], p1[l]);
    };

    {
        float4 e[2];
        load_e(0, e);
        store_b(e, 0);
    }
    __syncthreads();

    for (int k0 = 0; k0 < 1024; k0 += 32) {
        const int cur = (k0 >> 5) & 1;
        const bool more = (k0 + 32) < 1024;
        float4 e[2];
        if (more) load_e(k0 + 32, e);
        if (k0 && (k0 & 127) == 0) {     // chunk boundary: rescale accumulators
            const int c2 = k0 >> 7;
            #pragma unroll
            for (int mi = 0; mi < 4; mi++)
            #pragma unroll
            for (int r = 0; r < 4; r++) {
                int qq = wr * 64 + mi * 16 + fg * 4 + r;
                float f1 = wtr[0][c2][qq], f2 = wtr[1][c2][qq];
                #pragma unroll
                for (int ni = 0; ni < 2; ni++) {
                    acc1[mi][ni][r] *= f1;
                    acc2[mi][ni][r] *= f2;
                }
            }
        }
        f16x8 a1[4], a2[4], bg[2];
        #pragma unroll
        for (int i = 0; i < 4; i++) {
            size_t arow = (size_t)(b * 128 + wr * 64 + i * 16 + fr) * 1024 + k0 + fg * 8;
            a1[i] = *(const f16x8*)(A1 + arow);
            a2[i] = *(const f16x8*)(A2 + arow);
        }
        #pragma unroll
        for (int i = 0; i < 2; i++)
            bg[i] = *(const f16x8*)&Bs[cur][(wc * 32 + i * 16 + fr) * LDT + fg * 8];
        #pragma unroll
        for (int mi = 0; mi < 4; mi++)
        #pragma unroll
        for (int ni = 0; ni < 2; ni++) {
            acc1[mi][ni] = __builtin_amdgcn_mfma_f32_16x16x32_f16(a1[mi], bg[ni], acc1[mi][ni], 0, 0, 0);
            acc2[mi][ni] = __builtin_amdgcn_mfma_f32_16x16x32_f16(a2[mi], bg[ni], acc2[mi][ni], 0, 0, 0);
        }
        if (more) store_b(e, cur ^ 1);
        __syncthreads();
    }

    // transpose-bounce both outputs -> coalesced [B,512,128] fp16 (h-permuted rows), final scale applied
    const int n_l = t >> 2, qu = t & 3;
    const int nm = p64(n_l);
    #pragma unroll
    for (int mi = 0; mi < 4; mi++)
    #pragma unroll
    for (int r = 0; r < 4; r++) {
        int ml = wr * 64 + mi * 16 + fg * 4 + r;
        float fs = fin[0][ml];
        #pragma unroll
        for (int ni = 0; ni < 2; ni++)
            TT[(wc * 32 + ni * 16 + fr) * 136 + ml] = f2h(acc1[mi][ni][r] * fs);
    }
    __syncthreads();
    {
        short* dst = Y1T + ((size_t)b * 512 + n0 + nm) * 128 + qu * 32;
        #pragma unroll
        for (int j = 0; j < 4; j++)
            *(bf16x8*)(dst + j * 8) = *(const bf16x8*)&TT[n_l * 136 + qu * 32 + j * 8];
    }
    __syncthreads();
    #pragma unroll
    for (int mi = 0; mi < 4; mi++)
    #pragma unroll
    for (int r = 0; r < 4; r++) {
        int ml = wr * 64 + mi * 16 + fg * 4 + r;
        float fs = fin[1][ml];
        #pragma unroll
        for (int ni = 0; ni < 2; ni++)
            TT[(wc * 32 + ni * 16 + fr) * 136 + ml] = f2h(acc2[mi][ni][r] * fs);
    }
    __syncthreads();
    {
        short* dst = Y2T + ((size_t)b * 512 + n0 + nm) * 128 + qu * 32;
        #pragma unroll
        for (int j = 0; j < 4; j++)
            *(bf16x8*)(dst + j * 8) = *(const bf16x8*)&TT[n_l * 136 + qu * 32 + j * 8];
    }
}

// ---------------- epilogue GEMM (K=128, fp16), direct-global fragments, float4 fused output writes ----------------
template<bool WITHC>
__global__ __launch_bounds__(256)
void k_epi(const short* __restrict__ Pm, const short* __restrict__ BT1,
           const short* __restrict__ BT2, const float* __restrict__ Cc,
           float* __restrict__ out)
{
    const int t = threadIdx.x;
    const int hb = (int)(blockIdx.x & 3);
    const int mb = (int)((blockIdx.x >> 2) & 7);
    const int b  = (int)(blockIdx.x >> 5);
    const int m0 = mb * 128, h0 = hb * 128;
    const int lane = t & 63;
    const int wr = (t >> 7) & 1, wc = (t >> 6) & 1;
    const int fr = lane & 15, fg = lane >> 4;
    f32x4 acc1[4][4] = {}, acc2[4][4] = {};
    const short* Abase  = Pm  + ((size_t)b * 1024 + m0) * 128;
    const short* B1base = BT1 + ((size_t)b * 512 + h0) * 128;
    const short* B2base = BT2 + ((size_t)b * 512 + h0) * 128;
    #pragma unroll
    for (int kk = 0; kk < 4; kk++) {
        const int k0 = kk * 32;
        f16x8 af[4], b1[4], b2[4];
        #pragma unroll
        for (int i = 0; i < 4; i++) {
            af[i] = *(const f16x8*)(Abase  + (size_t)(wr * 64 + i * 16 + fr) * 128 + k0 + fg * 8);
            b1[i] = *(const f16x8*)(B1base + (size_t)(wc * 64 + i * 16 + fr) * 128 + k0 + fg * 8);
            b2[i] = *(const f16x8*)(B2base + (size_t)(wc * 64 + i * 16 + fr) * 128 + k0 + fg * 8);
        }
        #pragma unroll
        for (int mi = 0; mi < 4; mi++)
        #pragma unroll
        for (int ni = 0; ni < 4; ni++) {
            acc1[mi][ni] = __builtin_amdgcn_mfma_f32_16x16x32_f16(af[mi], b1[ni], acc1[mi][ni], 0, 0, 0);
            acc2[mi][ni] = __builtin_amdgcn_mfma_f32_16x16x32_f16(af[mi], b2[ni], acc2[mi][ni], 0, 0, 0);
        }
    }
    const size_t crow_base = (size_t)b * 1024 + m0;
    const int colb = wc * 64 + fr * 4;       // logical column base (4 consecutive)
    #pragma unroll
    for (int mi = 0; mi < 4; mi++)
    #pragma unroll
    for (int r = 0; r < 4; r++) {
        int rowl = wr * 64 + mi * 16 + fg * 4 + r;
        size_t obase = (crow_base + rowl) * 3072 + h0 + colb;
        float4 av, bv;
        av.x = acc1[mi][0][r]; av.y = acc1[mi][1][r]; av.z = acc1[mi][2][r]; av.w = acc1[mi][3][r];
        bv.x = acc2[mi][0][r]; bv.y = acc2[mi][1][r]; bv.z = acc2[mi][2][r]; bv.w = acc2[mi][3][r];
        if (WITHC) {
            float4 cv = *(const float4*)(Cc + (crow_base + rowl) * 512 + h0 + colb);
            *(float4*)(out + obase) = cv;
            *(float4*)(out + obase + 512) = av;
            float4 ca; ca.x = cv.x * av.x; ca.y = cv.y * av.y; ca.z = cv.z * av.z; ca.w = cv.w * av.w;
            *(float4*)(out + obase + 1024) = ca;
            float4 cb; cb.x = cv.x * bv.x; cb.y = cv.y * bv.y; cb.z = cv.z * bv.z; cb.w = cv.w * bv.w;
            *(float4*)(out + obase + 1536) = cb;
        } else {
            *(float4*)(out + obase + 2048) = bv;
            *(float4*)(out + obase + 2560) = av;
        }
    }
}

// ---------------- host launcher ----------------
extern "C" void kernel_launch(void* const* d_in, const int* in_sizes, int n_in,
                              void* d_out, int out_size, void* d_ws, size_t ws_size,
                              hipStream_t stream)
{
    const float* c     = (const float*)d_in[0];
    const float* q     = (const float*)d_in[1];
    const int*   cmask = (const int*)d_in[2];
    const int*   qmask = (const int*)d_in[3];
    const float* cwv   = (const float*)d_in[4];
    const float* qwv   = (const float*)d_in[5];
    const float* cqw   = (const float*)d_in[6];
    const float* bias  = (const float*)d_in[7];
    const float* W1    = (const float*)d_in[8];
    const float* b1    = (const float*)d_in[9];
    const float* W2    = (const float*)d_in[10];
    const float* b2    = (const float*)d_in[11];
    float* out = (float*)d_out;

    char* ws = (char*)d_ws;
    size_t off = 0;
    auto alloc = [&](size_t bytes) -> char* {
        char* p = ws + off;
        off = (off + bytes + 255) & ~(size_t)255;
        return p;
    };
    short* w1th = (short*)alloc(512 * 512 * 2);
    short* w1tl = (short*)alloc(512 * 512 * 2);
    short* w2th = (short*)alloc(512 * 512 * 2);
    short* w2tl = (short*)alloc(512 * 512 * 2);
    float* s1p  = (float*)alloc(64 * 4 * 128 * 4);
    short* q_cq = (short*)alloc((size_t)64 * 128 * 512 * 2);
    short* qT   = (short*)alloc((size_t)64 * 512 * 128 * 2);
    float* z1   = (float*)alloc((size_t)8192 * 512 * 4);     // layer-1 act; reused for binT/bcoT
    short* qp_f = (short*)alloc((size_t)8192 * 512 * 2);     // fp16 qp
    short* qpT  = (short*)alloc((size_t)64 * 512 * 128 * 2);
    float2* colpartS = (float2*)alloc((size_t)64 * 8 * 128 * 8);
    float2* colpartC = (float2*)alloc((size_t)64 * 8 * 128 * 8);
    short* s1s  = (short*)alloc((size_t)64 * 1024 * 128 * 2);
    short* s2sT = (short*)alloc((size_t)64 * 128 * 1024 * 2);  // raw per-chunk exp (fp16)
    short* sc1  = (short*)alloc((size_t)64 * 1024 * 128 * 2);
    short* sc2T = (short*)alloc((size_t)64 * 128 * 1024 * 2);  // raw per-chunk exp (fp16)
    short* binT = (short*)z1;
    short* bcoT = ((short*)z1) + (size_t)64 * 512 * 128;

    k_prep_w<<<2048, 256, 0, stream>>>(W1, W2, w1th, w1tl, w2th, w2tl);
    k_prep_q<<<256, 256, 0, stream>>>(q, qwv, cqw, q_cq, qT, s1p);
    k_linear<false><<<256, 256, 0, stream>>>(q, w1th, w1tl, b1, z1, nullptr, nullptr);
    k_linear<true><<<256, 256, 0, stream>>>(z1, w2th, w2tl, b2, nullptr, qp_f, qpT);

    // sim pipeline (fp16, with additive terms)
    k_att<true><<<512, 256, 0, stream>>>(
        c, q_cq, cwv, s1p, bias, qmask, cmask, s1s, s2sT, colpartS);

    // scoat pipeline (fp16)
    k_att<false><<<512, 256, 0, stream>>>(
        c, qp_f, nullptr, nullptr, nullptr, qmask, cmask, sc1, sc2T, colpartC);

    // fused dual K=1024 GEMM with inline column-softmax normalization
    k_kgemm2<<<512, 256, 0, stream>>>(s2sT, sc2T, c, colpartS, colpartC, binT, bcoT);

    // fused output epilogues (fp16 MFMA, float4 stores via h-permutation)
    k_epi<true><<<2048, 256, 0, stream>>>(s1s, qT, binT, c, out);
    k_epi<false><<<2048, 256, 0, stream>>>(sc1, qpT, bcoT, nullptr, out);
}

// Round 8
// 568.005 us; speedup vs baseline: 1.3002x; 1.0061x over previous
//
#include <hip/hip_runtime.h>
#include <cstdint>
#include <cstddef>

typedef short    bf16x8 __attribute__((ext_vector_type(8)));
typedef _Float16 f16x8  __attribute__((ext_vector_type(8)));
typedef _Float16 f16x4  __attribute__((ext_vector_type(4)));
typedef float    f32x4  __attribute__((ext_vector_type(4)));

#define NEGV (-1e30f)
#define LDT 40   // padded LDS row pitch (shorts) = 80B: 16B-aligned, 2-way-conflict max (free)

__device__ __forceinline__ short f2bf(float x){
    union { float f; unsigned u; } v; v.f = x;
    return (short)((v.u + 0x7fffu + ((v.u >> 16) & 1u)) >> 16);
}
__device__ __forceinline__ float bf2f(short h){
    union { float f; unsigned u; } v; v.u = ((unsigned)(unsigned short)h) << 16; return v.f;
}
__device__ __forceinline__ short f2h(float x){
    _Float16 h = (_Float16)x;
    union { _Float16 h; unsigned short u; } v; v.h = h;
    return (short)v.u;
}
__device__ __forceinline__ unsigned packh(float a, float b){
    return (unsigned)(unsigned short)f2h(a) | ((unsigned)(unsigned short)f2h(b) << 16);
}
// memory row (within a 64-row group) holding logical column h:
// epi's B-fragment load at row ni*16+fr then yields logical col fr*4+ni (consecutive per thread)
__device__ __forceinline__ int p64(int x){ return ((x & 3) << 4) | (x >> 2); }

// ---------------- prep: W1,W2 -> transposed bf16 hi/lo (MLP stays split-bf16) ----------------
__global__ __launch_bounds__(256)
void k_prep_w(const float* __restrict__ W1, const float* __restrict__ W2,
              short* __restrict__ W1Th, short* __restrict__ W1Tl,
              short* __restrict__ W2Th, short* __restrict__ W2Tl)
{
    int idx = blockIdx.x * 256 + threadIdx.x;
    int w = idx >> 18;
    int e = idx & ((1 << 18) - 1);
    int n = e & 511, k = e >> 9;
    const float* W = w ? W2 : W1;
    float x = W[k * 512 + n];
    short hi = f2bf(x);
    short lo = f2bf(x - bf2f(hi));
    size_t o = (size_t)n * 512 + k;
    if (w) { W2Th[o] = hi; W2Tl[o] = lo; } else { W1Th[o] = hi; W1Tl[o] = lo; }
}

// ---------------- prep q: qT (fp16, transposed, h-permuted), q_cq = f16(q*cqw), s1 partials ----------------
__global__ __launch_bounds__(256)
void k_prep_q(const float* __restrict__ q, const float* __restrict__ qwv,
              const float* __restrict__ cqw, short* __restrict__ q_cq,
              short* __restrict__ qT, float* __restrict__ s1p)
{
    __shared__ short TT[128 * 136];
    __shared__ float qws[128], cqs[128];
    const int t = threadIdx.x;
    const int b = (int)(blockIdx.x >> 2), hb = (int)(blockIdx.x & 3), h0 = hb * 128;
    if (t < 128) { qws[t] = qwv[h0 + t]; cqs[t] = cqw[h0 + t]; }
    __syncthreads();
    #pragma unroll
    for (int it = 0; it < 16; it++) {
        int idx = it * 256 + t;
        int m = idx >> 5, c4 = (idx & 31) * 4;
        float4 v = *(const float4*)(q + ((size_t)b * 128 + m) * 512 + h0 + c4);
        TT[(c4 + 0) * 136 + m] = f2h(v.x);
        TT[(c4 + 1) * 136 + m] = f2h(v.y);
        TT[(c4 + 2) * 136 + m] = f2h(v.z);
        TT[(c4 + 3) * 136 + m] = f2h(v.w);
        uint2 d;
        d.x = packh(v.x * cqs[c4],     v.y * cqs[c4 + 1]);
        d.y = packh(v.z * cqs[c4 + 2], v.w * cqs[c4 + 3]);
        *(uint2*)(q_cq + ((size_t)b * 128 + m) * 512 + h0 + c4) = d;
        float dot = v.x * qws[c4] + v.y * qws[c4 + 1] + v.z * qws[c4 + 2] + v.w * qws[c4 + 3];
        #pragma unroll
        for (int off = 1; off < 32; off <<= 1) dot += __shfl_xor(dot, off);
        if ((t & 31) == 0) s1p[((size_t)b * 4 + hb) * 128 + m] = dot;
    }
    __syncthreads();
    const int h = t >> 1, half = t & 1;
    const int hm = (h & 64) + p64(h & 63);   // permuted destination row
    short* dst = qT + ((size_t)b * 512 + h0 + hm) * 128 + half * 64;
    #pragma unroll
    for (int j = 0; j < 8; j++)
        *(bf16x8*)(dst + j * 8) = *(const bf16x8*)&TT[h * 136 + half * 64 + j * 8];
}

// ---------------- split-bf16 linear; WT variant writes fp16 copy + transposed (h-permuted) fp16 copy ----------------
template<bool WT>
__global__ __launch_bounds__(256)
void k_linear(const float* __restrict__ X, const short* __restrict__ WTh,
              const short* __restrict__ WTl, const float* __restrict__ bias,
              float* __restrict__ Y, short* __restrict__ Yf,
              short* __restrict__ YT)
{
    __shared__ __align__(16) short SMEM[4 * 128 * LDT];
    short* Ah = SMEM;
    short* Al = SMEM + 128 * LDT;
    short* Bh = SMEM + 2 * 128 * LDT;
    short* Bl = SMEM + 3 * 128 * LDT;
    const int t = threadIdx.x;
    const int m0 = (int)(blockIdx.x >> 2) * 128;
    const int n0 = (int)(blockIdx.x & 3) * 128;
    const int lane = t & 63;
    const int wr = (t >> 7) & 1, wc = (t >> 6) & 1;
    const int fr = lane & 15, fg = lane >> 4;
    const int srow = t >> 1, sk = (t & 1) * 16;

    f32x4 acc[4][4] = {};

    for (int k0 = 0; k0 < 512; k0 += 32) {
        __syncthreads();
        {
            const float* src = X + (size_t)(m0 + srow) * 512 + k0 + sk;
            float4 f[4];
            #pragma unroll
            for (int i = 0; i < 4; i++) f[i] = ((const float4*)src)[i];
            const float* fv = (const float*)f;
            short hi[16], lo[16];
            #pragma unroll
            for (int j = 0; j < 16; j++) {
                float x = fv[j];
                short h = f2bf(x);
                hi[j] = h; lo[j] = f2bf(x - bf2f(h));
            }
            #pragma unroll
            for (int j = 0; j < 2; j++) {
                *(bf16x8*)&Ah[srow * LDT + sk + j * 8] = *(bf16x8*)&hi[j * 8];
                *(bf16x8*)&Al[srow * LDT + sk + j * 8] = *(bf16x8*)&lo[j * 8];
            }
        }
        {
            const short* sh = WTh + (size_t)(n0 + srow) * 512 + k0 + sk;
            const short* sl = WTl + (size_t)(n0 + srow) * 512 + k0 + sk;
            #pragma unroll
            for (int j = 0; j < 2; j++) {
                *(bf16x8*)&Bh[srow * LDT + sk + j * 8] = ((const bf16x8*)sh)[j];
                *(bf16x8*)&Bl[srow * LDT + sk + j * 8] = ((const bf16x8*)sl)[j];
            }
        }
        __syncthreads();
        bf16x8 a_h[4], a_l[4], b_h[4], b_l[4];
        #pragma unroll
        for (int i = 0; i < 4; i++) {
            int ar = (wr * 64 + i * 16 + fr) * LDT + fg * 8;
            int br = (wc * 64 + i * 16 + fr) * LDT + fg * 8;
            a_h[i] = *(const bf16x8*)&Ah[ar];
            a_l[i] = *(const bf16x8*)&Al[ar];
            b_h[i] = *(const bf16x8*)&Bh[br];
            b_l[i] = *(const bf16x8*)&Bl[br];
        }
        #pragma unroll
        for (int mi = 0; mi < 4; mi++)
        #pragma unroll
        for (int ni = 0; ni < 4; ni++) {
            acc[mi][ni] = __builtin_amdgcn_mfma_f32_16x16x32_bf16(a_h[mi], b_h[ni], acc[mi][ni], 0, 0, 0);
            acc[mi][ni] = __builtin_amdgcn_mfma_f32_16x16x32_bf16(a_h[mi], b_l[ni], acc[mi][ni], 0, 0, 0);
            acc[mi][ni] = __builtin_amdgcn_mfma_f32_16x16x32_bf16(a_l[mi], b_h[ni], acc[mi][ni], 0, 0, 0);
        }
    }
    float bv[4];
    #pragma unroll
    for (int ni = 0; ni < 4; ni++) bv[ni] = bias[n0 + wc * 64 + ni * 16 + fr];

    if (!WT) {
        #pragma unroll
        for (int mi = 0; mi < 4; mi++)
        #pragma unroll
        for (int r = 0; r < 4; r++) {
            int row = m0 + wr * 64 + mi * 16 + fg * 4 + r;
            #pragma unroll
            for (int ni = 0; ni < 4; ni++)
                Y[(size_t)row * 512 + n0 + wc * 64 + ni * 16 + fr] =
                    fmaxf(acc[mi][ni][r] + bv[ni], 0.f);
        }
    } else {
        #pragma unroll
        for (int mi = 0; mi < 4; mi++)
        #pragma unroll
        for (int r = 0; r < 4; r++) {
            int row = m0 + wr * 64 + mi * 16 + fg * 4 + r;
            #pragma unroll
            for (int ni = 0; ni < 4; ni++) {
                float v = fmaxf(acc[mi][ni][r] + bv[ni], 0.f);
                size_t o = (size_t)row * 512 + n0 + wc * 64 + ni * 16 + fr;
                Yf[o] = f2h(v);     // fp16 copy for the scoat logits GEMM
            }
        }
        __syncthreads();
        short* TT = SMEM;
        #pragma unroll
        for (int mi = 0; mi < 4; mi++)
        #pragma unroll
        for (int r = 0; r < 4; r++) {
            int ml = wr * 64 + mi * 16 + fg * 4 + r;
            #pragma unroll
            for (int ni = 0; ni < 4; ni++)
                TT[(wc * 64 + ni * 16 + fr) * 136 + ml] =
                    f2h(fmaxf(acc[mi][ni][r] + bv[ni], 0.f));
        }
        __syncthreads();
        const int n = t >> 1, half = t & 1;
        const int nm = (n & 64) + p64(n & 63);   // permuted destination row
        short* dst = YT + ((size_t)(m0 >> 7) * 512 + n0 + nm) * 128 + half * 64;
        #pragma unroll
        for (int j = 0; j < 8; j++)
            *(bf16x8*)(dst + j * 8) = *(const bf16x8*)&TT[n * 136 + half * 64 + j * 8];
    }
}

// ---------------- DUAL logits GEMM: one c read -> both sim & scoat pipelines ----------------
// A = c fp32 -> fp16 on the fly (also exported to c16 for downstream consumers).
// B1 = q_cq (sim), B2 = qp (scoat). Dual f32 accumulators; sequential dual-softmax epilogues.
__global__ __launch_bounds__(256, 2)
void k_att_dual(const float* __restrict__ Cc, const short* __restrict__ B1g,
                const short* __restrict__ B2g, const float* __restrict__ cwv,
                const float* __restrict__ s1pg, const float* __restrict__ biasp,
                const int* __restrict__ qmask, const int* __restrict__ cmask,
                short* __restrict__ c16,
                short* __restrict__ Pr1, short* __restrict__ Pe1, float2* __restrict__ cp1,
                short* __restrict__ Pr2, short* __restrict__ Pe2, float2* __restrict__ cp2)
{
    __shared__ __align__(16) short SM[128 * 136];   // staging 3*128*LDT=30720B | bounce 34816B
    short* Ah  = SM;
    short* B1h = SM + 128 * LDT;
    short* B2h = SM + 2 * 128 * LDT;
    short* TT  = SM;
    __shared__ float red[2][128];
    __shared__ float mrowL[128], rinvL[128], cmaxL[128];
    __shared__ float cws[512];
    __shared__ float s0red[128][2];
    __shared__ float s0L[128], s1L[128];
    __shared__ int qmsL[128], cmsL[128];

    const int t = threadIdx.x;
    const int b  = (int)(blockIdx.x & 63);      // 8 chunks of b land on one XCD
    const int ch = (int)(blockIdx.x >> 6);
    const int m0 = ch * 128;
    const int lane = t & 63;
    const int wr = (t >> 7) & 1, wc = (t >> 6) & 1;
    const int fr = lane & 15, fg = lane >> 4;
    const int srow = t >> 1, sk = (t & 1) * 16;

    cws[t] = cwv[t]; cws[t + 256] = cwv[t + 256];
    if (t < 128) {
        qmsL[t] = qmask[b * 128 + t];
        cmsL[t] = cmask[b * 1024 + m0 + t];
        s1L[t] = s1pg[((size_t)b * 4 + 0) * 128 + t] + s1pg[((size_t)b * 4 + 1) * 128 + t]
               + s1pg[((size_t)b * 4 + 2) * 128 + t] + s1pg[((size_t)b * 4 + 3) * 128 + t];
    }

    const size_t aoff = ((size_t)b * 1024 + m0 + srow) * 512;
    const size_t boff = ((size_t)b * 128 + srow) * 512;
    float s0part = 0.f;
    f32x4 acc1[4][4] = {}, acc2[4][4] = {};

    for (int k0 = 0; k0 < 512; k0 += 32) {
        __syncthreads();
        {   // A from c fp32 -> fp16; s0 dot; export c16
            const float* src = Cc + aoff + k0 + sk;
            float4 f[4];
            #pragma unroll
            for (int i = 0; i < 4; i++) f[i] = ((const float4*)src)[i];
            const float* fv = (const float*)f;
            short hv[16];
            #pragma unroll
            for (int j = 0; j < 16; j++) {
                float x = fv[j];
                s0part += x * cws[k0 + sk + j];
                hv[j] = f2h(x);
            }
            #pragma unroll
            for (int j = 0; j < 2; j++) {
                *(bf16x8*)&Ah[srow * LDT + sk + j * 8] = *(bf16x8*)&hv[j * 8];
                *(bf16x8*)(c16 + aoff + k0 + sk + j * 8) = *(bf16x8*)&hv[j * 8];
            }
        }
        {   // B1/B2: pure 16-bit copies
            *(uint4*)&B1h[srow * LDT + sk]     = *(const uint4*)(B1g + boff + k0 + sk);
            *(uint4*)&B1h[srow * LDT + sk + 8] = *(const uint4*)(B1g + boff + k0 + sk + 8);
            *(uint4*)&B2h[srow * LDT + sk]     = *(const uint4*)(B2g + boff + k0 + sk);
            *(uint4*)&B2h[srow * LDT + sk + 8] = *(const uint4*)(B2g + boff + k0 + sk + 8);
        }
        __syncthreads();
        #pragma unroll
        for (int i = 0; i < 4; i++) {
            f16x8 a_ = *(const f16x8*)&Ah[(wr * 64 + i * 16 + fr) * LDT + fg * 8];
            #pragma unroll
            for (int ni = 0; ni < 4; ni++) {
                int br = (wc * 64 + ni * 16 + fr) * LDT + fg * 8;
                f16x8 b1_ = *(const f16x8*)&B1h[br];
                acc1[i][ni] = __builtin_amdgcn_mfma_f32_16x16x32_f16(a_, b1_, acc1[i][ni], 0, 0, 0);
                f16x8 b2_ = *(const f16x8*)&B2h[br];
                acc2[i][ni] = __builtin_amdgcn_mfma_f32_16x16x32_f16(a_, b2_, acc2[i][ni], 0, 0, 0);
            }
        }
    }

    // ---- s0/s1/bias additive terms (sim pipeline only) ----
    s0red[srow][t & 1] = s0part;
    __syncthreads();
    if (t < 128) s0L[t] = s0red[t][0] + s0red[t][1];
    __syncthreads();
    {
        float b0 = biasp[0];
        #pragma unroll
        for (int mi = 0; mi < 4; mi++)
        #pragma unroll
        for (int r = 0; r < 4; r++) {
            float s0r = s0L[wr * 64 + mi * 16 + fg * 4 + r] + b0;
            #pragma unroll
            for (int ni = 0; ni < 4; ni++)
                acc1[mi][ni][r] += s0r + s1L[wc * 64 + ni * 16 + fr];
        }
    }

    bool qmv[4];
    #pragma unroll
    for (int ni = 0; ni < 4; ni++) qmv[ni] = qmsL[wc * 64 + ni * 16 + fr] != 0;
    bool cmb[4][4];
    #pragma unroll
    for (int mi = 0; mi < 4; mi++)
    #pragma unroll
    for (int r = 0; r < 4; r++) cmb[mi][r] = cmsL[wr * 64 + mi * 16 + fg * 4 + r] != 0;

    auto emit = [&](f32x4 (&acc)[4][4], short* __restrict__ Pr,
                    short* __restrict__ Pe, float2* __restrict__ cpart_g) {
        __syncthreads();    // protect red/TT from previous pipeline's readers
        // ---- row softmax ----
        #pragma unroll
        for (int mi = 0; mi < 4; mi++)
        #pragma unroll
        for (int r = 0; r < 4; r++) {
            float m = NEGV;
            #pragma unroll
            for (int ni = 0; ni < 4; ni++) if (qmv[ni]) m = fmaxf(m, acc[mi][ni][r]);
            #pragma unroll
            for (int off = 1; off < 16; off <<= 1) m = fmaxf(m, __shfl_xor(m, off));
            if (fr == 0) red[wc][wr * 64 + mi * 16 + fg * 4 + r] = m;
        }
        __syncthreads();
        if (t < 128) mrowL[t] = fmaxf(red[0][t], red[1][t]);
        __syncthreads();
        #pragma unroll
        for (int mi = 0; mi < 4; mi++)
        #pragma unroll
        for (int r = 0; r < 4; r++) {
            float mr = mrowL[wr * 64 + mi * 16 + fg * 4 + r];
            float s = 0.f;
            #pragma unroll
            for (int ni = 0; ni < 4; ni++) if (qmv[ni]) s += __expf(acc[mi][ni][r] - mr);
            #pragma unroll
            for (int off = 1; off < 16; off <<= 1) s += __shfl_xor(s, off);
            if (fr == 0) red[wc][wr * 64 + mi * 16 + fg * 4 + r] = s;
        }
        __syncthreads();
        if (t < 128) rinvL[t] = 1.f / (red[0][t] + red[1][t]);
        __syncthreads();
        #pragma unroll
        for (int mi = 0; mi < 4; mi++)
        #pragma unroll
        for (int r = 0; r < 4; r++) {
            int rowl = wr * 64 + mi * 16 + fg * 4 + r;
            float mr = mrowL[rowl], iv = rinvL[rowl];
            size_t obase = ((size_t)b * 1024 + m0 + rowl) * 128;
            #pragma unroll
            for (int ni = 0; ni < 4; ni++) {
                float o = qmv[ni] ? __expf(acc[mi][ni][r] - mr) * iv : 0.f;
                Pr[obase + wc * 64 + ni * 16 + fr] = f2h(o);
            }
        }
        // ---- column pass: chunk max, raw exp(v - M_ch) transposed out ----
        float cpart[4];
        #pragma unroll
        for (int ni = 0; ni < 4; ni++) {
            float m = NEGV;
            #pragma unroll
            for (int mi = 0; mi < 4; mi++)
            #pragma unroll
            for (int r = 0; r < 4; r++) if (cmb[mi][r]) m = fmaxf(m, acc[mi][ni][r]);
            m = fmaxf(m, __shfl_xor(m, 16));
            m = fmaxf(m, __shfl_xor(m, 32));
            cpart[ni] = m;
        }
        if (fg == 0) {
            #pragma unroll
            for (int ni = 0; ni < 4; ni++) red[wr][wc * 64 + ni * 16 + fr] = cpart[ni];
        }
        __syncthreads();
        if (t < 128) cmaxL[t] = fmaxf(red[0][t], red[1][t]);
        __syncthreads();
        #pragma unroll
        for (int ni = 0; ni < 4; ni++) {
            const int q = wc * 64 + ni * 16 + fr;
            float cm = cmaxL[q];
            float s = 0.f;
            #pragma unroll
            for (int mi = 0; mi < 4; mi++)
            #pragma unroll
            for (int r = 0; r < 4; r++) {
                int rloc = wr * 64 + mi * 16 + fg * 4 + r;
                float e = cmb[mi][r] ? __expf(acc[mi][ni][r] - cm) : 0.f;
                s += e;
                TT[q * 136 + rloc] = f2h(e);
            }
            s += __shfl_xor(s, 16);
            s += __shfl_xor(s, 32);
            cpart[ni] = s;
        }
        __syncthreads();
        if (fg == 0) {
            #pragma unroll
            for (int ni = 0; ni < 4; ni++) red[wr][wc * 64 + ni * 16 + fr] = cpart[ni];
        }
        __syncthreads();
        {   // coalesced transposed write of the exp-shifted chunk
            const int q2 = t >> 1, half = t & 1;
            short* dst = Pe + ((size_t)b * 128 + q2) * 1024 + m0 + half * 64;
            #pragma unroll
            for (int j = 0; j < 8; j++)
                *(bf16x8*)(dst + j * 8) = *(const bf16x8*)&TT[q2 * 136 + half * 64 + j * 8];
        }
        if (t < 128) cpart_g[((size_t)b * 8 + ch) * 128 + t] = make_float2(cmaxL[t], red[0][t] + red[1][t]);
    };

    emit(acc1, Pr1, Pe1, cp1);
    emit(acc2, Pr2, Pe2, cp2);
}

// ---------------- fused dual K=1024 GEMM (c16 input) with inline column-softmax normalization ----------------
__global__ __launch_bounds__(256)
void k_kgemm2(const short* __restrict__ A1, const short* __restrict__ A2,
              const short* __restrict__ C16, const float2* __restrict__ cpS,
              const float2* __restrict__ cpC, short* __restrict__ Y1T,
              short* __restrict__ Y2T)
{
    __shared__ __align__(16) short Bs[2][64 * LDT];
    __shared__ __align__(16) short TT[64 * 136];
    __shared__ float wtr[2][8][128];
    __shared__ float fin[2][128];
    const int t = threadIdx.x;
    const int b  = (int)(blockIdx.x & 63);
    const int n0 = (int)(blockIdx.x >> 6) * 64;
    const int lane = t & 63;
    const int w  = t >> 6;
    const int wr = w >> 1, wc = w & 1;
    const int fr = lane & 15, fg = lane >> 4;
    const int n4 = (t & 15) * 4, kk2 = (t >> 4) * 2;

    {   // normalization tables
        const int tb = t >> 7, qq = t & 127;
        const float2* cp = tb ? cpC : cpS;
        float2 pc[8];
        #pragma unroll
        for (int c2 = 0; c2 < 8; c2++) pc[c2] = cp[((size_t)b * 8 + c2) * 128 + qq];
        float Mg = NEGV;
        #pragma unroll
        for (int c2 = 0; c2 < 8; c2++) Mg = fmaxf(Mg, pc[c2].x);
        float Sg = 0.f;
        #pragma unroll
        for (int c2 = 0; c2 < 8; c2++) Sg += pc[c2].y * __expf(pc[c2].x - Mg);
        const float clampv = Mg - 60.f;
        float mh[8];
        #pragma unroll
        for (int c2 = 0; c2 < 8; c2++) mh[c2] = fmaxf(pc[c2].x, clampv);
        wtr[tb][0][qq] = 1.f;
        #pragma unroll
        for (int c2 = 1; c2 < 8; c2++) wtr[tb][c2][qq] = __expf(mh[c2 - 1] - mh[c2]);
        fin[tb][qq] = (Sg > 0.f) ? __expf(mh[7] - Mg) / Sg : 0.f;
    }

    f32x4 acc1[4][2] = {}, acc2[4][2] = {};

    auto load_e = [&](int k0, uint2* e) {
        const short* p = C16 + ((size_t)b * 1024 + k0 + kk2) * 512 + n0 + n4;
        e[0] = *(const uint2*)(p);
        e[1] = *(const uint2*)(p + 512);
    };
    auto store_b = [&](const uint2* e, int buf) {
        const unsigned short* r0 = (const unsigned short*)&e[0];
        const unsigned short* r1 = (const unsigned short*)&e[1];
        #pragma unroll
        for (int l = 0; l < 4; l++)
            *(unsigned*)&Bs[buf][(n4 + l) * LDT + kk2] = (unsigned)r0[l] | ((unsigned)r1[l] << 16);
    };

    {
        uint2 e[2];
        load_e(0, e);
        store_b(e, 0);
    }
    __syncthreads();

    for (int k0 = 0; k0 < 1024; k0 += 32) {
        const int cur = (k0 >> 5) & 1;
        const bool more = (k0 + 32) < 1024;
        uint2 e[2];
        if (more) load_e(k0 + 32, e);
        if (k0 && (k0 & 127) == 0) {     // chunk boundary: rescale accumulators
            const int c2 = k0 >> 7;
            #pragma unroll
            for (int mi = 0; mi < 4; mi++)
            #pragma unroll
            for (int r = 0; r < 4; r++) {
                int qq = wr * 64 + mi * 16 + fg * 4 + r;
                float f1 = wtr[0][c2][qq], f2 = wtr[1][c2][qq];
                #pragma unroll
                for (int ni = 0; ni < 2; ni++) {
                    acc1[mi][ni][r] *= f1;
                    acc2[mi][ni][r] *= f2;
                }
            }
        }
        f16x8 a1[4], a2[4], bg[2];
        #pragma unroll
        for (int i = 0; i < 4; i++) {
            size_t arow = (size_t)(b * 128 + wr * 64 + i * 16 + fr) * 1024 + k0 + fg * 8;
            a1[i] = *(const f16x8*)(A1 + arow);
            a2[i] = *(const f16x8*)(A2 + arow);
        }
        #pragma unroll
        for (int i = 0; i < 2; i++)
            bg[i] = *(const f16x8*)&Bs[cur][(wc * 32 + i * 16 + fr) * LDT + fg * 8];
        #pragma unroll
        for (int mi = 0; mi < 4; mi++)
        #pragma unroll
        for (int ni = 0; ni < 2; ni++) {
            acc1[mi][ni] = __builtin_amdgcn_mfma_f32_16x16x32_f16(a1[mi], bg[ni], acc1[mi][ni], 0, 0, 0);
            acc2[mi][ni] = __builtin_amdgcn_mfma_f32_16x16x32_f16(a2[mi], bg[ni], acc2[mi][ni], 0, 0, 0);
        }
        if (more) store_b(e, cur ^ 1);
        __syncthreads();
    }

    // transpose-bounce both outputs -> coalesced [B,512,128] fp16 (h-permuted rows), final scale
    const int n_l = t >> 2, qu = t & 3;
    const int nm = p64(n_l);
    #pragma unroll
    for (int mi = 0; mi < 4; mi++)
    #pragma unroll
    for (int r = 0; r < 4; r++) {
        int ml = wr * 64 + mi * 16 + fg * 4 + r;
        float fs = fin[0][ml];
        #pragma unroll
        for (int ni = 0; ni < 2; ni++)
            TT[(wc * 32 + ni * 16 + fr) * 136 + ml] = f2h(acc1[mi][ni][r] * fs);
    }
    __syncthreads();
    {
        short* dst = Y1T + ((size_t)b * 512 + n0 + nm) * 128 + qu * 32;
        #pragma unroll
        for (int j = 0; j < 4; j++)
            *(bf16x8*)(dst + j * 8) = *(const bf16x8*)&TT[n_l * 136 + qu * 32 + j * 8];
    }
    __syncthreads();
    #pragma unroll
    for (int mi = 0; mi < 4; mi++)
    #pragma unroll
    for (int r = 0; r < 4; r++) {
        int ml = wr * 64 + mi * 16 + fg * 4 + r;
        float fs = fin[1][ml];
        #pragma unroll
        for (int ni = 0; ni < 2; ni++)
            TT[(wc * 32 + ni * 16 + fr) * 136 + ml] = f2h(acc2[mi][ni][r] * fs);
    }
    __syncthreads();
    {
        short* dst = Y2T + ((size_t)b * 512 + n0 + nm) * 128 + qu * 32;
        #pragma unroll
        for (int j = 0; j < 4; j++)
            *(bf16x8*)(dst + j * 8) = *(const bf16x8*)&TT[n_l * 136 + qu * 32 + j * 8];
    }
}

// ---------------- epilogue GEMM (K=128, fp16), direct-global fragments, float4 fused output writes ----------------
template<bool WITHC>
__global__ __launch_bounds__(256)
void k_epi(const short* __restrict__ Pm, const short* __restrict__ BT1,
           const short* __restrict__ BT2, const short* __restrict__ C16,
           float* __restrict__ out)
{
    const int t = threadIdx.x;
    const int hb = (int)(blockIdx.x & 3);
    const int mb = (int)((blockIdx.x >> 2) & 7);
    const int b  = (int)(blockIdx.x >> 5);
    const int m0 = mb * 128, h0 = hb * 128;
    const int lane = t & 63;
    const int wr = (t >> 7) & 1, wc = (t >> 6) & 1;
    const int fr = lane & 15, fg = lane >> 4;
    f32x4 acc1[4][4] = {}, acc2[4][4] = {};
    const short* Abase  = Pm  + ((size_t)b * 1024 + m0) * 128;
    const short* B1base = BT1 + ((size_t)b * 512 + h0) * 128;
    const short* B2base = BT2 + ((size_t)b * 512 + h0) * 128;
    #pragma unroll
    for (int kk = 0; kk < 4; kk++) {
        const int k0 = kk * 32;
        f16x8 af[4], b1[4], b2[4];
        #pragma unroll
        for (int i = 0; i < 4; i++) {
            af[i] = *(const f16x8*)(Abase  + (size_t)(wr * 64 + i * 16 + fr) * 128 + k0 + fg * 8);
            b1[i] = *(const f16x8*)(B1base + (size_t)(wc * 64 + i * 16 + fr) * 128 + k0 + fg * 8);
            b2[i] = *(const f16x8*)(B2base + (size_t)(wc * 64 + i * 16 + fr) * 128 + k0 + fg * 8);
        }
        #pragma unroll
        for (int mi = 0; mi < 4; mi++)
        #pragma unroll
        for (int ni = 0; ni < 4; ni++) {
            acc1[mi][ni] = __builtin_amdgcn_mfma_f32_16x16x32_f16(af[mi], b1[ni], acc1[mi][ni], 0, 0, 0);
            acc2[mi][ni] = __builtin_amdgcn_mfma_f32_16x16x32_f16(af[mi], b2[ni], acc2[mi][ni], 0, 0, 0);
        }
    }
    const size_t crow_base = (size_t)b * 1024 + m0;
    const int colb = wc * 64 + fr * 4;       // logical column base (4 consecutive)
    #pragma unroll
    for (int mi = 0; mi < 4; mi++)
    #pragma unroll
    for (int r = 0; r < 4; r++) {
        int rowl = wr * 64 + mi * 16 + fg * 4 + r;
        size_t obase = (crow_base + rowl) * 3072 + h0 + colb;
        float4 av, bv;
        av.x = acc1[mi][0][r]; av.y = acc1[mi][1][r]; av.z = acc1[mi][2][r]; av.w = acc1[mi][3][r];
        bv.x = acc2[mi][0][r]; bv.y = acc2[mi][1][r]; bv.z = acc2[mi][2][r]; bv.w = acc2[mi][3][r];
        if (WITHC) {
            f16x4 cv4 = *(const f16x4*)(C16 + (crow_base + rowl) * 512 + h0 + colb);
            float4 cv;
            cv.x = (float)cv4[0]; cv.y = (float)cv4[1]; cv.z = (float)cv4[2]; cv.w = (float)cv4[3];
            *(float4*)(out + obase) = cv;
            *(float4*)(out + obase + 512) = av;
            float4 ca; ca.x = cv.x * av.x; ca.y = cv.y * av.y; ca.z = cv.z * av.z; ca.w = cv.w * av.w;
            *(float4*)(out + obase + 1024) = ca;
            float4 cb; cb.x = cv.x * bv.x; cb.y = cv.y * bv.y; cb.z = cv.z * bv.z; cb.w = cv.w * bv.w;
            *(float4*)(out + obase + 1536) = cb;
        } else {
            *(float4*)(out + obase + 2048) = bv;
            *(float4*)(out + obase + 2560) = av;
        }
    }
}

// ---------------- host launcher ----------------
extern "C" void kernel_launch(void* const* d_in, const int* in_sizes, int n_in,
                              void* d_out, int out_size, void* d_ws, size_t ws_size,
                              hipStream_t stream)
{
    const float* c     = (const float*)d_in[0];
    const float* q     = (const float*)d_in[1];
    const int*   cmask = (const int*)d_in[2];
    const int*   qmask = (const int*)d_in[3];
    const float* cwv   = (const float*)d_in[4];
    const float* qwv   = (const float*)d_in[5];
    const float* cqw   = (const float*)d_in[6];
    const float* bias  = (const float*)d_in[7];
    const float* W1    = (const float*)d_in[8];
    const float* b1    = (const float*)d_in[9];
    const float* W2    = (const float*)d_in[10];
    const float* b2    = (const float*)d_in[11];
    float* out = (float*)d_out;

    char* ws = (char*)d_ws;
    size_t off = 0;
    auto alloc = [&](size_t bytes) -> char* {
        char* p = ws + off;
        off = (off + bytes + 255) & ~(size_t)255;
        return p;
    };
    short* w1th = (short*)alloc(512 * 512 * 2);
    short* w1tl = (short*)alloc(512 * 512 * 2);
    short* w2th = (short*)alloc(512 * 512 * 2);
    short* w2tl = (short*)alloc(512 * 512 * 2);
    float* s1p  = (float*)alloc(64 * 4 * 128 * 4);
    short* q_cq = (short*)alloc((size_t)64 * 128 * 512 * 2);
    short* qT   = (short*)alloc((size_t)64 * 512 * 128 * 2);
    float* z1   = (float*)alloc((size_t)8192 * 512 * 4);     // layer-1 act; reused for binT/bcoT
    short* qp_f = (short*)alloc((size_t)8192 * 512 * 2);     // fp16 qp
    short* qpT  = (short*)alloc((size_t)64 * 512 * 128 * 2);
    short* c16  = (short*)alloc((size_t)64 * 1024 * 512 * 2);  // fp16 c (exported by k_att_dual)
    float2* colpartS = (float2*)alloc((size_t)64 * 8 * 128 * 8);
    float2* colpartC = (float2*)alloc((size_t)64 * 8 * 128 * 8);
    short* s1s  = (short*)alloc((size_t)64 * 1024 * 128 * 2);
    short* s2sT = (short*)alloc((size_t)64 * 128 * 1024 * 2);  // raw per-chunk exp (fp16)
    short* sc1  = (short*)alloc((size_t)64 * 1024 * 128 * 2);
    short* sc2T = (short*)alloc((size_t)64 * 128 * 1024 * 2);  // raw per-chunk exp (fp16)
    short* binT = (short*)z1;
    short* bcoT = ((short*)z1) + (size_t)64 * 512 * 128;

    k_prep_w<<<2048, 256, 0, stream>>>(W1, W2, w1th, w1tl, w2th, w2tl);
    k_prep_q<<<256, 256, 0, stream>>>(q, qwv, cqw, q_cq, qT, s1p);
    k_linear<false><<<256, 256, 0, stream>>>(q, w1th, w1tl, b1, z1, nullptr, nullptr);
    k_linear<true><<<256, 256, 0, stream>>>(z1, w2th, w2tl, b2, nullptr, qp_f, qpT);

    // merged logits pipelines: one c read, both GEMMs, c16 export
    k_att_dual<<<512, 256, 0, stream>>>(
        c, q_cq, qp_f, cwv, s1p, bias, qmask, cmask, c16,
        s1s, s2sT, colpartS, sc1, sc2T, colpartC);

    // fused dual K=1024 GEMM (fp16 c16 input) with inline column-softmax normalization
    k_kgemm2<<<512, 256, 0, stream>>>(s2sT, sc2T, c16, colpartS, colpartC, binT, bcoT);

    // fused output epilogues (fp16 MFMA, float4 stores via h-permutation)
    k_epi<true><<<2048, 256, 0, stream>>>(s1s, qT, binT, c16, out);
    k_epi<false><<<2048, 256, 0, stream>>>(sc1, qpT, bcoT, nullptr, out);
}